// Round 1
// baseline (3816.597 us; speedup 1.0000x reference)
//
#include <hip/hip_runtime.h>
#include <hip/hip_bf16.h>

// Problem constants
#define BB 4
#define CC 256
#define TT 16
#define HW 196
#define DEMO_T 4
#define OBS_T 12
#define DPOS 784      // DEMO_T*HW
#define OPOS 2352     // OBS_T*HW
#define XROW 3136     // TT*HW
#define NHEADS 8
#define CH 32
#define INV_TEMP 0.0625f
#define NPOS 980      // DPOS + HW (cat keys per (b,t,n))

// ---------------------------------------------------------------------------
// Tiled fp32 GEMM: O[b][f][p] = sum_c W[f][c] * X[b][c][xBase + p]
// X row stride = xRowStride; 3 weight/output pairs selected by blockIdx.z.
// Block 256 threads, 64x64 tile, K-tile 16, 4x4 micro-tile per thread.
// ---------------------------------------------------------------------------
__global__ __launch_bounds__(256) void proj_gemm(
    const float* __restrict__ X, int xRowStride, int xBase, int ncols,
    const float* __restrict__ W0, const float* __restrict__ W1, const float* __restrict__ W2,
    float* __restrict__ O0, float* __restrict__ O1, float* __restrict__ O2)
{
    const int ptiles = (ncols + 63) >> 6;
    const int b  = blockIdx.x / ptiles;
    const int pt = blockIdx.x % ptiles;
    const int fbase = blockIdx.y * 64;
    const int pbase = pt * 64;
    const float* W = (blockIdx.z == 0) ? W0 : (blockIdx.z == 1) ? W1 : W2;
    float*       O = (blockIdx.z == 0) ? O0 : (blockIdx.z == 1) ? O1 : O2;

    const int tid = threadIdx.x;
    const int tx = tid & 15, ty = tid >> 4;

    __shared__ float Wt[64][20];
    __shared__ float Xt[16][68];

    float acc[4][4] = {};
    const float* Xb = X + (size_t)b * CC * xRowStride + xBase;
    const bool fullp = (pbase + 64 <= ncols);

    for (int c0 = 0; c0 < CC; c0 += 16) {
        // W tile: 64f x 16c, one float4 per thread
        {
            int fi = tid >> 2, ci4 = (tid & 3) * 4;
            const float4 wv = *reinterpret_cast<const float4*>(&W[(size_t)(fbase + fi) * CC + c0 + ci4]);
            Wt[fi][ci4]   = wv.x; Wt[fi][ci4+1] = wv.y;
            Wt[fi][ci4+2] = wv.z; Wt[fi][ci4+3] = wv.w;
        }
        // X tile: 16c x 64p, one float4 per thread
        {
            int ci = tid >> 4, pj = (tid & 15) * 4;
            const float* src = Xb + (size_t)(c0 + ci) * xRowStride + pbase + pj;
            if (fullp) {
                const float4 xv = *reinterpret_cast<const float4*>(src);
                Xt[ci][pj]   = xv.x; Xt[ci][pj+1] = xv.y;
                Xt[ci][pj+2] = xv.z; Xt[ci][pj+3] = xv.w;
            } else {
                #pragma unroll
                for (int u = 0; u < 4; u++)
                    Xt[ci][pj+u] = (pbase + pj + u < ncols) ? src[u] : 0.f;
            }
        }
        __syncthreads();
        #pragma unroll
        for (int ci = 0; ci < 16; ci++) {
            float wv[4], xv[4];
            #pragma unroll
            for (int i = 0; i < 4; i++) wv[i] = Wt[ty*4+i][ci];
            #pragma unroll
            for (int j = 0; j < 4; j++) xv[j] = Xt[ci][tx*4+j];
            #pragma unroll
            for (int i = 0; i < 4; i++)
                #pragma unroll
                for (int j = 0; j < 4; j++) acc[i][j] += wv[i] * xv[j];
        }
        __syncthreads();
    }
    #pragma unroll
    for (int i = 0; i < 4; i++) {
        const int f = fbase + ty*4 + i;
        float* dst = O + ((size_t)b * CC + f) * ncols + pbase + tx*4;
        #pragma unroll
        for (int j = 0; j < 4; j++) {
            if (pbase + tx*4 + j < ncols) dst[j] = acc[i][j];
        }
    }
}

// ---------------------------------------------------------------------------
// Demo attention (flash-style, softmax over the dq axis j):
//   S[i,j] = sum_c dk[c,i] dq[c,j] / 16 ;  attn = softmax_j(S)
//   dvatt[c,i] = sum_j attn[i,j] dv[c,j]
// Grid (25 i-tiles of 32, HEADS, B), 256 threads: thread = (il = t%32, cg = t/32),
// cg owns 4 channels. Online softmax over 7 j-tiles of 112.
// ---------------------------------------------------------------------------
__global__ __launch_bounds__(256) void demo_attn(
    const float* __restrict__ dq, const float* __restrict__ dk,
    const float* __restrict__ dv, float* __restrict__ dvatt)
{
    const int itile = blockIdx.x, n = blockIdx.y, b = blockIdx.z;
    const int ibase = itile * 32;
    const float* Kp = dk + ((size_t)b*CC + n*CH) * DPOS;
    const float* Qp = dq + ((size_t)b*CC + n*CH) * DPOS;
    const float* Vp = dv + ((size_t)b*CC + n*CH) * DPOS;

    __shared__ float Kt[32][33];
    __shared__ float Qt[32][113];
    __shared__ float Vt[32][113];
    __shared__ float St[32][113];
    __shared__ float red[32][9];
    __shared__ float m_s[32], l_s[32], scale_s[32];

    const int tid = threadIdx.x;
    const int il = tid & 31, cg = tid >> 5;

    for (int idx = tid; idx < 32*32; idx += 256) {
        int c = idx >> 5, ii = idx & 31;
        Kt[c][ii] = (ibase + ii < DPOS) ? Kp[c*DPOS + ibase + ii] : 0.f;
    }
    if (tid < 32) { m_s[tid] = -1e30f; l_s[tid] = 0.f; }
    float acc[4] = {0.f, 0.f, 0.f, 0.f};
    __syncthreads();

    for (int jt = 0; jt < DPOS; jt += 112) {
        for (int idx = tid; idx < 32*112; idx += 256) {
            int c = idx / 112, j = idx % 112;
            Qt[c][j] = Qp[c*DPOS + jt + j];
            Vt[c][j] = Vp[c*DPOS + jt + j];
        }
        __syncthreads();

        float svals[14];
        float pmax = -1e30f;
        #pragma unroll
        for (int k = 0; k < 14; k++) {
            const int j = cg + 8*k;
            float s = 0.f;
            #pragma unroll
            for (int c = 0; c < 32; c++) s += Kt[c][il] * Qt[c][j];
            s *= INV_TEMP;
            svals[k] = s;
            pmax = fmaxf(pmax, s);
        }
        red[il][cg] = pmax;
        __syncthreads();
        if (tid < 32) {
            float mt = red[tid][0];
            #pragma unroll
            for (int g = 1; g < 8; g++) mt = fmaxf(mt, red[tid][g]);
            const float mold = m_s[tid];
            const float mnew = fmaxf(mold, mt);
            scale_s[tid] = __expf(mold - mnew);
            m_s[tid] = mnew;
        }
        __syncthreads();
        const float mnew = m_s[il], scale = scale_s[il];
        float psum = 0.f;
        #pragma unroll
        for (int k = 0; k < 14; k++) {
            const float p = __expf(svals[k] - mnew);
            St[il][cg + 8*k] = p;
            psum += p;
        }
        red[il][cg] = psum;
        #pragma unroll
        for (int cc = 0; cc < 4; cc++) acc[cc] *= scale;
        __syncthreads();
        if (tid < 32) {
            float s = 0.f;
            #pragma unroll
            for (int g = 0; g < 8; g++) s += red[tid][g];
            l_s[tid] = l_s[tid] * scale_s[tid] + s;
        }
        for (int j = 0; j < 112; j++) {
            const float p = St[il][j];
            #pragma unroll
            for (int cc = 0; cc < 4; cc++) acc[cc] += p * Vt[cg*4+cc][j];
        }
        __syncthreads();
    }
    if (ibase + il < DPOS) {
        const float linv = 1.f / l_s[il];
        #pragma unroll
        for (int cc = 0; cc < 4; cc++)
            dvatt[((size_t)b*CC + n*CH + cg*4 + cc) * DPOS + ibase + il] = acc[cc] * linv;
    }
}

// ---------------------------------------------------------------------------
// Obs attention per (b, t, n):
//   K[c,p] = p<784 ? dk[c,p] : ok[c, t*196 + p-784]   (same for V with dvatt/ov)
//   S[p,q] = K[:,p].Q[:,q]/16 ; attn = softmax over q (per p-row, independent!)
//   O[c,q] = sum_p V[c,p] attn[p,q]  -> merged[b][n*32+c][t*196+q]
// Block 256 threads; Q resident in LDS; loop p in 35 tiles of 28.
// ---------------------------------------------------------------------------
__global__ __launch_bounds__(256) void obs_attn(
    const float* __restrict__ dk, const float* __restrict__ dvatt,
    const float* __restrict__ ok, const float* __restrict__ ov,
    const float* __restrict__ oq, float* __restrict__ merged)
{
    const int t_ = blockIdx.x, n = blockIdx.y, b = blockIdx.z;
    const float* Kd = dk    + ((size_t)b*CC + n*CH) * DPOS;
    const float* Vd = dvatt + ((size_t)b*CC + n*CH) * DPOS;
    const float* Ko = ok + ((size_t)b*CC + n*CH) * OPOS + t_*HW;
    const float* Vo = ov + ((size_t)b*CC + n*CH) * OPOS + t_*HW;
    const float* Qo = oq + ((size_t)b*CC + n*CH) * OPOS + t_*HW;

    __shared__ float Qt[32][197];
    __shared__ float St[28][197];
    __shared__ float Kt[32][29];
    __shared__ float Vt[32][29];

    const int tid = threadIdx.x;
    for (int idx = tid; idx < 32*HW; idx += 256) {
        int c = idx / HW, q = idx % HW;
        Qt[c][q] = Qo[(size_t)c * OPOS + q];
    }
    const int c  = tid & 31;
    const int qg = tid >> 5;
    float acc[25];
    #pragma unroll
    for (int k = 0; k < 25; k++) acc[k] = 0.f;
    __syncthreads();

    for (int ptile = 0; ptile < NPOS; ptile += 28) {
        // K/V tile gather (demo vs obs source)
        for (int idx = tid; idx < 32*28; idx += 256) {
            int cc = idx / 28, pl = idx % 28;
            int p = ptile + pl;
            float kv, vv;
            if (p < DPOS) { kv = Kd[(size_t)cc*DPOS + p];           vv = Vd[(size_t)cc*DPOS + p]; }
            else          { kv = Ko[(size_t)cc*OPOS + (p - DPOS)];  vv = Vo[(size_t)cc*OPOS + (p - DPOS)]; }
            Kt[cc][pl] = kv; Vt[cc][pl] = vv;
        }
        __syncthreads();
        // scores
        for (int idx = tid; idx < 28*HW; idx += 256) {
            int pl = idx / HW, q = idx % HW;
            float s = 0.f;
            #pragma unroll
            for (int ci = 0; ci < 32; ci++) s += Kt[ci][pl] * Qt[ci][q];
            St[pl][q] = s * INV_TEMP;
        }
        __syncthreads();
        // softmax over q per row; wave w handles rows w, w+4, ...
        {
            const int lane = tid & 63, w = tid >> 6;
            for (int r = w; r < 28; r += 4) {
                float m = -1e30f;
                #pragma unroll
                for (int k = 0; k < 4; k++) {
                    int q = lane + 64*k;
                    if (q < HW) m = fmaxf(m, St[r][q]);
                }
                #pragma unroll
                for (int off = 32; off > 0; off >>= 1) m = fmaxf(m, __shfl_xor(m, off));
                float sum = 0.f;
                #pragma unroll
                for (int k = 0; k < 4; k++) {
                    int q = lane + 64*k;
                    if (q < HW) { float p = __expf(St[r][q] - m); St[r][q] = p; sum += p; }
                }
                #pragma unroll
                for (int off = 32; off > 0; off >>= 1) sum += __shfl_xor(sum, off);
                const float inv = 1.f / sum;
                #pragma unroll
                for (int k = 0; k < 4; k++) {
                    int q = lane + 64*k;
                    if (q < HW) St[r][q] *= inv;
                }
            }
        }
        __syncthreads();
        // accumulate O[c, q] += V[c,p] * attn[p,q]
        #pragma unroll 4
        for (int pl = 0; pl < 28; pl++) {
            const float v = Vt[c][pl];
            #pragma unroll
            for (int k = 0; k < 25; k++) {
                const int q = qg + 8*k;
                if (q < HW) acc[k] += v * St[pl][q];
            }
        }
        __syncthreads();
    }
    // stage O into LDS (reuse Qt) for coalesced store
    #pragma unroll
    for (int k = 0; k < 25; k++) {
        const int q = qg + 8*k;
        if (q < HW) Qt[c][q] = acc[k];
    }
    __syncthreads();
    for (int idx = tid; idx < 32*HW; idx += 256) {
        int cc = idx / HW, q = idx % HW;
        merged[((size_t)b*CC + n*CH + cc) * OPOS + t_*HW + q] = Qt[cc][q];
    }
}

// ---------------------------------------------------------------------------
// Fused residual-ReLU + concat + BatchNorm. One block per channel.
//   obs_new = obs_in + relu(obs_out); cat = [demo_in, obs_new]
//   out = gamma * (cat - mean) * rsqrt(var + eps) + beta
// ---------------------------------------------------------------------------
__global__ __launch_bounds__(256) void bn_fuse(
    const float* __restrict__ xin, const float* __restrict__ obsout,
    const float* __restrict__ gamma, const float* __restrict__ beta,
    float* __restrict__ xout)
{
    const int c = blockIdx.x;
    const int tid = threadIdx.x;
    float sum = 0.f, sumsq = 0.f;
    for (int idx = tid; idx < BB*DPOS; idx += 256) {
        int b = idx / DPOS, pos = idx % DPOS;
        float v = xin[((size_t)b*CC + c) * XROW + pos];
        sum += v; sumsq += v * v;
    }
    for (int idx = tid; idx < BB*OPOS; idx += 256) {
        int b = idx / OPOS, pos = idx % OPOS;
        float v = xin[((size_t)b*CC + c) * XROW + DPOS + pos]
                + fmaxf(obsout[((size_t)b*CC + c) * OPOS + pos], 0.f);
        sum += v; sumsq += v * v;
    }
    #pragma unroll
    for (int off = 32; off > 0; off >>= 1) {
        sum   += __shfl_xor(sum, off);
        sumsq += __shfl_xor(sumsq, off);
    }
    __shared__ float ssum[4], ssq[4];
    __shared__ float s_mean, s_inv;
    const int lane = tid & 63, w = tid >> 6;
    if (lane == 0) { ssum[w] = sum; ssq[w] = sumsq; }
    __syncthreads();
    if (tid == 0) {
        float s  = ssum[0] + ssum[1] + ssum[2] + ssum[3];
        float sq = ssq[0] + ssq[1] + ssq[2] + ssq[3];
        const float mean = s / 12544.f;
        const float var  = sq / 12544.f - mean * mean;
        s_mean = mean;
        s_inv  = rsqrtf(var + 1e-5f);
    }
    __syncthreads();
    const float mean = s_mean;
    const float gi = gamma[c] * s_inv;
    const float bt = beta[c];
    for (int idx = tid; idx < BB*DPOS; idx += 256) {
        int b = idx / DPOS, pos = idx % DPOS;
        size_t o = ((size_t)b*CC + c) * XROW + pos;
        xout[o] = (xin[o] - mean) * gi + bt;
    }
    for (int idx = tid; idx < BB*OPOS; idx += 256) {
        int b = idx / OPOS, pos = idx % OPOS;
        float v = xin[((size_t)b*CC + c) * XROW + DPOS + pos]
                + fmaxf(obsout[((size_t)b*CC + c) * OPOS + pos], 0.f);
        xout[((size_t)b*CC + c) * XROW + DPOS + pos] = (v - mean) * gi + bt;
    }
}

// ---------------------------------------------------------------------------
extern "C" void kernel_launch(void* const* d_in, const int* in_sizes, int n_in,
                              void* d_out, int out_size, void* d_ws, size_t ws_size,
                              hipStream_t stream)
{
    const float* x   = (const float*)d_in[0];
    const float* dqw = (const float*)d_in[1];
    const float* dkw = (const float*)d_in[2];
    const float* dvw = (const float*)d_in[3];
    const float* oqw = (const float*)d_in[4];
    const float* okw = (const float*)d_in[5];
    const float* ovw = (const float*)d_in[6];
    const float* oow = (const float*)d_in[7];
    const float* gam = (const float*)d_in[8];
    const float* bet = (const float*)d_in[9];

    const size_t XN = (size_t)BB * CC * TT * HW;   // 3,211,264
    const size_t DN = (size_t)BB * CC * DPOS;      //   802,816
    const size_t ON = (size_t)BB * CC * OPOS;      // 2,408,448

    float* ws     = (float*)d_ws;
    float* xb0    = ws;
    float* xb1    = xb0 + XN;
    float* dq     = xb1 + XN;
    float* dk     = dq + DN;
    float* dv     = dk + DN;
    float* oq     = dv + DN;
    float* okb    = oq + ON;
    float* ovb    = okb + ON;
    float* dvatt  = ovb + ON;
    float* merged = dvatt + DN;
    float* obsout = merged + ON;

    const dim3 blk(256);
    for (int i = 0; i < 3; i++) {
        const float* xin  = (i == 0) ? x : (i == 1 ? xb0 : xb1);
        float*       xout = (i == 2) ? (float*)d_out : (i == 0 ? xb0 : xb1);
        const size_t wOff = (size_t)i * CC * CC;

        proj_gemm<<<dim3(BB*13, 4, 3), blk, 0, stream>>>(
            xin, XROW, 0, DPOS, dqw + wOff, dkw + wOff, dvw + wOff, dq, dk, dv);
        proj_gemm<<<dim3(BB*37, 4, 3), blk, 0, stream>>>(
            xin, XROW, DPOS, OPOS, oqw + wOff, okw + wOff, ovw + wOff, oq, okb, ovb);
        demo_attn<<<dim3(25, NHEADS, BB), blk, 0, stream>>>(dq, dk, dv, dvatt);
        obs_attn<<<dim3(OBS_T, NHEADS, BB), blk, 0, stream>>>(dk, dvatt, okb, ovb, oq, merged);
        proj_gemm<<<dim3(BB*37, 4, 1), blk, 0, stream>>>(
            merged, OPOS, 0, OPOS, oow + wOff, oow + wOff, oow + wOff, obsout, obsout, obsout);
        bn_fuse<<<dim3(CC), blk, 0, stream>>>(xin, obsout, gam + i*CC, bet + i*CC, xout);
    }
}

// Round 2
// 1864.360 us; speedup vs baseline: 2.0471x; 2.0471x over previous
//
#include <hip/hip_runtime.h>
#include <hip/hip_bf16.h>

// Problem constants
#define BB 4
#define CC 256
#define TT 16
#define HW 196
#define DEMO_T 4
#define OBS_T 12
#define DPOS 784      // DEMO_T*HW
#define OPOS 2352     // OBS_T*HW
#define XROW 3136     // TT*HW
#define NHEADS 8
#define CH 32
#define INV_TEMP 0.0625f
#define NPOS 980      // DPOS + HW (cat keys per (b,t,n))

// ---------------------------------------------------------------------------
// Tiled fp32 GEMM: O[b][f][p] = sum_c W[f][c] * X[b][c][xBase + p]
// 64x64 tile, K-tile 16, 4x4 micro-tile. W tile stored TRANSPOSED so the
// inner loop is two ds_read_b128 per 16 FMA.
// ---------------------------------------------------------------------------
__global__ __launch_bounds__(256) void proj_gemm(
    const float* __restrict__ X, int xRowStride, int xBase, int ncols,
    const float* __restrict__ W0, const float* __restrict__ W1, const float* __restrict__ W2,
    float* __restrict__ O0, float* __restrict__ O1, float* __restrict__ O2)
{
    const int ptiles = (ncols + 63) >> 6;
    const int b  = blockIdx.x / ptiles;
    const int pt = blockIdx.x % ptiles;
    const int fbase = blockIdx.y * 64;
    const int pbase = pt * 64;
    const float* W = (blockIdx.z == 0) ? W0 : (blockIdx.z == 1) ? W1 : W2;
    float*       O = (blockIdx.z == 0) ? O0 : (blockIdx.z == 1) ? O1 : O2;

    const int tid = threadIdx.x;
    const int tx = tid & 15, ty = tid >> 4;

    __shared__ float WtT[16][68];   // [c][f]
    __shared__ float Xt[16][68];    // [c][p]

    float acc[4][4] = {};
    const float* Xb = X + (size_t)b * CC * xRowStride + xBase;
    const bool fullp = (pbase + 64 <= ncols);

    for (int c0 = 0; c0 < CC; c0 += 16) {
        // W tile: 64f x 16c, one float4 per thread, store transposed
        {
            int fi = tid >> 2, ci4 = (tid & 3) * 4;
            const float4 wv = *reinterpret_cast<const float4*>(&W[(size_t)(fbase + fi) * CC + c0 + ci4]);
            WtT[ci4+0][fi] = wv.x; WtT[ci4+1][fi] = wv.y;
            WtT[ci4+2][fi] = wv.z; WtT[ci4+3][fi] = wv.w;
        }
        // X tile: 16c x 64p, one float4 per thread
        {
            int ci = tid >> 4, pj = (tid & 15) * 4;
            const float* src = Xb + (size_t)(c0 + ci) * xRowStride + pbase + pj;
            if (fullp) {
                const float4 xv = *reinterpret_cast<const float4*>(src);
                Xt[ci][pj]   = xv.x; Xt[ci][pj+1] = xv.y;
                Xt[ci][pj+2] = xv.z; Xt[ci][pj+3] = xv.w;
            } else {
                #pragma unroll
                for (int u = 0; u < 4; u++)
                    Xt[ci][pj+u] = (pbase + pj + u < ncols) ? src[u] : 0.f;
            }
        }
        __syncthreads();
        #pragma unroll
        for (int ci = 0; ci < 16; ci++) {
            const float4 wv4 = *reinterpret_cast<const float4*>(&WtT[ci][ty*4]);
            const float4 xv4 = *reinterpret_cast<const float4*>(&Xt[ci][tx*4]);
            const float wv[4] = {wv4.x, wv4.y, wv4.z, wv4.w};
            const float xv[4] = {xv4.x, xv4.y, xv4.z, xv4.w};
            #pragma unroll
            for (int i = 0; i < 4; i++)
                #pragma unroll
                for (int j = 0; j < 4; j++) acc[i][j] += wv[i] * xv[j];
        }
        __syncthreads();
    }
    #pragma unroll
    for (int i = 0; i < 4; i++) {
        const int f = fbase + ty*4 + i;
        float* dst = O + ((size_t)b * CC + f) * ncols + pbase + tx*4;
        #pragma unroll
        for (int j = 0; j < 4; j++) {
            if (pbase + tx*4 + j < ncols) dst[j] = acc[i][j];
        }
    }
}

// ---------------------------------------------------------------------------
// Demo attention (flash-style, softmax over the dq axis j):
//   S[i,j] = sum_c dk[c,i] dq[c,j] / 16 ;  attn = softmax_j(S)
//   dvatt[c,i] = sum_j attn[i,j] dv[c,j]
// ---------------------------------------------------------------------------
__global__ __launch_bounds__(256) void demo_attn(
    const float* __restrict__ dq, const float* __restrict__ dk,
    const float* __restrict__ dv, float* __restrict__ dvatt)
{
    const int itile = blockIdx.x, n = blockIdx.y, b = blockIdx.z;
    const int ibase = itile * 32;
    const float* Kp = dk + ((size_t)b*CC + n*CH) * DPOS;
    const float* Qp = dq + ((size_t)b*CC + n*CH) * DPOS;
    const float* Vp = dv + ((size_t)b*CC + n*CH) * DPOS;

    __shared__ float Kt[32][33];
    __shared__ float Qt[32][113];
    __shared__ float Vt[32][113];
    __shared__ float St[32][113];
    __shared__ float red[32][9];
    __shared__ float m_s[32], l_s[32], scale_s[32];

    const int tid = threadIdx.x;
    const int il = tid & 31, cg = tid >> 5;

    for (int idx = tid; idx < 32*32; idx += 256) {
        int c = idx >> 5, ii = idx & 31;
        Kt[c][ii] = (ibase + ii < DPOS) ? Kp[c*DPOS + ibase + ii] : 0.f;
    }
    if (tid < 32) { m_s[tid] = -1e30f; l_s[tid] = 0.f; }
    float acc[4] = {0.f, 0.f, 0.f, 0.f};
    __syncthreads();

    for (int jt = 0; jt < DPOS; jt += 112) {
        for (int idx = tid; idx < 32*112; idx += 256) {
            int c = idx / 112, j = idx % 112;
            Qt[c][j] = Qp[c*DPOS + jt + j];
            Vt[c][j] = Vp[c*DPOS + jt + j];
        }
        __syncthreads();

        float svals[14];
        float pmax = -1e30f;
        #pragma unroll
        for (int k = 0; k < 14; k++) {
            const int j = cg + 8*k;
            float s = 0.f;
            #pragma unroll
            for (int c = 0; c < 32; c++) s += Kt[c][il] * Qt[c][j];
            s *= INV_TEMP;
            svals[k] = s;
            pmax = fmaxf(pmax, s);
        }
        red[il][cg] = pmax;
        __syncthreads();
        if (tid < 32) {
            float mt = red[tid][0];
            #pragma unroll
            for (int g = 1; g < 8; g++) mt = fmaxf(mt, red[tid][g]);
            const float mold = m_s[tid];
            const float mnew = fmaxf(mold, mt);
            scale_s[tid] = __expf(mold - mnew);
            m_s[tid] = mnew;
        }
        __syncthreads();
        const float mnew = m_s[il], scale = scale_s[il];
        float psum = 0.f;
        #pragma unroll
        for (int k = 0; k < 14; k++) {
            const float p = __expf(svals[k] - mnew);
            St[il][cg + 8*k] = p;
            psum += p;
        }
        red[il][cg] = psum;
        #pragma unroll
        for (int cc = 0; cc < 4; cc++) acc[cc] *= scale;
        __syncthreads();
        if (tid < 32) {
            float s = 0.f;
            #pragma unroll
            for (int g = 0; g < 8; g++) s += red[tid][g];
            l_s[tid] = l_s[tid] * scale_s[tid] + s;
        }
        for (int j = 0; j < 112; j++) {
            const float p = St[il][j];
            #pragma unroll
            for (int cc = 0; cc < 4; cc++) acc[cc] += p * Vt[cg*4+cc][j];
        }
        __syncthreads();
    }
    if (ibase + il < DPOS) {
        const float linv = 1.f / l_s[il];
        #pragma unroll
        for (int cc = 0; cc < 4; cc++)
            dvatt[((size_t)b*CC + n*CH + cg*4 + cc) * DPOS + ibase + il] = acc[cc] * linv;
    }
}

// ---------------------------------------------------------------------------
// Obs attention per (b, t, n) — register micro-tiled.
//   K[c,p] = p<784 ? dk[c,p] : ok[c, t*196 + p-784]   (same for V)
//   S[p,q] = K[:,p].Q[:,q]/16 ; softmax over q per p-row; O[c,q]=sum_p V attn
// p padded to 992 = 31 tiles of 32 (pad rows K=V=0 -> contribute 0).
// Thread layout both phases: wave w owns 8 rows (p or c), lane owns 4 q
// (q = lane*4..+3, lanes 0..48 valid). K/V broadcast float4 reads; Q/St
// ds_read_b128 per lane. Next tile's K/V prefetched to registers.
// ---------------------------------------------------------------------------
__global__ __launch_bounds__(256) void obs_attn(
    const float* __restrict__ dk, const float* __restrict__ dvatt,
    const float* __restrict__ ok, const float* __restrict__ ov,
    const float* __restrict__ oq, float* __restrict__ merged)
{
    const int t_ = blockIdx.x, n = blockIdx.y, b = blockIdx.z;
    const float* Kd = dk    + ((size_t)b*CC + n*CH) * DPOS;
    const float* Vd = dvatt + ((size_t)b*CC + n*CH) * DPOS;
    const float* Ko = ok + ((size_t)b*CC + n*CH) * OPOS + t_*HW;
    const float* Vo = ov + ((size_t)b*CC + n*CH) * OPOS + t_*HW;
    const float* Qo = oq + ((size_t)b*CC + n*CH) * OPOS + t_*HW;

    __shared__ float Qt[32][200];   // [c][q]  25600 B
    __shared__ float St[32][200];   // [p][q]  25600 B
    __shared__ float Kt[32][32];    // [c][p]   4096 B
    __shared__ float VtT[32][36];   // [p][c]   4608 B   (total 59904 B)

    const int tid  = threadIdx.x;
    const int lane = tid & 63;
    const int w    = tid >> 6;
    const int qoff = (lane < 50) ? lane * 4 : 0;   // clamp OOB lanes

    // Stage Q: 32c x 196q (49 quads per row)
    for (int idx = tid; idx < 32*49; idx += 256) {
        int c = idx / 49, qq = idx % 49;
        const float4 v = *reinterpret_cast<const float4*>(Qo + (size_t)c*OPOS + qq*4);
        *reinterpret_cast<float4*>(&Qt[c][qq*4]) = v;
    }
    // Stage K/V tile 0 (p 0..31, all demo)
    const int sc = tid >> 3, spq = tid & 7;
    {
        const int p0 = spq * 4;
        const float4 kq = *reinterpret_cast<const float4*>(Kd + (size_t)sc*DPOS + p0);
        const float4 vq = *reinterpret_cast<const float4*>(Vd + (size_t)sc*DPOS + p0);
        *reinterpret_cast<float4*>(&Kt[sc][p0]) = kq;
        VtT[p0+0][sc] = vq.x; VtT[p0+1][sc] = vq.y;
        VtT[p0+2][sc] = vq.z; VtT[p0+3][sc] = vq.w;
    }
    float accO[8][4];
    #pragma unroll
    for (int i = 0; i < 8; i++)
        #pragma unroll
        for (int k = 0; k < 4; k++) accO[i][k] = 0.f;
    __syncthreads();

    for (int tl = 0; tl < 31; ++tl) {
        // prefetch next tile's K/V to registers (latency hidden under compute)
        float4 nk = make_float4(0.f,0.f,0.f,0.f), nv = make_float4(0.f,0.f,0.f,0.f);
        if (tl < 30) {
            const int p0 = (tl+1)*32 + spq*4;
            if (p0 < DPOS) {
                nk = *reinterpret_cast<const float4*>(Kd + (size_t)sc*DPOS + p0);
                nv = *reinterpret_cast<const float4*>(Vd + (size_t)sc*DPOS + p0);
            } else if (p0 < NPOS) {
                nk = *reinterpret_cast<const float4*>(Ko + (size_t)sc*OPOS + (p0 - DPOS));
                nv = *reinterpret_cast<const float4*>(Vo + (size_t)sc*OPOS + (p0 - DPOS));
            }
        }

        // ---- score: s[i][k], p = w*8+i, q = lane*4+k ----
        float s[8][4];
        #pragma unroll
        for (int i = 0; i < 8; i++)
            #pragma unroll
            for (int k = 0; k < 4; k++) s[i][k] = 0.f;
        #pragma unroll 2
        for (int ci = 0; ci < 32; ++ci) {
            const float4 k0 = *reinterpret_cast<const float4*>(&Kt[ci][w*8]);
            const float4 k1 = *reinterpret_cast<const float4*>(&Kt[ci][w*8+4]);
            const float4 qv = *reinterpret_cast<const float4*>(&Qt[ci][qoff]);
            const float kk[8] = {k0.x,k0.y,k0.z,k0.w,k1.x,k1.y,k1.z,k1.w};
            const float qq[4] = {qv.x,qv.y,qv.z,qv.w};
            #pragma unroll
            for (int i = 0; i < 8; i++)
                #pragma unroll
                for (int k = 0; k < 4; k++) s[i][k] += kk[i] * qq[k];
        }
        // ---- softmax per p-row (shuffle reduce over lanes), write P -> St ----
        #pragma unroll
        for (int i = 0; i < 8; i++) {
            float sv[4];
            #pragma unroll
            for (int k = 0; k < 4; k++) sv[k] = (lane < 49) ? s[i][k]*INV_TEMP : -1e30f;
            float m = fmaxf(fmaxf(sv[0],sv[1]), fmaxf(sv[2],sv[3]));
            #pragma unroll
            for (int off = 32; off > 0; off >>= 1) m = fmaxf(m, __shfl_xor(m, off));
            const float p0 = __expf(sv[0]-m), p1 = __expf(sv[1]-m);
            const float p2 = __expf(sv[2]-m), p3 = __expf(sv[3]-m);
            float sum = p0+p1+p2+p3;
            #pragma unroll
            for (int off = 32; off > 0; off >>= 1) sum += __shfl_xor(sum, off);
            const float inv = 1.f / sum;
            if (lane < 49)
                *reinterpret_cast<float4*>(&St[w*8+i][lane*4]) =
                    make_float4(p0*inv, p1*inv, p2*inv, p3*inv);
        }
        __syncthreads();

        // ---- PV: accO[i][k], c = w*8+i ----
        #pragma unroll 4
        for (int p = 0; p < 32; ++p) {
            const float4 v0 = *reinterpret_cast<const float4*>(&VtT[p][w*8]);
            const float4 v1 = *reinterpret_cast<const float4*>(&VtT[p][w*8+4]);
            const float4 pq = *reinterpret_cast<const float4*>(&St[p][qoff]);
            const float vv[8] = {v0.x,v0.y,v0.z,v0.w,v1.x,v1.y,v1.z,v1.w};
            const float pp[4] = {pq.x,pq.y,pq.z,pq.w};
            #pragma unroll
            for (int i = 0; i < 8; i++)
                #pragma unroll
                for (int k = 0; k < 4; k++) accO[i][k] += vv[i] * pp[k];
        }
        __syncthreads();

        if (tl < 30) {
            const int p0 = spq * 4;
            *reinterpret_cast<float4*>(&Kt[sc][p0]) = nk;
            VtT[p0+0][sc] = nv.x; VtT[p0+1][sc] = nv.y;
            VtT[p0+2][sc] = nv.z; VtT[p0+3][sc] = nv.w;
            __syncthreads();
        }
    }
    if (lane < 49) {
        #pragma unroll
        for (int i = 0; i < 8; i++) {
            float* dst = merged + ((size_t)b*CC + n*CH + w*8 + i)*OPOS + t_*HW + lane*4;
            *reinterpret_cast<float4*>(dst) =
                make_float4(accO[i][0], accO[i][1], accO[i][2], accO[i][3]);
        }
    }
}

// ---------------------------------------------------------------------------
// Fused residual-ReLU + concat + BatchNorm. One block per channel.
// ---------------------------------------------------------------------------
__global__ __launch_bounds__(256) void bn_fuse(
    const float* __restrict__ xin, const float* __restrict__ obsout,
    const float* __restrict__ gamma, const float* __restrict__ beta,
    float* __restrict__ xout)
{
    const int c = blockIdx.x;
    const int tid = threadIdx.x;
    float sum = 0.f, sumsq = 0.f;
    for (int idx = tid; idx < BB*DPOS; idx += 256) {
        int b = idx / DPOS, pos = idx % DPOS;
        float v = xin[((size_t)b*CC + c) * XROW + pos];
        sum += v; sumsq += v * v;
    }
    for (int idx = tid; idx < BB*OPOS; idx += 256) {
        int b = idx / OPOS, pos = idx % OPOS;
        float v = xin[((size_t)b*CC + c) * XROW + DPOS + pos]
                + fmaxf(obsout[((size_t)b*CC + c) * OPOS + pos], 0.f);
        sum += v; sumsq += v * v;
    }
    #pragma unroll
    for (int off = 32; off > 0; off >>= 1) {
        sum   += __shfl_xor(sum, off);
        sumsq += __shfl_xor(sumsq, off);
    }
    __shared__ float ssum[4], ssq[4];
    __shared__ float s_mean, s_inv;
    const int lane = tid & 63, w = tid >> 6;
    if (lane == 0) { ssum[w] = sum; ssq[w] = sumsq; }
    __syncthreads();
    if (tid == 0) {
        float s  = ssum[0] + ssum[1] + ssum[2] + ssum[3];
        float sq = ssq[0] + ssq[1] + ssq[2] + ssq[3];
        const float mean = s / 12544.f;
        const float var  = sq / 12544.f - mean * mean;
        s_mean = mean;
        s_inv  = rsqrtf(var + 1e-5f);
    }
    __syncthreads();
    const float mean = s_mean;
    const float gi = gamma[c] * s_inv;
    const float bt = beta[c];
    for (int idx = tid; idx < BB*DPOS; idx += 256) {
        int b = idx / DPOS, pos = idx % DPOS;
        size_t o = ((size_t)b*CC + c) * XROW + pos;
        xout[o] = (xin[o] - mean) * gi + bt;
    }
    for (int idx = tid; idx < BB*OPOS; idx += 256) {
        int b = idx / OPOS, pos = idx % OPOS;
        float v = xin[((size_t)b*CC + c) * XROW + DPOS + pos]
                + fmaxf(obsout[((size_t)b*CC + c) * OPOS + pos], 0.f);
        xout[((size_t)b*CC + c) * XROW + DPOS + pos] = (v - mean) * gi + bt;
    }
}

// ---------------------------------------------------------------------------
extern "C" void kernel_launch(void* const* d_in, const int* in_sizes, int n_in,
                              void* d_out, int out_size, void* d_ws, size_t ws_size,
                              hipStream_t stream)
{
    const float* x   = (const float*)d_in[0];
    const float* dqw = (const float*)d_in[1];
    const float* dkw = (const float*)d_in[2];
    const float* dvw = (const float*)d_in[3];
    const float* oqw = (const float*)d_in[4];
    const float* okw = (const float*)d_in[5];
    const float* ovw = (const float*)d_in[6];
    const float* oow = (const float*)d_in[7];
    const float* gam = (const float*)d_in[8];
    const float* bet = (const float*)d_in[9];

    const size_t XN = (size_t)BB * CC * TT * HW;   // 3,211,264
    const size_t DN = (size_t)BB * CC * DPOS;      //   802,816
    const size_t ON = (size_t)BB * CC * OPOS;      // 2,408,448

    float* ws     = (float*)d_ws;
    float* xb0    = ws;
    float* xb1    = xb0 + XN;
    float* dq     = xb1 + XN;
    float* dk     = dq + DN;
    float* dv     = dk + DN;
    float* oq     = dv + DN;
    float* okb    = oq + ON;
    float* ovb    = okb + ON;
    float* dvatt  = ovb + ON;
    float* merged = dvatt + DN;
    float* obsout = merged + ON;

    const dim3 blk(256);
    for (int i = 0; i < 3; i++) {
        const float* xin  = (i == 0) ? x : (i == 1 ? xb0 : xb1);
        float*       xout = (i == 2) ? (float*)d_out : (i == 0 ? xb0 : xb1);
        const size_t wOff = (size_t)i * CC * CC;

        proj_gemm<<<dim3(BB*13, 4, 3), blk, 0, stream>>>(
            xin, XROW, 0, DPOS, dqw + wOff, dkw + wOff, dvw + wOff, dq, dk, dv);
        proj_gemm<<<dim3(BB*37, 4, 3), blk, 0, stream>>>(
            xin, XROW, DPOS, OPOS, oqw + wOff, okw + wOff, ovw + wOff, oq, okb, ovb);
        demo_attn<<<dim3(25, NHEADS, BB), blk, 0, stream>>>(dq, dk, dv, dvatt);
        obs_attn<<<dim3(OBS_T, NHEADS, BB), blk, 0, stream>>>(dk, dvatt, okb, ovb, oq, merged);
        proj_gemm<<<dim3(BB*37, 4, 1), blk, 0, stream>>>(
            merged, OPOS, 0, OPOS, oow + wOff, oow + wOff, oow + wOff, obsout, obsout, obsout);
        bn_fuse<<<dim3(CC), blk, 0, stream>>>(xin, obsout, gam + i*CC, bet + i*CC, xout);
    }
}

// Round 3
// 1267.216 us; speedup vs baseline: 3.0118x; 1.4712x over previous
//
#include <hip/hip_runtime.h>
#include <hip/hip_bf16.h>

// Problem constants
#define BB 4
#define CC 256
#define TT 16
#define HW 196
#define DEMO_T 4
#define OBS_T 12
#define DPOS 784      // DEMO_T*HW
#define OPOS 2352     // OBS_T*HW
#define XROW 3136     // TT*HW
#define NHEADS 8
#define CH 32
#define INV_TEMP 0.0625f
#define NPOS 980      // DPOS + HW (cat keys per (b,t,n))

typedef float  f32x4 __attribute__((ext_vector_type(4)));
typedef short  s8v   __attribute__((ext_vector_type(8)));
typedef short  s4v   __attribute__((ext_vector_type(4)));

static __device__ __forceinline__ ushort f2bf(float f) {
    union { float f; uint u; } x; x.f = f;
    const uint r = x.u + 0x7FFF + ((x.u >> 16) & 1);   // RNE
    return (ushort)(r >> 16);
}

static __device__ __forceinline__ f32x4 mfma_pv(s4v a, s4v b, f32x4 c) {
#if __has_builtin(__builtin_amdgcn_mfma_f32_16x16x16bf16_1k)
    return __builtin_amdgcn_mfma_f32_16x16x16bf16_1k(a, b, c, 0, 0, 0);
#else
    // zero-padded fallback: k is a dummy index; both operands agree.
    s8v a8 = {a[0], a[1], a[2], a[3], 0, 0, 0, 0};
    s8v b8 = {b[0], b[1], b[2], b[3], 0, 0, 0, 0};
    return __builtin_amdgcn_mfma_f32_16x16x32_bf16(a8, b8, c, 0, 0, 0);
#endif
}

// ---------------------------------------------------------------------------
// Tiled fp32 GEMM: O[b][f][p] = sum_c W[f][c] * X[b][c][xBase + p]
// ---------------------------------------------------------------------------
__global__ __launch_bounds__(256) void proj_gemm(
    const float* __restrict__ X, int xRowStride, int xBase, int ncols,
    const float* __restrict__ W0, const float* __restrict__ W1, const float* __restrict__ W2,
    float* __restrict__ O0, float* __restrict__ O1, float* __restrict__ O2)
{
    const int ptiles = (ncols + 63) >> 6;
    const int b  = blockIdx.x / ptiles;
    const int pt = blockIdx.x % ptiles;
    const int fbase = blockIdx.y * 64;
    const int pbase = pt * 64;
    const float* W = (blockIdx.z == 0) ? W0 : (blockIdx.z == 1) ? W1 : W2;
    float*       O = (blockIdx.z == 0) ? O0 : (blockIdx.z == 1) ? O1 : O2;

    const int tid = threadIdx.x;
    const int tx = tid & 15, ty = tid >> 4;

    __shared__ float WtT[16][68];   // [c][f]
    __shared__ float Xt[16][68];    // [c][p]

    float acc[4][4] = {};
    const float* Xb = X + (size_t)b * CC * xRowStride + xBase;
    const bool fullp = (pbase + 64 <= ncols);

    for (int c0 = 0; c0 < CC; c0 += 16) {
        {
            int fi = tid >> 2, ci4 = (tid & 3) * 4;
            const float4 wv = *reinterpret_cast<const float4*>(&W[(size_t)(fbase + fi) * CC + c0 + ci4]);
            WtT[ci4+0][fi] = wv.x; WtT[ci4+1][fi] = wv.y;
            WtT[ci4+2][fi] = wv.z; WtT[ci4+3][fi] = wv.w;
        }
        {
            int ci = tid >> 4, pj = (tid & 15) * 4;
            const float* src = Xb + (size_t)(c0 + ci) * xRowStride + pbase + pj;
            if (fullp) {
                const float4 xv = *reinterpret_cast<const float4*>(src);
                Xt[ci][pj]   = xv.x; Xt[ci][pj+1] = xv.y;
                Xt[ci][pj+2] = xv.z; Xt[ci][pj+3] = xv.w;
            } else {
                #pragma unroll
                for (int u = 0; u < 4; u++)
                    Xt[ci][pj+u] = (pbase + pj + u < ncols) ? src[u] : 0.f;
            }
        }
        __syncthreads();
        #pragma unroll
        for (int ci = 0; ci < 16; ci++) {
            const float4 wv4 = *reinterpret_cast<const float4*>(&WtT[ci][ty*4]);
            const float4 xv4 = *reinterpret_cast<const float4*>(&Xt[ci][tx*4]);
            const float wv[4] = {wv4.x, wv4.y, wv4.z, wv4.w};
            const float xv[4] = {xv4.x, xv4.y, xv4.z, xv4.w};
            #pragma unroll
            for (int i = 0; i < 4; i++)
                #pragma unroll
                for (int j = 0; j < 4; j++) acc[i][j] += wv[i] * xv[j];
        }
        __syncthreads();
    }
    #pragma unroll
    for (int i = 0; i < 4; i++) {
        const int f = fbase + ty*4 + i;
        float* dst = O + ((size_t)b * CC + f) * ncols + pbase + tx*4;
        #pragma unroll
        for (int j = 0; j < 4; j++) {
            if (pbase + tx*4 + j < ncols) dst[j] = acc[i][j];
        }
    }
}

// ---------------------------------------------------------------------------
// Demo attention (flash-style, softmax over the dq axis j) — unchanged.
// ---------------------------------------------------------------------------
__global__ __launch_bounds__(256) void demo_attn(
    const float* __restrict__ dq, const float* __restrict__ dk,
    const float* __restrict__ dv, float* __restrict__ dvatt)
{
    const int itile = blockIdx.x, n = blockIdx.y, b = blockIdx.z;
    const int ibase = itile * 32;
    const float* Kp = dk + ((size_t)b*CC + n*CH) * DPOS;
    const float* Qp = dq + ((size_t)b*CC + n*CH) * DPOS;
    const float* Vp = dv + ((size_t)b*CC + n*CH) * DPOS;

    __shared__ float Kt[32][33];
    __shared__ float Qt[32][113];
    __shared__ float Vt[32][113];
    __shared__ float St[32][113];
    __shared__ float red[32][9];
    __shared__ float m_s[32], l_s[32], scale_s[32];

    const int tid = threadIdx.x;
    const int il = tid & 31, cg = tid >> 5;

    for (int idx = tid; idx < 32*32; idx += 256) {
        int c = idx >> 5, ii = idx & 31;
        Kt[c][ii] = (ibase + ii < DPOS) ? Kp[c*DPOS + ibase + ii] : 0.f;
    }
    if (tid < 32) { m_s[tid] = -1e30f; l_s[tid] = 0.f; }
    float acc[4] = {0.f, 0.f, 0.f, 0.f};
    __syncthreads();

    for (int jt = 0; jt < DPOS; jt += 112) {
        for (int idx = tid; idx < 32*112; idx += 256) {
            int c = idx / 112, j = idx % 112;
            Qt[c][j] = Qp[c*DPOS + jt + j];
            Vt[c][j] = Vp[c*DPOS + jt + j];
        }
        __syncthreads();

        float svals[14];
        float pmax = -1e30f;
        #pragma unroll
        for (int k = 0; k < 14; k++) {
            const int j = cg + 8*k;
            float s = 0.f;
            #pragma unroll
            for (int c = 0; c < 32; c++) s += Kt[c][il] * Qt[c][j];
            s *= INV_TEMP;
            svals[k] = s;
            pmax = fmaxf(pmax, s);
        }
        red[il][cg] = pmax;
        __syncthreads();
        if (tid < 32) {
            float mt = red[tid][0];
            #pragma unroll
            for (int g = 1; g < 8; g++) mt = fmaxf(mt, red[tid][g]);
            const float mold = m_s[tid];
            const float mnew = fmaxf(mold, mt);
            scale_s[tid] = __expf(mold - mnew);
            m_s[tid] = mnew;
        }
        __syncthreads();
        const float mnew = m_s[il], scale = scale_s[il];
        float psum = 0.f;
        #pragma unroll
        for (int k = 0; k < 14; k++) {
            const float p = __expf(svals[k] - mnew);
            St[il][cg + 8*k] = p;
            psum += p;
        }
        red[il][cg] = psum;
        #pragma unroll
        for (int cc = 0; cc < 4; cc++) acc[cc] *= scale;
        __syncthreads();
        if (tid < 32) {
            float s = 0.f;
            #pragma unroll
            for (int g = 0; g < 8; g++) s += red[tid][g];
            l_s[tid] = l_s[tid] * scale_s[tid] + s;
        }
        for (int j = 0; j < 112; j++) {
            const float p = St[il][j];
            #pragma unroll
            for (int cc = 0; cc < 4; cc++) acc[cc] += p * Vt[cg*4+cc][j];
        }
        __syncthreads();
    }
    if (ibase + il < DPOS) {
        const float linv = 1.f / l_s[il];
        #pragma unroll
        for (int cc = 0; cc < 4; cc++)
            dvatt[((size_t)b*CC + n*CH + cg*4 + cc) * DPOS + ibase + il] = acc[cc] * linv;
    }
}

// ---------------------------------------------------------------------------
// pack_T: fp32 [b][256][P] -> bf16 [b][8][P][32]  (per-head transpose)
// ---------------------------------------------------------------------------
__global__ __launch_bounds__(256) void pack_T(
    const float* __restrict__ src, ushort* __restrict__ dst, int P)
{
    const int hn = blockIdx.y, bb = blockIdx.z;
    const int p0 = blockIdx.x * 64;
    __shared__ float L[32][73];
    const int tid = threadIdx.x;
    {
        const int c = tid >> 3, sg = tid & 7;
        const int p = p0 + sg*8;
        const float* s = src + ((size_t)bb*CC + hn*CH + c) * P + p;
        float4 a = {0,0,0,0}, b2 = {0,0,0,0};
        if (p < P) { a = *reinterpret_cast<const float4*>(s);
                     b2 = *reinterpret_cast<const float4*>(s + 4); }
        L[c][sg*8+0]=a.x;  L[c][sg*8+1]=a.y;  L[c][sg*8+2]=a.z;  L[c][sg*8+3]=a.w;
        L[c][sg*8+4]=b2.x; L[c][sg*8+5]=b2.y; L[c][sg*8+6]=b2.z; L[c][sg*8+7]=b2.w;
    }
    __syncthreads();
    {
        const int pl = tid >> 2, cs = (tid & 3) * 8;
        if (p0 + pl < P) {
            ushort o[8];
            #pragma unroll
            for (int j = 0; j < 8; j++) o[j] = f2bf(L[cs+j][pl]);
            uint4 v;
            v.x = o[0] | ((uint)o[1]<<16); v.y = o[2] | ((uint)o[3]<<16);
            v.z = o[4] | ((uint)o[5]<<16); v.w = o[6] | ((uint)o[7]<<16);
            *reinterpret_cast<uint4*>(dst + (((size_t)bb*NHEADS + hn)*P + p0 + pl)*32 + cs) = v;
        }
    }
}

// ---------------------------------------------------------------------------
// pack_cvt: flat fp32 -> bf16 (n4 = count/4)
// ---------------------------------------------------------------------------
__global__ __launch_bounds__(256) void pack_cvt(
    const float* __restrict__ src, ushort* __restrict__ dst, int n4)
{
    for (size_t i = (size_t)blockIdx.x * 256 + threadIdx.x; i < (size_t)n4;
         i += (size_t)gridDim.x * 256) {
        const float4 v = *reinterpret_cast<const float4*>(src + i*4);
        uint2 o;
        o.x = f2bf(v.x) | ((uint)f2bf(v.y) << 16);
        o.y = f2bf(v.z) | ((uint)f2bf(v.w) << 16);
        *reinterpret_cast<uint2*>(dst + i*4) = o;
    }
}

// ---------------------------------------------------------------------------
// Obs attention per (b, t, n) — bf16 MFMA.
//   S[p,q] = K[:,p].Q[:,q]/16 via mfma 16x16x32 (K-dim = c = 32)
//   softmax over q per p-row, fully in registers (shfl over lane&15)
//   O[c,q] += V[c,p] P[p,q] via mfma 16x16x16 (K-dim = p), P already in
//   B-fragment layout.
// p padded to 1024 = 16 chunks of 64 (wave w owns 16 rows per chunk).
// LDS: QT[208][40] + KT[64][40] + VT[32][72] bf16, overlapped with
// Ored[32][212] f32 for the final cross-wave O reduction.
// ---------------------------------------------------------------------------
__global__ __launch_bounds__(256) void obs_attn_mfma(
    const ushort* __restrict__ KdP, const ushort* __restrict__ KoP,
    const ushort* __restrict__ QP,  const ushort* __restrict__ VdP,
    const ushort* __restrict__ VoP, float* __restrict__ merged)
{
    const int tt = blockIdx.x, hn = blockIdx.y, bb = blockIdx.z;
    __shared__ __align__(16) ushort smem_u[13568];   // 27136 B
    ushort* QT = smem_u;            // [208][40]
    ushort* KT = smem_u + 8320;     // [64][40]
    ushort* VT = smem_u + 10880;    // [32][72]

    const int tid  = threadIdx.x;
    const int lane = tid & 63, w = tid >> 6;
    const int l15  = lane & 15, grp = lane >> 4;

    const size_t kdBase = ((size_t)bb*NHEADS + hn) * DPOS * 32;
    const size_t koBase = ((size_t)bb*NHEADS + hn) * OPOS * 32 + (size_t)tt*HW*32;
    const size_t vdRow0 = ((size_t)bb*CC + hn*CH) * DPOS;
    const size_t voRow0 = ((size_t)bb*CC + hn*CH) * OPOS + (size_t)tt*HW;

    auto fetchK = [&](int cp) -> uint4 {
        const int r = tid >> 2, sg = tid & 3;
        const int p = cp + r;
        uint4 v = {0,0,0,0};
        if (p < DPOS)      v = *reinterpret_cast<const uint4*>(KdP + kdBase + (size_t)p*32 + sg*8);
        else if (p < NPOS) v = *reinterpret_cast<const uint4*>(KoP + koBase + (size_t)(p-DPOS)*32 + sg*8);
        return v;
    };
    auto writeK = [&](uint4 v) {
        const int r = tid >> 2, sg = tid & 3;
        *reinterpret_cast<uint4*>(&KT[r*40 + sg*8]) = v;
    };
    auto fetchV = [&](int cp) -> uint4 {
        const int c = tid >> 3, sg = tid & 7;
        const int p0 = cp + sg*8;
        uint4 v = {0,0,0,0};
        const size_t vd = vdRow0 + (size_t)c*DPOS;
        const size_t vo = voRow0 + (size_t)c*OPOS;
        if (p0 + 7 < DPOS) {
            uint2 a  = *reinterpret_cast<const uint2*>(VdP + vd + p0);
            uint2 b2 = *reinterpret_cast<const uint2*>(VdP + vd + p0 + 4);
            v.x=a.x; v.y=a.y; v.z=b2.x; v.w=b2.y;
        } else if (p0 >= DPOS && p0 + 7 < NPOS) {
            uint2 a  = *reinterpret_cast<const uint2*>(VoP + vo + (p0-DPOS));
            uint2 b2 = *reinterpret_cast<const uint2*>(VoP + vo + (p0-DPOS) + 4);
            v.x=a.x; v.y=a.y; v.z=b2.x; v.w=b2.y;
        } else if (p0 < NPOS) {
            ushort e[8];
            #pragma unroll
            for (int j = 0; j < 8; j++) {
                const int p = p0 + j;
                e[j] = (p < DPOS) ? VdP[vd + p]
                     : (p < NPOS ? VoP[vo + (p-DPOS)] : (ushort)0);
            }
            v.x = e[0] | ((uint)e[1] << 16); v.y = e[2] | ((uint)e[3] << 16);
            v.z = e[4] | ((uint)e[5] << 16); v.w = e[6] | ((uint)e[7] << 16);
        }
        return v;
    };
    auto writeV = [&](uint4 v) {
        const int c = tid >> 3, sg = tid & 7;
        *reinterpret_cast<uint4*>(&VT[c*72 + sg*8]) = v;
    };

    // stage Q (rows >= 196 zero)
    for (int idx = tid; idx < 832; idx += 256) {
        const int r = idx >> 2, sg = idx & 3;
        uint4 v = {0,0,0,0};
        if (r < HW) v = *reinterpret_cast<const uint4*>(QP + koBase + (size_t)r*32 + sg*8);
        *reinterpret_cast<uint4*>(&QT[r*40 + sg*8]) = v;
    }
    writeK(fetchK(0));
    writeV(fetchV(0));

    f32x4 accO[2][13];
    #pragma unroll
    for (int ct = 0; ct < 2; ++ct)
        #pragma unroll
        for (int qt = 0; qt < 13; ++qt)
            accO[ct][qt] = (f32x4){0.f, 0.f, 0.f, 0.f};
    __syncthreads();

    for (int ch = 0; ch < 16; ++ch) {
        uint4 nk = {0,0,0,0}, nv = {0,0,0,0};
        if (ch < 15) { nk = fetchK((ch+1)*64); nv = fetchV((ch+1)*64); }

        // ---- S: 13 q-tiles via mfma 16x16x32 (A: K rows, B: Q cols) ----
        const s8v aK = *reinterpret_cast<const s8v*>(&KT[(w*16 + l15)*40 + grp*8]);
        f32x4 ss[13];
        #pragma unroll
        for (int qt = 0; qt < 13; ++qt) {
            const s8v bQ = *reinterpret_cast<const s8v*>(&QT[(qt*16 + l15)*40 + grp*8]);
            const f32x4 z = {0.f, 0.f, 0.f, 0.f};
            ss[qt] = __builtin_amdgcn_mfma_f32_16x16x32_bf16(aK, bQ, z, 0, 0, 0);
        }
        // ---- softmax over q per p-row (lane holds q=l15, p=grp*4+r) ----
        #pragma unroll
        for (int r = 0; r < 4; ++r) {
            float m = -1e30f;
            #pragma unroll
            for (int qt = 0; qt < 13; ++qt) {
                float v = ss[qt][r] * INV_TEMP;
                if (qt == 12 && l15 >= 4) v = -1e30f;   // q >= 196 pad
                ss[qt][r] = v;
                m = fmaxf(m, v);
            }
            m = fmaxf(m, __shfl_xor(m, 1));
            m = fmaxf(m, __shfl_xor(m, 2));
            m = fmaxf(m, __shfl_xor(m, 4));
            m = fmaxf(m, __shfl_xor(m, 8));
            float sum = 0.f;
            #pragma unroll
            for (int qt = 0; qt < 13; ++qt) {
                const float e = __expf(ss[qt][r] - m);
                ss[qt][r] = e;
                sum += e;
            }
            sum += __shfl_xor(sum, 1);
            sum += __shfl_xor(sum, 2);
            sum += __shfl_xor(sum, 4);
            sum += __shfl_xor(sum, 8);
            const float is = 1.f / sum;
            #pragma unroll
            for (int qt = 0; qt < 13; ++qt) ss[qt][r] *= is;
        }
        // ---- pack P: registers ARE the 16x16x16 B-fragment ----
        s4v pf[13];
        #pragma unroll
        for (int qt = 0; qt < 13; ++qt) {
            s4v p4;
            #pragma unroll
            for (int r = 0; r < 4; ++r) p4[r] = (short)f2bf(ss[qt][r]);
            pf[qt] = p4;
        }
        // ---- PV: O[c][q] += V[c][p] P[p][q], K-dim = this wave's 16 p ----
        #pragma unroll
        for (int ct = 0; ct < 2; ++ct) {
            const s4v aV = *reinterpret_cast<const s4v*>(
                &VT[(ct*16 + l15)*72 + w*16 + grp*4]);
            #pragma unroll
            for (int qt = 0; qt < 13; ++qt)
                accO[ct][qt] = mfma_pv(aV, pf[qt], accO[ct][qt]);
        }
        __syncthreads();
        if (ch < 15) { writeK(nk); writeV(nv); __syncthreads(); }
    }

    // ---- cross-wave O reduction in LDS (overlaps staging buffers) ----
    float* Ored = reinterpret_cast<float*>(smem_u);   // [32][212]
    for (int wv = 0; wv < 4; ++wv) {
        if (w == wv) {
            #pragma unroll
            for (int ct = 0; ct < 2; ++ct)
                #pragma unroll
                for (int qt = 0; qt < 13; ++qt)
                    #pragma unroll
                    for (int r = 0; r < 4; ++r) {
                        const int c = ct*16 + grp*4 + r;
                        const int q = qt*16 + l15;
                        if (wv == 0) Ored[c*212 + q]  = accO[ct][qt][r];
                        else         Ored[c*212 + q] += accO[ct][qt][r];
                    }
        }
        __syncthreads();
    }
    for (int idx = tid; idx < 32*49; idx += 256) {
        const int c = idx / 49, q0 = (idx % 49) * 4;
        const float4 v = *reinterpret_cast<const float4*>(&Ored[c*212 + q0]);
        *reinterpret_cast<float4*>(
            merged + ((size_t)bb*CC + hn*CH + c)*OPOS + (size_t)tt*HW + q0) = v;
    }
}

// ---------------------------------------------------------------------------
// Fused residual-ReLU + concat + BatchNorm. One block per channel.
// ---------------------------------------------------------------------------
__global__ __launch_bounds__(256) void bn_fuse(
    const float* __restrict__ xin, const float* __restrict__ obsout,
    const float* __restrict__ gamma, const float* __restrict__ beta,
    float* __restrict__ xout)
{
    const int c = blockIdx.x;
    const int tid = threadIdx.x;
    float sum = 0.f, sumsq = 0.f;
    for (int idx = tid; idx < BB*DPOS; idx += 256) {
        int b = idx / DPOS, pos = idx % DPOS;
        float v = xin[((size_t)b*CC + c) * XROW + pos];
        sum += v; sumsq += v * v;
    }
    for (int idx = tid; idx < BB*OPOS; idx += 256) {
        int b = idx / OPOS, pos = idx % OPOS;
        float v = xin[((size_t)b*CC + c) * XROW + DPOS + pos]
                + fmaxf(obsout[((size_t)b*CC + c) * OPOS + pos], 0.f);
        sum += v; sumsq += v * v;
    }
    #pragma unroll
    for (int off = 32; off > 0; off >>= 1) {
        sum   += __shfl_xor(sum, off);
        sumsq += __shfl_xor(sumsq, off);
    }
    __shared__ float ssum[4], ssq[4];
    __shared__ float s_mean, s_inv;
    const int lane = tid & 63, w = tid >> 6;
    if (lane == 0) { ssum[w] = sum; ssq[w] = sumsq; }
    __syncthreads();
    if (tid == 0) {
        float s  = ssum[0] + ssum[1] + ssum[2] + ssum[3];
        float sq = ssq[0] + ssq[1] + ssq[2] + ssq[3];
        const float mean = s / 12544.f;
        const float var  = sq / 12544.f - mean * mean;
        s_mean = mean;
        s_inv  = rsqrtf(var + 1e-5f);
    }
    __syncthreads();
    const float mean = s_mean;
    const float gi = gamma[c] * s_inv;
    const float bt = beta[c];
    for (int idx = tid; idx < BB*DPOS; idx += 256) {
        int b = idx / DPOS, pos = idx % DPOS;
        size_t o = ((size_t)b*CC + c) * XROW + pos;
        xout[o] = (xin[o] - mean) * gi + bt;
    }
    for (int idx = tid; idx < BB*OPOS; idx += 256) {
        int b = idx / OPOS, pos = idx % OPOS;
        float v = xin[((size_t)b*CC + c) * XROW + DPOS + pos]
                + fmaxf(obsout[((size_t)b*CC + c) * OPOS + pos], 0.f);
        xout[((size_t)b*CC + c) * XROW + DPOS + pos] = (v - mean) * gi + bt;
    }
}

// ---------------------------------------------------------------------------
extern "C" void kernel_launch(void* const* d_in, const int* in_sizes, int n_in,
                              void* d_out, int out_size, void* d_ws, size_t ws_size,
                              hipStream_t stream)
{
    const float* x   = (const float*)d_in[0];
    const float* dqw = (const float*)d_in[1];
    const float* dkw = (const float*)d_in[2];
    const float* dvw = (const float*)d_in[3];
    const float* oqw = (const float*)d_in[4];
    const float* okw = (const float*)d_in[5];
    const float* ovw = (const float*)d_in[6];
    const float* oow = (const float*)d_in[7];
    const float* gam = (const float*)d_in[8];
    const float* bet = (const float*)d_in[9];

    const size_t XN = (size_t)BB * CC * TT * HW;   // 3,211,264
    const size_t DN = (size_t)BB * CC * DPOS;      //   802,816
    const size_t ON = (size_t)BB * CC * OPOS;      // 2,408,448

    float* ws     = (float*)d_ws;
    float* xb0    = ws;
    float* xb1    = xb0 + XN;
    float* dq     = xb1 + XN;
    float* dk     = dq + DN;
    float* dv     = dk + DN;
    float* oq     = dv + DN;
    float* okb    = oq + ON;
    float* ovb    = okb + ON;
    float* dvatt  = ovb + ON;
    float* merged = dvatt + DN;
    float* obsout = merged + ON;

    // bf16 packs aliased onto dead fp32 buffers (lifetimes verified):
    ushort* KdP = (ushort*)dq;       // dq dead after demo_attn
    ushort* VdP = (ushort*)dv;       // dv dead after demo_attn
    ushort* KoP = (ushort*)obsout;   // obsout dead until out-proj
    ushort* QP  = (ushort*)okb;      // okb dead after KoP pack
    ushort* VoP = (ushort*)oq;       // oq dead after QP pack

    const dim3 blk(256);
    for (int i = 0; i < 3; i++) {
        const float* xin  = (i == 0) ? x : (i == 1 ? xb0 : xb1);
        float*       xout = (i == 2) ? (float*)d_out : (i == 0 ? xb0 : xb1);
        const size_t wOff = (size_t)i * CC * CC;

        proj_gemm<<<dim3(BB*13, 4, 3), blk, 0, stream>>>(
            xin, XROW, 0, DPOS, dqw + wOff, dkw + wOff, dvw + wOff, dq, dk, dv);
        proj_gemm<<<dim3(BB*37, 4, 3), blk, 0, stream>>>(
            xin, XROW, DPOS, OPOS, oqw + wOff, okw + wOff, ovw + wOff, oq, okb, ovb);
        demo_attn<<<dim3(25, NHEADS, BB), blk, 0, stream>>>(dq, dk, dv, dvatt);

        // packs (order matters for aliasing: KoP reads okb before QP overwrites it,
        // QP reads oq before VoP overwrites it)
        pack_T<<<dim3(13, NHEADS, BB), blk, 0, stream>>>(dk,  KdP, DPOS);
        pack_T<<<dim3(37, NHEADS, BB), blk, 0, stream>>>(okb, KoP, OPOS);
        pack_T<<<dim3(37, NHEADS, BB), blk, 0, stream>>>(oq,  QP,  OPOS);
        pack_cvt<<<dim3(784),  blk, 0, stream>>>(dvatt, VdP, (int)(DN/4));
        pack_cvt<<<dim3(1024), blk, 0, stream>>>(ovb,   VoP, (int)(ON/4));

        obs_attn_mfma<<<dim3(OBS_T, NHEADS, BB), blk, 0, stream>>>(
            KdP, KoP, QP, VdP, VoP, merged);

        proj_gemm<<<dim3(BB*37, 4, 1), blk, 0, stream>>>(
            merged, OPOS, 0, OPOS, oow + wOff, oow + wOff, oow + wOff, obsout, obsout, obsout);
        bn_fuse<<<dim3(CC), blk, 0, stream>>>(xin, obsout, gam + i*CC, bet + i*CC, xout);
    }
}

// Round 4
// 884.462 us; speedup vs baseline: 4.3152x; 1.4328x over previous
//
#include <hip/hip_runtime.h>
#include <hip/hip_bf16.h>

// Problem constants
#define BB 4
#define CC 256
#define TT 16
#define HW 196
#define DEMO_T 4
#define OBS_T 12
#define DPOS 784      // DEMO_T*HW
#define OPOS 2352     // OBS_T*HW
#define XROW 3136     // TT*HW
#define NHEADS 8
#define CH 32
#define INV_TEMP 0.0625f
#define NPOS 980      // DPOS + HW (cat keys per (b,t,n))

typedef float  f32x4 __attribute__((ext_vector_type(4)));
typedef short  s8v   __attribute__((ext_vector_type(8)));
typedef short  s4v   __attribute__((ext_vector_type(4)));

static __device__ __forceinline__ ushort f2bf(float f) {
    union { float f; uint u; } x; x.f = f;
    const uint r = x.u + 0x7FFF + ((x.u >> 16) & 1);   // RNE
    return (ushort)(r >> 16);
}

static __device__ __forceinline__ f32x4 mfma_pv(s4v a, s4v b, f32x4 c) {
#if __has_builtin(__builtin_amdgcn_mfma_f32_16x16x16bf16_1k)
    return __builtin_amdgcn_mfma_f32_16x16x16bf16_1k(a, b, c, 0, 0, 0);
#else
    s8v a8 = {a[0], a[1], a[2], a[3], 0, 0, 0, 0};
    s8v b8 = {b[0], b[1], b[2], b[3], 0, 0, 0, 0};
    return __builtin_amdgcn_mfma_f32_16x16x32_bf16(a8, b8, c, 0, 0, 0);
#endif
}

// ---------------------------------------------------------------------------
// Tiled fp32 GEMM: O[b][f][p] = sum_c W[f][c] * X[b][c][xBase + p]
// ---------------------------------------------------------------------------
__global__ __launch_bounds__(256) void proj_gemm(
    const float* __restrict__ X, int xRowStride, int xBase, int ncols,
    const float* __restrict__ W0, const float* __restrict__ W1, const float* __restrict__ W2,
    float* __restrict__ O0, float* __restrict__ O1, float* __restrict__ O2)
{
    const int ptiles = (ncols + 63) >> 6;
    const int b  = blockIdx.x / ptiles;
    const int pt = blockIdx.x % ptiles;
    const int fbase = blockIdx.y * 64;
    const int pbase = pt * 64;
    const float* W = (blockIdx.z == 0) ? W0 : (blockIdx.z == 1) ? W1 : W2;
    float*       O = (blockIdx.z == 0) ? O0 : (blockIdx.z == 1) ? O1 : O2;

    const int tid = threadIdx.x;
    const int tx = tid & 15, ty = tid >> 4;

    __shared__ float WtT[16][68];   // [c][f]
    __shared__ float Xt[16][68];    // [c][p]

    float acc[4][4] = {};
    const float* Xb = X + (size_t)b * CC * xRowStride + xBase;
    const bool fullp = (pbase + 64 <= ncols);

    for (int c0 = 0; c0 < CC; c0 += 16) {
        {
            int fi = tid >> 2, ci4 = (tid & 3) * 4;
            const float4 wv = *reinterpret_cast<const float4*>(&W[(size_t)(fbase + fi) * CC + c0 + ci4]);
            WtT[ci4+0][fi] = wv.x; WtT[ci4+1][fi] = wv.y;
            WtT[ci4+2][fi] = wv.z; WtT[ci4+3][fi] = wv.w;
        }
        {
            int ci = tid >> 4, pj = (tid & 15) * 4;
            const float* src = Xb + (size_t)(c0 + ci) * xRowStride + pbase + pj;
            if (fullp) {
                const float4 xv = *reinterpret_cast<const float4*>(src);
                Xt[ci][pj]   = xv.x; Xt[ci][pj+1] = xv.y;
                Xt[ci][pj+2] = xv.z; Xt[ci][pj+3] = xv.w;
            } else {
                #pragma unroll
                for (int u = 0; u < 4; u++)
                    Xt[ci][pj+u] = (pbase + pj + u < ncols) ? src[u] : 0.f;
            }
        }
        __syncthreads();
        #pragma unroll
        for (int ci = 0; ci < 16; ci++) {
            const float4 wv4 = *reinterpret_cast<const float4*>(&WtT[ci][ty*4]);
            const float4 xv4 = *reinterpret_cast<const float4*>(&Xt[ci][tx*4]);
            const float wv[4] = {wv4.x, wv4.y, wv4.z, wv4.w};
            const float xv[4] = {xv4.x, xv4.y, xv4.z, xv4.w};
            #pragma unroll
            for (int i = 0; i < 4; i++)
                #pragma unroll
                for (int j = 0; j < 4; j++) acc[i][j] += wv[i] * xv[j];
        }
        __syncthreads();
    }
    #pragma unroll
    for (int i = 0; i < 4; i++) {
        const int f = fbase + ty*4 + i;
        float* dst = O + ((size_t)b * CC + f) * ncols + pbase + tx*4;
        #pragma unroll
        for (int j = 0; j < 4; j++) {
            if (pbase + tx*4 + j < ncols) dst[j] = acc[i][j];
        }
    }
}

// ---------------------------------------------------------------------------
// pack_T: fp32 [b][256][P] -> bf16 [b][8][P][32]  (per-head transpose)
// ---------------------------------------------------------------------------
__global__ __launch_bounds__(256) void pack_T(
    const float* __restrict__ src, ushort* __restrict__ dst, int P)
{
    const int hn = blockIdx.y, bb = blockIdx.z;
    const int p0 = blockIdx.x * 64;
    __shared__ float L[32][73];
    const int tid = threadIdx.x;
    {
        const int c = tid >> 3, sg = tid & 7;
        const int p = p0 + sg*8;
        const float* s = src + ((size_t)bb*CC + hn*CH + c) * P + p;
        float4 a = {0,0,0,0}, b2 = {0,0,0,0};
        if (p < P) { a = *reinterpret_cast<const float4*>(s);
                     b2 = *reinterpret_cast<const float4*>(s + 4); }
        L[c][sg*8+0]=a.x;  L[c][sg*8+1]=a.y;  L[c][sg*8+2]=a.z;  L[c][sg*8+3]=a.w;
        L[c][sg*8+4]=b2.x; L[c][sg*8+5]=b2.y; L[c][sg*8+6]=b2.z; L[c][sg*8+7]=b2.w;
    }
    __syncthreads();
    {
        const int pl = tid >> 2, cs = (tid & 3) * 8;
        if (p0 + pl < P) {
            ushort o[8];
            #pragma unroll
            for (int j = 0; j < 8; j++) o[j] = f2bf(L[cs+j][pl]);
            uint4 v;
            v.x = o[0] | ((uint)o[1]<<16); v.y = o[2] | ((uint)o[3]<<16);
            v.z = o[4] | ((uint)o[5]<<16); v.w = o[6] | ((uint)o[7]<<16);
            *reinterpret_cast<uint4*>(dst + (((size_t)bb*NHEADS + hn)*P + p0 + pl)*32 + cs) = v;
        }
    }
}

// ---------------------------------------------------------------------------
// pack_cvt: flat fp32 -> bf16 (n4 = count/4)
// ---------------------------------------------------------------------------
__global__ __launch_bounds__(256) void pack_cvt(
    const float* __restrict__ src, ushort* __restrict__ dst, int n4)
{
    for (size_t i = (size_t)blockIdx.x * 256 + threadIdx.x; i < (size_t)n4;
         i += (size_t)gridDim.x * 256) {
        const float4 v = *reinterpret_cast<const float4*>(src + i*4);
        uint2 o;
        o.x = f2bf(v.x) | ((uint)f2bf(v.y) << 16);
        o.y = f2bf(v.z) | ((uint)f2bf(v.w) << 16);
        *reinterpret_cast<uint2*>(dst + i*4) = o;
    }
}

// ---------------------------------------------------------------------------
// Demo attention — bf16 MFMA, flash-style over j (softmax axis).
//   S'[j,i] = sum_c Q[c,j] K[c,i] / 16   (A = Q^T rows j, B = K^T cols i)
//   attn = softmax over j (online, across 13 chunks of 64)
//   O[c,i] = sum_j V[c,j] P[j,i]  (A = V natural rows c, B = P registers)
// C-layout of S': col=i=lane&15, row=j=(lane>>4)*4+r -> softmax over j is an
// in-lane (4 regs x 4 tiles) + shfl_xor(16,32) reduce; P regs are directly
// the 16x16x16 PV B-fragment. Output written as bf16 [b][256][784] (dvattP),
// which is exactly obs_attn's V-demo input layout.
// Grid (13 i-chunks of 64, HEADS, B); wave w owns i-tile ib*64+w*16.
// ---------------------------------------------------------------------------
__global__ __launch_bounds__(256) void demo_attn_mfma(
    const ushort* __restrict__ QdP, const ushort* __restrict__ KdP,
    const ushort* __restrict__ VdP, ushort* __restrict__ dvattP)
{
    const int ib = blockIdx.x, hn = blockIdx.y, bb = blockIdx.z;
    const int tid = threadIdx.x, lane = tid & 63, w = tid >> 6;
    const int l15 = lane & 15, grp = lane >> 4;

    __shared__ __align__(16) ushort Qc[64][40];   // j-chunk, [j][c]
    __shared__ __align__(16) ushort Vc[32][72];   // j-chunk, [c][j]

    const size_t hBase = ((size_t)bb*NHEADS + hn) * DPOS;   // pack row base
    const size_t vRow0 = ((size_t)bb*CC + hn*CH) * DPOS;    // natural rows

    // B fragment (K^T[i][c]): lane n=i=l15, k=c=grp*8..+7. One global read,
    // fully coalesced (16 rows x 64B contiguous). i>=784 reads garbage ->
    // columns discarded at the write guard.
    const int i_glob = ib*64 + w*16 + l15;
    const s8v bK = *reinterpret_cast<const s8v*>(KdP + (hBase + i_glob)*32 + grp*8);

    auto fetchQ = [&](int j0) -> uint4 {
        const int r = tid >> 2, sg = tid & 3;
        return *reinterpret_cast<const uint4*>(QdP + (hBase + j0 + r)*32 + sg*8);
    };
    auto writeQ = [&](uint4 v) {
        const int r = tid >> 2, sg = tid & 3;
        *reinterpret_cast<uint4*>(&Qc[r][sg*8]) = v;
    };
    auto fetchV = [&](int j0) -> uint4 {
        const int c = tid >> 3, sg = tid & 7;
        return *reinterpret_cast<const uint4*>(VdP + vRow0 + (size_t)c*DPOS + j0 + sg*8);
    };
    auto writeV = [&](uint4 v) {
        const int c = tid >> 3, sg = tid & 7;
        *reinterpret_cast<uint4*>(&Vc[c][sg*8]) = v;
    };

    writeQ(fetchQ(0));
    writeV(fetchV(0));
    f32x4 accO[2] = {{0.f,0.f,0.f,0.f}, {0.f,0.f,0.f,0.f}};
    float m_run = -1e30f, l_run = 0.f;
    __syncthreads();

    // 784 = 12 chunks of 64 + 1 chunk of 16 -> last chunk has exactly 1 tile.
    for (int ch = 0; ch < 13; ++ch) {
        uint4 nQ, nV;
        if (ch < 12) { nQ = fetchQ((ch+1)*64); nV = fetchV((ch+1)*64); }
        const int nt = (ch == 12) ? 1 : 4;

        // S' tiles
        f32x4 st[4];
        #pragma unroll 4
        for (int jt = 0; jt < nt; ++jt) {
            const s8v aQ = *reinterpret_cast<const s8v*>(&Qc[jt*16 + l15][grp*8]);
            const f32x4 z = {0.f,0.f,0.f,0.f};
            st[jt] = __builtin_amdgcn_mfma_f32_16x16x32_bf16(aQ, bK, z, 0, 0, 0);
        }
        // online softmax over j (in-lane regs + shfl over grp bits)
        float mloc = -1e30f;
        #pragma unroll 4
        for (int jt = 0; jt < nt; ++jt)
            #pragma unroll
            for (int r = 0; r < 4; ++r) {
                const float v = st[jt][r] * INV_TEMP;
                st[jt][r] = v;
                mloc = fmaxf(mloc, v);
            }
        mloc = fmaxf(mloc, __shfl_xor(mloc, 16));
        mloc = fmaxf(mloc, __shfl_xor(mloc, 32));
        const float mnew  = fmaxf(m_run, mloc);
        const float scale = __expf(m_run - mnew);
        m_run = mnew;
        float lsum = 0.f;
        #pragma unroll 4
        for (int jt = 0; jt < nt; ++jt)
            #pragma unroll
            for (int r = 0; r < 4; ++r) {
                const float e = __expf(st[jt][r] - mnew);
                st[jt][r] = e;
                lsum += e;
            }
        lsum += __shfl_xor(lsum, 16);
        lsum += __shfl_xor(lsum, 32);
        l_run = l_run * scale + lsum;
        #pragma unroll
        for (int ct = 0; ct < 2; ++ct)
            #pragma unroll
            for (int r = 0; r < 4; ++r) accO[ct][r] *= scale;

        // PV: P regs are the B-fragment (n=i=l15, k=j=grp*4+r)
        #pragma unroll 4
        for (int jt = 0; jt < nt; ++jt) {
            s4v pf;
            #pragma unroll
            for (int r = 0; r < 4; ++r) pf[r] = (short)f2bf(st[jt][r]);
            #pragma unroll
            for (int ct = 0; ct < 2; ++ct) {
                const s4v aV = *reinterpret_cast<const s4v*>(
                    &Vc[ct*16 + l15][jt*16 + grp*4]);
                accO[ct] = mfma_pv(aV, pf, accO[ct]);
            }
        }
        __syncthreads();
        if (ch < 12) { writeQ(nQ); writeV(nV); __syncthreads(); }
    }

    // normalize + stage (reuse Vc) + coalesced bf16 store
    const float linv = 1.f / l_run;
    #pragma unroll
    for (int ct = 0; ct < 2; ++ct)
        #pragma unroll
        for (int r = 0; r < 4; ++r)
            Vc[ct*16 + grp*4 + r][w*16 + l15] = f2bf(accO[ct][r] * linv);
    __syncthreads();
    {
        const int c = tid >> 3, sg = tid & 7;
        const int col = ib*64 + sg*8;
        if (col < DPOS) {
            const uint4 v = *reinterpret_cast<const uint4*>(&Vc[c][sg*8]);
            *reinterpret_cast<uint4*>(dvattP + vRow0 + (size_t)c*DPOS + col) = v;
        }
    }
}

// ---------------------------------------------------------------------------
// Obs attention per (b, t, n) — bf16 MFMA (unchanged from round 3).
// ---------------------------------------------------------------------------
__global__ __launch_bounds__(256) void obs_attn_mfma(
    const ushort* __restrict__ KdP, const ushort* __restrict__ KoP,
    const ushort* __restrict__ QP,  const ushort* __restrict__ VdP,
    const ushort* __restrict__ VoP, float* __restrict__ merged)
{
    const int tt = blockIdx.x, hn = blockIdx.y, bb = blockIdx.z;
    __shared__ __align__(16) ushort smem_u[13568];   // 27136 B
    ushort* QT = smem_u;            // [208][40]
    ushort* KT = smem_u + 8320;     // [64][40]
    ushort* VT = smem_u + 10880;    // [32][72]

    const int tid  = threadIdx.x;
    const int lane = tid & 63, w = tid >> 6;
    const int l15  = lane & 15, grp = lane >> 4;

    const size_t kdBase = ((size_t)bb*NHEADS + hn) * DPOS * 32;
    const size_t koBase = ((size_t)bb*NHEADS + hn) * OPOS * 32 + (size_t)tt*HW*32;
    const size_t vdRow0 = ((size_t)bb*CC + hn*CH) * DPOS;
    const size_t voRow0 = ((size_t)bb*CC + hn*CH) * OPOS + (size_t)tt*HW;

    auto fetchK = [&](int cp) -> uint4 {
        const int r = tid >> 2, sg = tid & 3;
        const int p = cp + r;
        uint4 v = {0,0,0,0};
        if (p < DPOS)      v = *reinterpret_cast<const uint4*>(KdP + kdBase + (size_t)p*32 + sg*8);
        else if (p < NPOS) v = *reinterpret_cast<const uint4*>(KoP + koBase + (size_t)(p-DPOS)*32 + sg*8);
        return v;
    };
    auto writeK = [&](uint4 v) {
        const int r = tid >> 2, sg = tid & 3;
        *reinterpret_cast<uint4*>(&KT[r*40 + sg*8]) = v;
    };
    auto fetchV = [&](int cp) -> uint4 {
        const int c = tid >> 3, sg = tid & 7;
        const int p0 = cp + sg*8;
        uint4 v = {0,0,0,0};
        const size_t vd = vdRow0 + (size_t)c*DPOS;
        const size_t vo = voRow0 + (size_t)c*OPOS;
        if (p0 + 7 < DPOS) {
            uint2 a  = *reinterpret_cast<const uint2*>(VdP + vd + p0);
            uint2 b2 = *reinterpret_cast<const uint2*>(VdP + vd + p0 + 4);
            v.x=a.x; v.y=a.y; v.z=b2.x; v.w=b2.y;
        } else if (p0 >= DPOS && p0 + 7 < NPOS) {
            uint2 a  = *reinterpret_cast<const uint2*>(VoP + vo + (p0-DPOS));
            uint2 b2 = *reinterpret_cast<const uint2*>(VoP + vo + (p0-DPOS) + 4);
            v.x=a.x; v.y=a.y; v.z=b2.x; v.w=b2.y;
        } else if (p0 < NPOS) {
            ushort e[8];
            #pragma unroll
            for (int j = 0; j < 8; j++) {
                const int p = p0 + j;
                e[j] = (p < DPOS) ? VdP[vd + p]
                     : (p < NPOS ? VoP[vo + (p-DPOS)] : (ushort)0);
            }
            v.x = e[0] | ((uint)e[1] << 16); v.y = e[2] | ((uint)e[3] << 16);
            v.z = e[4] | ((uint)e[5] << 16); v.w = e[6] | ((uint)e[7] << 16);
        }
        return v;
    };
    auto writeV = [&](uint4 v) {
        const int c = tid >> 3, sg = tid & 7;
        *reinterpret_cast<uint4*>(&VT[c*72 + sg*8]) = v;
    };

    for (int idx = tid; idx < 832; idx += 256) {
        const int r = idx >> 2, sg = idx & 3;
        uint4 v = {0,0,0,0};
        if (r < HW) v = *reinterpret_cast<const uint4*>(QP + koBase + (size_t)r*32 + sg*8);
        *reinterpret_cast<uint4*>(&QT[r*40 + sg*8]) = v;
    }
    writeK(fetchK(0));
    writeV(fetchV(0));

    f32x4 accO[2][13];
    #pragma unroll
    for (int ct = 0; ct < 2; ++ct)
        #pragma unroll
        for (int qt = 0; qt < 13; ++qt)
            accO[ct][qt] = (f32x4){0.f, 0.f, 0.f, 0.f};
    __syncthreads();

    for (int ch = 0; ch < 16; ++ch) {
        uint4 nk = {0,0,0,0}, nv = {0,0,0,0};
        if (ch < 15) { nk = fetchK((ch+1)*64); nv = fetchV((ch+1)*64); }

        const s8v aK = *reinterpret_cast<const s8v*>(&KT[(w*16 + l15)*40 + grp*8]);
        f32x4 ss[13];
        #pragma unroll
        for (int qt = 0; qt < 13; ++qt) {
            const s8v bQ = *reinterpret_cast<const s8v*>(&QT[(qt*16 + l15)*40 + grp*8]);
            const f32x4 z = {0.f, 0.f, 0.f, 0.f};
            ss[qt] = __builtin_amdgcn_mfma_f32_16x16x32_bf16(aK, bQ, z, 0, 0, 0);
        }
        #pragma unroll
        for (int r = 0; r < 4; ++r) {
            float m = -1e30f;
            #pragma unroll
            for (int qt = 0; qt < 13; ++qt) {
                float v = ss[qt][r] * INV_TEMP;
                if (qt == 12 && l15 >= 4) v = -1e30f;   // q >= 196 pad
                ss[qt][r] = v;
                m = fmaxf(m, v);
            }
            m = fmaxf(m, __shfl_xor(m, 1));
            m = fmaxf(m, __shfl_xor(m, 2));
            m = fmaxf(m, __shfl_xor(m, 4));
            m = fmaxf(m, __shfl_xor(m, 8));
            float sum = 0.f;
            #pragma unroll
            for (int qt = 0; qt < 13; ++qt) {
                const float e = __expf(ss[qt][r] - m);
                ss[qt][r] = e;
                sum += e;
            }
            sum += __shfl_xor(sum, 1);
            sum += __shfl_xor(sum, 2);
            sum += __shfl_xor(sum, 4);
            sum += __shfl_xor(sum, 8);
            const float is = 1.f / sum;
            #pragma unroll
            for (int qt = 0; qt < 13; ++qt) ss[qt][r] *= is;
        }
        s4v pf[13];
        #pragma unroll
        for (int qt = 0; qt < 13; ++qt) {
            s4v p4;
            #pragma unroll
            for (int r = 0; r < 4; ++r) p4[r] = (short)f2bf(ss[qt][r]);
            pf[qt] = p4;
        }
        #pragma unroll
        for (int ct = 0; ct < 2; ++ct) {
            const s4v aV = *reinterpret_cast<const s4v*>(
                &VT[(ct*16 + l15)*72 + w*16 + grp*4]);
            #pragma unroll
            for (int qt = 0; qt < 13; ++qt)
                accO[ct][qt] = mfma_pv(aV, pf[qt], accO[ct][qt]);
        }
        __syncthreads();
        if (ch < 15) { writeK(nk); writeV(nv); __syncthreads(); }
    }

    float* Ored = reinterpret_cast<float*>(smem_u);   // [32][212]
    for (int wv = 0; wv < 4; ++wv) {
        if (w == wv) {
            #pragma unroll
            for (int ct = 0; ct < 2; ++ct)
                #pragma unroll
                for (int qt = 0; qt < 13; ++qt)
                    #pragma unroll
                    for (int r = 0; r < 4; ++r) {
                        const int c = ct*16 + grp*4 + r;
                        const int q = qt*16 + l15;
                        if (wv == 0) Ored[c*212 + q]  = accO[ct][qt][r];
                        else         Ored[c*212 + q] += accO[ct][qt][r];
                    }
        }
        __syncthreads();
    }
    for (int idx = tid; idx < 32*49; idx += 256) {
        const int c = idx / 49, q0 = (idx % 49) * 4;
        const float4 v = *reinterpret_cast<const float4*>(&Ored[c*212 + q0]);
        *reinterpret_cast<float4*>(
            merged + ((size_t)bb*CC + hn*CH + c)*OPOS + (size_t)tt*HW + q0) = v;
    }
}

// ---------------------------------------------------------------------------
// Fused residual-ReLU + concat + BatchNorm. One block per channel.
// ---------------------------------------------------------------------------
__global__ __launch_bounds__(256) void bn_fuse(
    const float* __restrict__ xin, const float* __restrict__ obsout,
    const float* __restrict__ gamma, const float* __restrict__ beta,
    float* __restrict__ xout)
{
    const int c = blockIdx.x;
    const int tid = threadIdx.x;
    float sum = 0.f, sumsq = 0.f;
    for (int idx = tid; idx < BB*DPOS; idx += 256) {
        int b = idx / DPOS, pos = idx % DPOS;
        float v = xin[((size_t)b*CC + c) * XROW + pos];
        sum += v; sumsq += v * v;
    }
    for (int idx = tid; idx < BB*OPOS; idx += 256) {
        int b = idx / OPOS, pos = idx % OPOS;
        float v = xin[((size_t)b*CC + c) * XROW + DPOS + pos]
                + fmaxf(obsout[((size_t)b*CC + c) * OPOS + pos], 0.f);
        sum += v; sumsq += v * v;
    }
    #pragma unroll
    for (int off = 32; off > 0; off >>= 1) {
        sum   += __shfl_xor(sum, off);
        sumsq += __shfl_xor(sumsq, off);
    }
    __shared__ float ssum[4], ssq[4];
    __shared__ float s_mean, s_inv;
    const int lane = tid & 63, w = tid >> 6;
    if (lane == 0) { ssum[w] = sum; ssq[w] = sumsq; }
    __syncthreads();
    if (tid == 0) {
        float s  = ssum[0] + ssum[1] + ssum[2] + ssum[3];
        float sq = ssq[0] + ssq[1] + ssq[2] + ssq[3];
        const float mean = s / 12544.f;
        const float var  = sq / 12544.f - mean * mean;
        s_mean = mean;
        s_inv  = rsqrtf(var + 1e-5f);
    }
    __syncthreads();
    const float mean = s_mean;
    const float gi = gamma[c] * s_inv;
    const float bt = beta[c];
    for (int idx = tid; idx < BB*DPOS; idx += 256) {
        int b = idx / DPOS, pos = idx % DPOS;
        size_t o = ((size_t)b*CC + c) * XROW + pos;
        xout[o] = (xin[o] - mean) * gi + bt;
    }
    for (int idx = tid; idx < BB*OPOS; idx += 256) {
        int b = idx / OPOS, pos = idx % OPOS;
        float v = xin[((size_t)b*CC + c) * XROW + DPOS + pos]
                + fmaxf(obsout[((size_t)b*CC + c) * OPOS + pos], 0.f);
        xout[((size_t)b*CC + c) * XROW + DPOS + pos] = (v - mean) * gi + bt;
    }
}

// ---------------------------------------------------------------------------
extern "C" void kernel_launch(void* const* d_in, const int* in_sizes, int n_in,
                              void* d_out, int out_size, void* d_ws, size_t ws_size,
                              hipStream_t stream)
{
    const float* x   = (const float*)d_in[0];
    const float* dqw = (const float*)d_in[1];
    const float* dkw = (const float*)d_in[2];
    const float* dvw = (const float*)d_in[3];
    const float* oqw = (const float*)d_in[4];
    const float* okw = (const float*)d_in[5];
    const float* ovw = (const float*)d_in[6];
    const float* oow = (const float*)d_in[7];
    const float* gam = (const float*)d_in[8];
    const float* bet = (const float*)d_in[9];

    const size_t XN = (size_t)BB * CC * TT * HW;   // 3,211,264
    const size_t DN = (size_t)BB * CC * DPOS;      //   802,816
    const size_t ON = (size_t)BB * CC * OPOS;      // 2,408,448

    float* ws     = (float*)d_ws;
    float* xb0    = ws;
    float* xb1    = xb0 + XN;
    float* dq     = xb1 + XN;
    float* dk     = dq + DN;
    float* dv     = dk + DN;
    float* oq     = dv + DN;
    float* okb    = oq + ON;
    float* ovb    = okb + ON;
    float* dvatt  = ovb + ON;     // fp32 slot now hosts KdP (bf16)
    float* merged = dvatt + DN;
    float* obsout = merged + ON;

    // bf16 packs aliased onto dead fp32 regions (lifetimes per layer):
    //  KdP     on dvatt   : written step3, read steps 4+6
    //  QdP     on merged  : written step3, read step4 (merged written step6)
    //  VdemoP  on obsout[0, DN)        : written step3, read step4
    //  dvattP  on obsout[DN, 2DN)      : written step4, read step6
    //  KoP     on obsout[2DN, 2DN+2ON) : written step5, read step6
    //  (obsout fp32 overwritten step7, after all packs dead)
    //  QP on okb (okb read by KoP pack first); VoP on oq (read by QP pack first)
    ushort* KdP    = (ushort*)dvatt;
    ushort* QdP    = (ushort*)merged;
    ushort* VdemoP = (ushort*)obsout;
    ushort* dvattP = (ushort*)obsout + DN;
    ushort* KoP    = (ushort*)obsout + 2*DN;
    ushort* QP     = (ushort*)okb;
    ushort* VoP    = (ushort*)oq;

    const dim3 blk(256);
    for (int i = 0; i < 3; i++) {
        const float* xin  = (i == 0) ? x : (i == 1 ? xb0 : xb1);
        float*       xout = (i == 2) ? (float*)d_out : (i == 0 ? xb0 : xb1);
        const size_t wOff = (size_t)i * CC * CC;

        // 1-2: projections (fp32)
        proj_gemm<<<dim3(BB*13, 4, 3), blk, 0, stream>>>(
            xin, XROW, 0, DPOS, dqw + wOff, dkw + wOff, dvw + wOff, dq, dk, dv);
        proj_gemm<<<dim3(BB*37, 4, 3), blk, 0, stream>>>(
            xin, XROW, DPOS, OPOS, oqw + wOff, okw + wOff, ovw + wOff, oq, okb, ovb);

        // 3: demo packs
        pack_T<<<dim3(13, NHEADS, BB), blk, 0, stream>>>(dq, QdP, DPOS);
        pack_T<<<dim3(13, NHEADS, BB), blk, 0, stream>>>(dk, KdP, DPOS);
        pack_cvt<<<dim3(784), blk, 0, stream>>>(dv, VdemoP, (int)(DN/4));

        // 4: demo attention (MFMA), writes bf16 dvattP directly
        demo_attn_mfma<<<dim3(13, NHEADS, BB), blk, 0, stream>>>(
            QdP, KdP, VdemoP, dvattP);

        // 5: obs packs (order matters: KoP reads okb before QP overwrites it,
        //    QP reads oq before VoP overwrites it)
        pack_T<<<dim3(37, NHEADS, BB), blk, 0, stream>>>(okb, KoP, OPOS);
        pack_T<<<dim3(37, NHEADS, BB), blk, 0, stream>>>(oq,  QP,  OPOS);
        pack_cvt<<<dim3(1024), blk, 0, stream>>>(ovb, VoP, (int)(ON/4));

        // 6: obs attention (MFMA)
        obs_attn_mfma<<<dim3(OBS_T, NHEADS, BB), blk, 0, stream>>>(
            KdP, KoP, QP, dvattP, VoP, merged);

        // 7: output projection (fp32)
        proj_gemm<<<dim3(BB*37, 4, 1), blk, 0, stream>>>(
            merged, OPOS, 0, OPOS, oow + wOff, oow + wOff, oow + wOff, obsout, obsout, obsout);

        // 8: residual + BN
        bn_fuse<<<dim3(CC), blk, 0, stream>>>(xin, obsout, gam + i*CC, bet + i*CC, xout);
    }
}

// Round 5
// 782.084 us; speedup vs baseline: 4.8800x; 1.1309x over previous
//
#include <hip/hip_runtime.h>
#include <hip/hip_bf16.h>

// Problem constants
#define BB 4
#define CC 256
#define TT 16
#define HW 196
#define DEMO_T 4
#define OBS_T 12
#define DPOS 784      // DEMO_T*HW
#define OPOS 2352     // OBS_T*HW
#define XROW 3136     // TT*HW
#define NHEADS 8
#define CH 32
#define INV_TEMP 0.0625f
#define NPOS 980      // DPOS + HW (cat keys per (b,t,n))

typedef float  f32x4 __attribute__((ext_vector_type(4)));
typedef short  s8v   __attribute__((ext_vector_type(8)));
typedef short  s4v   __attribute__((ext_vector_type(4)));

static __device__ __forceinline__ ushort f2bf(float f) {
    union { float f; uint u; } x; x.f = f;
    const uint r = x.u + 0x7FFF + ((x.u >> 16) & 1);   // RNE
    return (ushort)(r >> 16);
}

static __device__ __forceinline__ f32x4 mfma_pv(s4v a, s4v b, f32x4 c) {
#if __has_builtin(__builtin_amdgcn_mfma_f32_16x16x16bf16_1k)
    return __builtin_amdgcn_mfma_f32_16x16x16bf16_1k(a, b, c, 0, 0, 0);
#else
    s8v a8 = {a[0], a[1], a[2], a[3], 0, 0, 0, 0};
    s8v b8 = {b[0], b[1], b[2], b[3], 0, 0, 0, 0};
    return __builtin_amdgcn_mfma_f32_16x16x32_bf16(a8, b8, c, 0, 0, 0);
#endif
}

// ---------------------------------------------------------------------------
// Tiled fp32 GEMM: O[b][f][p] = sum_c W[f][c] * X[b][c][xBase + p]
// ---------------------------------------------------------------------------
__global__ __launch_bounds__(256) void proj_gemm(
    const float* __restrict__ X, int xRowStride, int xBase, int ncols,
    const float* __restrict__ W0, const float* __restrict__ W1, const float* __restrict__ W2,
    float* __restrict__ O0, float* __restrict__ O1, float* __restrict__ O2)
{
    const int ptiles = (ncols + 63) >> 6;
    const int b  = blockIdx.x / ptiles;
    const int pt = blockIdx.x % ptiles;
    const int fbase = blockIdx.y * 64;
    const int pbase = pt * 64;
    const float* W = (blockIdx.z == 0) ? W0 : (blockIdx.z == 1) ? W1 : W2;
    float*       O = (blockIdx.z == 0) ? O0 : (blockIdx.z == 1) ? O1 : O2;

    const int tid = threadIdx.x;
    const int tx = tid & 15, ty = tid >> 4;

    __shared__ float WtT[16][68];   // [c][f]
    __shared__ float Xt[16][68];    // [c][p]

    float acc[4][4] = {};
    const float* Xb = X + (size_t)b * CC * xRowStride + xBase;
    const bool fullp = (pbase + 64 <= ncols);

    for (int c0 = 0; c0 < CC; c0 += 16) {
        {
            int fi = tid >> 2, ci4 = (tid & 3) * 4;
            const float4 wv = *reinterpret_cast<const float4*>(&W[(size_t)(fbase + fi) * CC + c0 + ci4]);
            WtT[ci4+0][fi] = wv.x; WtT[ci4+1][fi] = wv.y;
            WtT[ci4+2][fi] = wv.z; WtT[ci4+3][fi] = wv.w;
        }
        {
            int ci = tid >> 4, pj = (tid & 15) * 4;
            const float* src = Xb + (size_t)(c0 + ci) * xRowStride + pbase + pj;
            if (fullp) {
                const float4 xv = *reinterpret_cast<const float4*>(src);
                Xt[ci][pj]   = xv.x; Xt[ci][pj+1] = xv.y;
                Xt[ci][pj+2] = xv.z; Xt[ci][pj+3] = xv.w;
            } else {
                #pragma unroll
                for (int u = 0; u < 4; u++)
                    Xt[ci][pj+u] = (pbase + pj + u < ncols) ? src[u] : 0.f;
            }
        }
        __syncthreads();
        #pragma unroll
        for (int ci = 0; ci < 16; ci++) {
            const float4 wv4 = *reinterpret_cast<const float4*>(&WtT[ci][ty*4]);
            const float4 xv4 = *reinterpret_cast<const float4*>(&Xt[ci][tx*4]);
            const float wv[4] = {wv4.x, wv4.y, wv4.z, wv4.w};
            const float xv[4] = {xv4.x, xv4.y, xv4.z, xv4.w};
            #pragma unroll
            for (int i = 0; i < 4; i++)
                #pragma unroll
                for (int j = 0; j < 4; j++) acc[i][j] += wv[i] * xv[j];
        }
        __syncthreads();
    }
    #pragma unroll
    for (int i = 0; i < 4; i++) {
        const int f = fbase + ty*4 + i;
        float* dst = O + ((size_t)b * CC + f) * ncols + pbase + tx*4;
        #pragma unroll
        for (int j = 0; j < 4; j++) {
            if (pbase + tx*4 + j < ncols) dst[j] = acc[i][j];
        }
    }
}

// ---------------------------------------------------------------------------
// pack_T: fp32 [b][256][P] -> bf16 [b][8][P][32]  (per-head transpose)
// ---------------------------------------------------------------------------
__global__ __launch_bounds__(256) void pack_T(
    const float* __restrict__ src, ushort* __restrict__ dst, int P)
{
    const int hn = blockIdx.y, bb = blockIdx.z;
    const int p0 = blockIdx.x * 64;
    __shared__ float L[32][73];
    const int tid = threadIdx.x;
    {
        const int c = tid >> 3, sg = tid & 7;
        const int p = p0 + sg*8;
        const float* s = src + ((size_t)bb*CC + hn*CH + c) * P + p;
        float4 a = {0,0,0,0}, b2 = {0,0,0,0};
        if (p < P) { a = *reinterpret_cast<const float4*>(s);
                     b2 = *reinterpret_cast<const float4*>(s + 4); }
        L[c][sg*8+0]=a.x;  L[c][sg*8+1]=a.y;  L[c][sg*8+2]=a.z;  L[c][sg*8+3]=a.w;
        L[c][sg*8+4]=b2.x; L[c][sg*8+5]=b2.y; L[c][sg*8+6]=b2.z; L[c][sg*8+7]=b2.w;
    }
    __syncthreads();
    {
        const int pl = tid >> 2, cs = (tid & 3) * 8;
        if (p0 + pl < P) {
            ushort o[8];
            #pragma unroll
            for (int j = 0; j < 8; j++) o[j] = f2bf(L[cs+j][pl]);
            uint4 v;
            v.x = o[0] | ((uint)o[1]<<16); v.y = o[2] | ((uint)o[3]<<16);
            v.z = o[4] | ((uint)o[5]<<16); v.w = o[6] | ((uint)o[7]<<16);
            *reinterpret_cast<uint4*>(dst + (((size_t)bb*NHEADS + hn)*P + p0 + pl)*32 + cs) = v;
        }
    }
}

// ---------------------------------------------------------------------------
// pack_cvt: flat fp32 -> bf16 (n4 = count/4)
// ---------------------------------------------------------------------------
__global__ __launch_bounds__(256) void pack_cvt(
    const float* __restrict__ src, ushort* __restrict__ dst, int n4)
{
    for (size_t i = (size_t)blockIdx.x * 256 + threadIdx.x; i < (size_t)n4;
         i += (size_t)gridDim.x * 256) {
        const float4 v = *reinterpret_cast<const float4*>(src + i*4);
        uint2 o;
        o.x = f2bf(v.x) | ((uint)f2bf(v.y) << 16);
        o.y = f2bf(v.z) | ((uint)f2bf(v.w) << 16);
        *reinterpret_cast<uint2*>(dst + i*4) = o;
    }
}

// ---------------------------------------------------------------------------
// Demo attention — bf16 MFMA, 512 threads, 2 wave-groups split over j.
// Group 0: j-chunks 0..6; group 1: j-chunks 7..12. Each group runs an
// independent online softmax (m,l,O); merged at the end via the standard
// flash-combine in LDS. Output bf16 dvattP [b][256][784].
// ---------------------------------------------------------------------------
__global__ __launch_bounds__(512) void demo_attn_mfma(
    const ushort* __restrict__ QdP, const ushort* __restrict__ KdP,
    const ushort* __restrict__ VdP, ushort* __restrict__ dvattP)
{
    const int ib = blockIdx.x, hn = blockIdx.y, bb = blockIdx.z;
    const int tid = threadIdx.x;
    const int g   = tid >> 8;          // wave-group 0/1
    const int gt  = tid & 255;         // group-local tid
    const int lane = tid & 63;
    const int w    = (tid >> 6) & 3;   // group-local wave
    const int l15 = lane & 15, grp = lane >> 4;

    // LDS: Qc[2][64][40] (5120 us) | Vc[2][32][72] (4608 us) | merge f32 2560
    __shared__ __align__(16) ushort smem_d[14848];   // 29696 B
    ushort* Qc = smem_d;               // + g*2560
    ushort* Vc = smem_d + 5120;        // + g*2304

    const size_t hBase = ((size_t)bb*NHEADS + hn) * DPOS;
    const size_t vRow0 = ((size_t)bb*CC + hn*CH) * DPOS;

    const int i_glob = ib*64 + w*16 + l15;
    const s8v bK = *reinterpret_cast<const s8v*>(KdP + (hBase + i_glob)*32 + grp*8);

    auto fetchQ = [&](int j0) -> uint4 {
        const int r = gt >> 2, sg = gt & 3;
        return *reinterpret_cast<const uint4*>(QdP + (hBase + j0 + r)*32 + sg*8);
    };
    auto writeQ = [&](uint4 v) {
        const int r = gt >> 2, sg = gt & 3;
        *reinterpret_cast<uint4*>(&Qc[g*2560 + r*40 + sg*8]) = v;
    };
    auto fetchV = [&](int j0) -> uint4 {
        const int c = gt >> 3, sg = gt & 7;
        return *reinterpret_cast<const uint4*>(VdP + vRow0 + (size_t)c*DPOS + j0 + sg*8);
    };
    auto writeV = [&](uint4 v) {
        const int c = gt >> 3, sg = gt & 7;
        *reinterpret_cast<uint4*>(&Vc[g*2304 + c*72 + sg*8]) = v;
    };

    const int myFirst = g ? 7 : 0;
    const int myCount = g ? 6 : 7;

    writeQ(fetchQ(myFirst*64));
    writeV(fetchV(myFirst*64));
    f32x4 accO[2] = {{0.f,0.f,0.f,0.f}, {0.f,0.f,0.f,0.f}};
    float m_run = -1e30f, l_run = 0.f;
    __syncthreads();

    for (int it = 0; it < 7; ++it) {
        const bool active = (it < myCount);
        const int ch = myFirst + it;
        const bool pf = (it + 1 < myCount);
        uint4 nQ, nV;
        if (pf) { nQ = fetchQ((ch+1)*64); nV = fetchV((ch+1)*64); }

        if (active) {
            const int nt = (ch == 12) ? 1 : 4;
            f32x4 st[4];
            for (int jt = 0; jt < nt; ++jt) {
                const s8v aQ = *reinterpret_cast<const s8v*>(
                    &Qc[g*2560 + (jt*16 + l15)*40 + grp*8]);
                const f32x4 z = {0.f,0.f,0.f,0.f};
                st[jt] = __builtin_amdgcn_mfma_f32_16x16x32_bf16(aQ, bK, z, 0, 0, 0);
            }
            float mloc = -1e30f;
            for (int jt = 0; jt < nt; ++jt)
                #pragma unroll
                for (int r = 0; r < 4; ++r) {
                    const float v = st[jt][r] * INV_TEMP;
                    st[jt][r] = v;
                    mloc = fmaxf(mloc, v);
                }
            mloc = fmaxf(mloc, __shfl_xor(mloc, 16));
            mloc = fmaxf(mloc, __shfl_xor(mloc, 32));
            const float mnew  = fmaxf(m_run, mloc);
            const float scale = __expf(m_run - mnew);
            m_run = mnew;
            float lsum = 0.f;
            for (int jt = 0; jt < nt; ++jt)
                #pragma unroll
                for (int r = 0; r < 4; ++r) {
                    const float e = __expf(st[jt][r] - mnew);
                    st[jt][r] = e;
                    lsum += e;
                }
            lsum += __shfl_xor(lsum, 16);
            lsum += __shfl_xor(lsum, 32);
            l_run = l_run * scale + lsum;
            #pragma unroll
            for (int ct = 0; ct < 2; ++ct)
                #pragma unroll
                for (int r = 0; r < 4; ++r) accO[ct][r] *= scale;

            for (int jt = 0; jt < nt; ++jt) {
                s4v pf4;
                #pragma unroll
                for (int r = 0; r < 4; ++r) pf4[r] = (short)f2bf(st[jt][r]);
                #pragma unroll
                for (int ct = 0; ct < 2; ++ct) {
                    const s4v aV = *reinterpret_cast<const s4v*>(
                        &Vc[g*2304 + (ct*16 + l15)*72 + jt*16 + grp*4]);
                    accO[ct] = mfma_pv(aV, pf4, accO[ct]);
                }
            }
        }
        __syncthreads();
        if (pf) { writeQ(nQ); writeV(nV); }
        __syncthreads();
    }

    // ---- merge group 1 into group 0 (flash combine) ----
    float* mbase = reinterpret_cast<float*>(smem_d + 9728);
    float* Mb = mbase;          // [4][64]
    float* Lb = mbase + 256;    // [4][64]
    float* Ob = mbase + 512;    // [4][64][8]
    if (g == 1) {
        Mb[w*64 + lane] = m_run;
        Lb[w*64 + lane] = l_run;
        #pragma unroll
        for (int ct = 0; ct < 2; ++ct)
            #pragma unroll
            for (int r = 0; r < 4; ++r)
                Ob[(w*64 + lane)*8 + ct*4 + r] = accO[ct][r];
    }
    __syncthreads();
    if (g == 0) {
        const float m1 = Mb[w*64 + lane], l1 = Lb[w*64 + lane];
        const float mm = fmaxf(m_run, m1);
        const float s0 = __expf(m_run - mm), s1 = __expf(m1 - mm);
        const float linv = 1.f / (l_run * s0 + l1 * s1);
        #pragma unroll
        for (int ct = 0; ct < 2; ++ct)
            #pragma unroll
            for (int r = 0; r < 4; ++r) {
                const float o = (accO[ct][r]*s0 + Ob[(w*64 + lane)*8 + ct*4 + r]*s1) * linv;
                Vc[(ct*16 + grp*4 + r)*72 + w*16 + l15] = f2bf(o);   // group-0 Vc region
            }
    }
    __syncthreads();
    if (g == 0) {
        const int c = gt >> 3, sg = gt & 7;
        const int col = ib*64 + sg*8;
        if (col < DPOS) {
            const uint4 v = *reinterpret_cast<const uint4*>(&Vc[c*72 + sg*8]);
            *reinterpret_cast<uint4*>(dvattP + vRow0 + (size_t)c*DPOS + col) = v;
        }
    }
}

// ---------------------------------------------------------------------------
// Obs attention per (b, t, n) — bf16 MFMA, 512 threads, 2 wave-groups split
// over p: group g handles p-chunks 8g..8g+7 (p-rows are independent: softmax
// is per p-row over q). Each group reduces its 4 waves into its own Ored
// buffer; the store adds the two partials.
// LDS union: staging (QT+KT[2]+VT[2] = 36096 B) overlapped by Ored f32
// [2][32][212] = 54272 B after compute.
// ---------------------------------------------------------------------------
__global__ __launch_bounds__(512) void obs_attn_mfma(
    const ushort* __restrict__ KdP, const ushort* __restrict__ KoP,
    const ushort* __restrict__ QP,  const ushort* __restrict__ VdP,
    const ushort* __restrict__ VoP, float* __restrict__ merged)
{
    const int tt = blockIdx.x, hn = blockIdx.y, bb = blockIdx.z;
    __shared__ __align__(16) ushort smem_u[27136];   // 54272 B
    ushort* QT = smem_u;            // [208][40]        (8320 us)
    ushort* KT = smem_u + 8320;     // [2][64][40]      (5120 us)
    ushort* VT = smem_u + 13440;    // [2][32][72]      (4608 us)

    const int tid  = threadIdx.x;
    const int g    = tid >> 8;
    const int gt   = tid & 255;
    const int lane = tid & 63;
    const int w    = (tid >> 6) & 3;
    const int l15  = lane & 15, grp = lane >> 4;

    const size_t kdBase = ((size_t)bb*NHEADS + hn) * DPOS * 32;
    const size_t koBase = ((size_t)bb*NHEADS + hn) * OPOS * 32 + (size_t)tt*HW*32;
    const size_t vdRow0 = ((size_t)bb*CC + hn*CH) * DPOS;
    const size_t voRow0 = ((size_t)bb*CC + hn*CH) * OPOS + (size_t)tt*HW;

    auto fetchK = [&](int cp) -> uint4 {
        const int r = gt >> 2, sg = gt & 3;
        const int p = cp + r;
        uint4 v = {0,0,0,0};
        if (p < DPOS)      v = *reinterpret_cast<const uint4*>(KdP + kdBase + (size_t)p*32 + sg*8);
        else if (p < NPOS) v = *reinterpret_cast<const uint4*>(KoP + koBase + (size_t)(p-DPOS)*32 + sg*8);
        return v;
    };
    auto writeK = [&](uint4 v) {
        const int r = gt >> 2, sg = gt & 3;
        *reinterpret_cast<uint4*>(&KT[(g*64 + r)*40 + sg*8]) = v;
    };
    auto fetchV = [&](int cp) -> uint4 {
        const int c = gt >> 3, sg = gt & 7;
        const int p0 = cp + sg*8;
        uint4 v = {0,0,0,0};
        const size_t vd = vdRow0 + (size_t)c*DPOS;
        const size_t vo = voRow0 + (size_t)c*OPOS;
        if (p0 + 7 < DPOS) {
            uint2 a  = *reinterpret_cast<const uint2*>(VdP + vd + p0);
            uint2 b2 = *reinterpret_cast<const uint2*>(VdP + vd + p0 + 4);
            v.x=a.x; v.y=a.y; v.z=b2.x; v.w=b2.y;
        } else if (p0 >= DPOS && p0 + 7 < NPOS) {
            uint2 a  = *reinterpret_cast<const uint2*>(VoP + vo + (p0-DPOS));
            uint2 b2 = *reinterpret_cast<const uint2*>(VoP + vo + (p0-DPOS) + 4);
            v.x=a.x; v.y=a.y; v.z=b2.x; v.w=b2.y;
        } else if (p0 < NPOS) {
            ushort e[8];
            #pragma unroll
            for (int j = 0; j < 8; j++) {
                const int p = p0 + j;
                e[j] = (p < DPOS) ? VdP[vd + p]
                     : (p < NPOS ? VoP[vo + (p-DPOS)] : (ushort)0);
            }
            v.x = e[0] | ((uint)e[1] << 16); v.y = e[2] | ((uint)e[3] << 16);
            v.z = e[4] | ((uint)e[5] << 16); v.w = e[6] | ((uint)e[7] << 16);
        }
        return v;
    };
    auto writeV = [&](uint4 v) {
        const int c = gt >> 3, sg = gt & 7;
        *reinterpret_cast<uint4*>(&VT[(g*32 + c)*72 + sg*8]) = v;
    };

    for (int idx = tid; idx < 832; idx += 512) {
        const int r = idx >> 2, sg = idx & 3;
        uint4 v = {0,0,0,0};
        if (r < HW) v = *reinterpret_cast<const uint4*>(QP + koBase + (size_t)r*32 + sg*8);
        *reinterpret_cast<uint4*>(&QT[r*40 + sg*8]) = v;
    }
    writeK(fetchK(g*512));
    writeV(fetchV(g*512));

    f32x4 accO[2][13];
    #pragma unroll
    for (int ct = 0; ct < 2; ++ct)
        #pragma unroll
        for (int qt = 0; qt < 13; ++qt)
            accO[ct][qt] = (f32x4){0.f, 0.f, 0.f, 0.f};
    __syncthreads();

    for (int it = 0; it < 8; ++it) {
        uint4 nk = {0,0,0,0}, nv = {0,0,0,0};
        if (it < 7) { nk = fetchK((g*8 + it + 1)*64); nv = fetchV((g*8 + it + 1)*64); }

        const s8v aK = *reinterpret_cast<const s8v*>(&KT[(g*64 + w*16 + l15)*40 + grp*8]);
        f32x4 ss[13];
        #pragma unroll
        for (int qt = 0; qt < 13; ++qt) {
            const s8v bQ = *reinterpret_cast<const s8v*>(&QT[(qt*16 + l15)*40 + grp*8]);
            const f32x4 z = {0.f, 0.f, 0.f, 0.f};
            ss[qt] = __builtin_amdgcn_mfma_f32_16x16x32_bf16(aK, bQ, z, 0, 0, 0);
        }
        #pragma unroll
        for (int r = 0; r < 4; ++r) {
            float m = -1e30f;
            #pragma unroll
            for (int qt = 0; qt < 13; ++qt) {
                float v = ss[qt][r] * INV_TEMP;
                if (qt == 12 && l15 >= 4) v = -1e30f;   // q >= 196 pad
                ss[qt][r] = v;
                m = fmaxf(m, v);
            }
            m = fmaxf(m, __shfl_xor(m, 1));
            m = fmaxf(m, __shfl_xor(m, 2));
            m = fmaxf(m, __shfl_xor(m, 4));
            m = fmaxf(m, __shfl_xor(m, 8));
            float sum = 0.f;
            #pragma unroll
            for (int qt = 0; qt < 13; ++qt) {
                const float e = __expf(ss[qt][r] - m);
                ss[qt][r] = e;
                sum += e;
            }
            sum += __shfl_xor(sum, 1);
            sum += __shfl_xor(sum, 2);
            sum += __shfl_xor(sum, 4);
            sum += __shfl_xor(sum, 8);
            const float is = 1.f / sum;
            #pragma unroll
            for (int qt = 0; qt < 13; ++qt) ss[qt][r] *= is;
        }
        s4v pf[13];
        #pragma unroll
        for (int qt = 0; qt < 13; ++qt) {
            s4v p4;
            #pragma unroll
            for (int r = 0; r < 4; ++r) p4[r] = (short)f2bf(ss[qt][r]);
            pf[qt] = p4;
        }
        #pragma unroll
        for (int ct = 0; ct < 2; ++ct) {
            const s4v aV = *reinterpret_cast<const s4v*>(
                &VT[(g*32 + ct*16 + l15)*72 + w*16 + grp*4]);
            #pragma unroll
            for (int qt = 0; qt < 13; ++qt)
                accO[ct][qt] = mfma_pv(aV, pf[qt], accO[ct][qt]);
        }
        __syncthreads();
        if (it < 7) { writeK(nk); writeV(nv); __syncthreads(); }
    }

    // ---- per-group 4-wave reduction into Ored[g], then add partials ----
    float* OredF = reinterpret_cast<float*>(smem_u);   // [2][32][212]
    float* Og = OredF + g * 6784;
    for (int wv = 0; wv < 4; ++wv) {
        if (w == wv) {
            #pragma unroll
            for (int ct = 0; ct < 2; ++ct)
                #pragma unroll
                for (int qt = 0; qt < 13; ++qt)
                    #pragma unroll
                    for (int r = 0; r < 4; ++r) {
                        const int c = ct*16 + grp*4 + r;
                        const int q = qt*16 + l15;
                        if (wv == 0) Og[c*212 + q]  = accO[ct][qt][r];
                        else         Og[c*212 + q] += accO[ct][qt][r];
                    }
        }
        __syncthreads();
    }
    for (int idx = tid; idx < 32*49; idx += 512) {
        const int c = idx / 49, q0 = (idx % 49) * 4;
        const float4 a  = *reinterpret_cast<const float4*>(&OredF[c*212 + q0]);
        const float4 b2 = *reinterpret_cast<const float4*>(&OredF[6784 + c*212 + q0]);
        const float4 o = make_float4(a.x + b2.x, a.y + b2.y, a.z + b2.z, a.w + b2.w);
        *reinterpret_cast<float4*>(
            merged + ((size_t)bb*CC + hn*CH + c)*OPOS + (size_t)tt*HW + q0) = o;
    }
}

// ---------------------------------------------------------------------------
// Fused residual-ReLU + concat + BatchNorm. One block per channel. float4.
// ---------------------------------------------------------------------------
__global__ __launch_bounds__(256) void bn_fuse(
    const float* __restrict__ xin, const float* __restrict__ obsout,
    const float* __restrict__ gamma, const float* __restrict__ beta,
    float* __restrict__ xout)
{
    const int c = blockIdx.x;
    const int tid = threadIdx.x;
    float sum = 0.f, sumsq = 0.f;
    for (int idx = tid; idx < BB*(DPOS/4); idx += 256) {
        const int b = idx / (DPOS/4), pos = idx % (DPOS/4);
        const float4 v = *reinterpret_cast<const float4*>(
            &xin[((size_t)b*CC + c) * XROW + pos*4]);
        sum   += v.x + v.y + v.z + v.w;
        sumsq += v.x*v.x + v.y*v.y + v.z*v.z + v.w*v.w;
    }
    for (int idx = tid; idx < BB*(OPOS/4); idx += 256) {
        const int b = idx / (OPOS/4), pos = idx % (OPOS/4);
        const float4 xv = *reinterpret_cast<const float4*>(
            &xin[((size_t)b*CC + c) * XROW + DPOS + pos*4]);
        const float4 ov = *reinterpret_cast<const float4*>(
            &obsout[((size_t)b*CC + c) * OPOS + pos*4]);
        const float4 v = make_float4(xv.x + fmaxf(ov.x, 0.f), xv.y + fmaxf(ov.y, 0.f),
                                     xv.z + fmaxf(ov.z, 0.f), xv.w + fmaxf(ov.w, 0.f));
        sum   += v.x + v.y + v.z + v.w;
        sumsq += v.x*v.x + v.y*v.y + v.z*v.z + v.w*v.w;
    }
    #pragma unroll
    for (int off = 32; off > 0; off >>= 1) {
        sum   += __shfl_xor(sum, off);
        sumsq += __shfl_xor(sumsq, off);
    }
    __shared__ float ssum[4], ssq[4];
    __shared__ float s_mean, s_inv;
    const int lane = tid & 63, w = tid >> 6;
    if (lane == 0) { ssum[w] = sum; ssq[w] = sumsq; }
    __syncthreads();
    if (tid == 0) {
        float s  = ssum[0] + ssum[1] + ssum[2] + ssum[3];
        float sq = ssq[0] + ssq[1] + ssq[2] + ssq[3];
        const float mean = s / 12544.f;
        const float var  = sq / 12544.f - mean * mean;
        s_mean = mean;
        s_inv  = rsqrtf(var + 1e-5f);
    }
    __syncthreads();
    const float mean = s_mean;
    const float gi = gamma[c] * s_inv;
    const float bt = beta[c];
    for (int idx = tid; idx < BB*(DPOS/4); idx += 256) {
        const int b = idx / (DPOS/4), pos = idx % (DPOS/4);
        const size_t o = ((size_t)b*CC + c) * XROW + pos*4;
        const float4 v = *reinterpret_cast<const float4*>(&xin[o]);
        const float4 r = make_float4((v.x-mean)*gi+bt, (v.y-mean)*gi+bt,
                                     (v.z-mean)*gi+bt, (v.w-mean)*gi+bt);
        *reinterpret_cast<float4*>(&xout[o]) = r;
    }
    for (int idx = tid; idx < BB*(OPOS/4); idx += 256) {
        const int b = idx / (OPOS/4), pos = idx % (OPOS/4);
        const float4 xv = *reinterpret_cast<const float4*>(
            &xin[((size_t)b*CC + c) * XROW + DPOS + pos*4]);
        const float4 ov = *reinterpret_cast<const float4*>(
            &obsout[((size_t)b*CC + c) * OPOS + pos*4]);
        const float4 v = make_float4(xv.x + fmaxf(ov.x, 0.f), xv.y + fmaxf(ov.y, 0.f),
                                     xv.z + fmaxf(ov.z, 0.f), xv.w + fmaxf(ov.w, 0.f));
        const float4 r = make_float4((v.x-mean)*gi+bt, (v.y-mean)*gi+bt,
                                     (v.z-mean)*gi+bt, (v.w-mean)*gi+bt);
        *reinterpret_cast<float4*>(&xout[((size_t)b*CC + c) * XROW + DPOS + pos*4]) = r;
    }
}

// ---------------------------------------------------------------------------
extern "C" void kernel_launch(void* const* d_in, const int* in_sizes, int n_in,
                              void* d_out, int out_size, void* d_ws, size_t ws_size,
                              hipStream_t stream)
{
    const float* x   = (const float*)d_in[0];
    const float* dqw = (const float*)d_in[1];
    const float* dkw = (const float*)d_in[2];
    const float* dvw = (const float*)d_in[3];
    const float* oqw = (const float*)d_in[4];
    const float* okw = (const float*)d_in[5];
    const float* ovw = (const float*)d_in[6];
    const float* oow = (const float*)d_in[7];
    const float* gam = (const float*)d_in[8];
    const float* bet = (const float*)d_in[9];

    const size_t XN = (size_t)BB * CC * TT * HW;   // 3,211,264
    const size_t DN = (size_t)BB * CC * DPOS;      //   802,816
    const size_t ON = (size_t)BB * CC * OPOS;      // 2,408,448

    float* ws     = (float*)d_ws;
    float* xb0    = ws;
    float* xb1    = xb0 + XN;
    float* dq     = xb1 + XN;
    float* dk     = dq + DN;
    float* dv     = dk + DN;
    float* oq     = dv + DN;
    float* okb    = oq + ON;
    float* ovb    = okb + ON;
    float* dvatt  = ovb + ON;     // fp32 slot hosts KdP (bf16)
    float* merged = dvatt + DN;
    float* obsout = merged + ON;

    // bf16 packs aliased onto dead fp32 regions (lifetimes per layer):
    //  KdP on dvatt; QdP on merged; VdemoP on obsout[0,DN);
    //  dvattP on obsout[DN,2DN); KoP on obsout[2DN,2DN+2ON);
    //  QP on okb (read by KoP pack first); VoP on oq (read by QP pack first)
    ushort* KdP    = (ushort*)dvatt;
    ushort* QdP    = (ushort*)merged;
    ushort* VdemoP = (ushort*)obsout;
    ushort* dvattP = (ushort*)obsout + DN;
    ushort* KoP    = (ushort*)obsout + 2*DN;
    ushort* QP     = (ushort*)okb;
    ushort* VoP    = (ushort*)oq;

    const dim3 blk(256);
    const dim3 blk2(512);
    for (int i = 0; i < 3; i++) {
        const float* xin  = (i == 0) ? x : (i == 1 ? xb0 : xb1);
        float*       xout = (i == 2) ? (float*)d_out : (i == 0 ? xb0 : xb1);
        const size_t wOff = (size_t)i * CC * CC;

        // 1-2: projections (fp32)
        proj_gemm<<<dim3(BB*13, 4, 3), blk, 0, stream>>>(
            xin, XROW, 0, DPOS, dqw + wOff, dkw + wOff, dvw + wOff, dq, dk, dv);
        proj_gemm<<<dim3(BB*37, 4, 3), blk, 0, stream>>>(
            xin, XROW, DPOS, OPOS, oqw + wOff, okw + wOff, ovw + wOff, oq, okb, ovb);

        // 3: demo packs
        pack_T<<<dim3(13, NHEADS, BB), blk, 0, stream>>>(dq, QdP, DPOS);
        pack_T<<<dim3(13, NHEADS, BB), blk, 0, stream>>>(dk, KdP, DPOS);
        pack_cvt<<<dim3(784), blk, 0, stream>>>(dv, VdemoP, (int)(DN/4));

        // 4: demo attention (MFMA, 512 thr), writes bf16 dvattP directly
        demo_attn_mfma<<<dim3(13, NHEADS, BB), blk2, 0, stream>>>(
            QdP, KdP, VdemoP, dvattP);

        // 5: obs packs (order matters: KoP reads okb before QP overwrites it,
        //    QP reads oq before VoP overwrites it)
        pack_T<<<dim3(37, NHEADS, BB), blk, 0, stream>>>(okb, KoP, OPOS);
        pack_T<<<dim3(37, NHEADS, BB), blk, 0, stream>>>(oq,  QP,  OPOS);
        pack_cvt<<<dim3(1024), blk, 0, stream>>>(ovb, VoP, (int)(ON/4));

        // 6: obs attention (MFMA, 512 thr)
        obs_attn_mfma<<<dim3(OBS_T, NHEADS, BB), blk2, 0, stream>>>(
            KdP, KoP, QP, dvattP, VoP, merged);

        // 7: output projection (fp32)
        proj_gemm<<<dim3(BB*37, 4, 1), blk, 0, stream>>>(
            merged, OPOS, 0, OPOS, oow + wOff, oow + wOff, oow + wOff, obsout, obsout, obsout);

        // 8: residual + BN
        bn_fuse<<<dim3(CC), blk, 0, stream>>>(xin, obsout, gam + i*CC, bet + i*CC, xout);
    }
}

// Round 6
// 518.903 us; speedup vs baseline: 7.3551x; 1.5072x over previous
//
#include <hip/hip_runtime.h>
#include <hip/hip_bf16.h>

// Problem constants
#define BB 4
#define CC 256
#define TT 16
#define HW 196
#define DEMO_T 4
#define OBS_T 12
#define DPOS 784      // DEMO_T*HW
#define OPOS 2352     // OBS_T*HW
#define XROW 3136     // TT*HW
#define NHEADS 8
#define CH 32
#define INV_TEMP 0.0625f
#define NPOS 980      // DPOS + HW (cat keys per (b,t,n))

typedef float  f32x4 __attribute__((ext_vector_type(4)));
typedef short  s8v   __attribute__((ext_vector_type(8)));
typedef short  s4v   __attribute__((ext_vector_type(4)));

static __device__ __forceinline__ ushort f2bf(float f) {
    union { float f; uint u; } x; x.f = f;
    const uint r = x.u + 0x7FFF + ((x.u >> 16) & 1);   // RNE
    return (ushort)(r >> 16);
}

static __device__ __forceinline__ f32x4 mfma_pv(s4v a, s4v b, f32x4 c) {
#if __has_builtin(__builtin_amdgcn_mfma_f32_16x16x16bf16_1k)
    return __builtin_amdgcn_mfma_f32_16x16x16bf16_1k(a, b, c, 0, 0, 0);
#else
    s8v a8 = {a[0], a[1], a[2], a[3], 0, 0, 0, 0};
    s8v b8 = {b[0], b[1], b[2], b[3], 0, 0, 0, 0};
    return __builtin_amdgcn_mfma_f32_16x16x32_bf16(a8, b8, c, 0, 0, 0);
#endif
}

// ---------------------------------------------------------------------------
// pack_T: fp32 [b][256][P] -> bf16 [b][8][P][32]  (per-head/c-chunk transpose)
// ---------------------------------------------------------------------------
__global__ __launch_bounds__(256) void pack_T(
    const float* __restrict__ src, ushort* __restrict__ dst, int P)
{
    const int hn = blockIdx.y, bb = blockIdx.z;
    const int p0 = blockIdx.x * 64;
    __shared__ float L[32][73];
    const int tid = threadIdx.x;
    {
        const int c = tid >> 3, sg = tid & 7;
        const int p = p0 + sg*8;
        const float* s = src + ((size_t)bb*CC + hn*CH + c) * P + p;
        float4 a = {0,0,0,0}, b2 = {0,0,0,0};
        if (p < P) { a = *reinterpret_cast<const float4*>(s);
                     b2 = *reinterpret_cast<const float4*>(s + 4); }
        L[c][sg*8+0]=a.x;  L[c][sg*8+1]=a.y;  L[c][sg*8+2]=a.z;  L[c][sg*8+3]=a.w;
        L[c][sg*8+4]=b2.x; L[c][sg*8+5]=b2.y; L[c][sg*8+6]=b2.z; L[c][sg*8+7]=b2.w;
    }
    __syncthreads();
    {
        const int pl = tid >> 2, cs = (tid & 3) * 8;
        if (p0 + pl < P) {
            ushort o[8];
            #pragma unroll
            for (int j = 0; j < 8; j++) o[j] = f2bf(L[cs+j][pl]);
            uint4 v;
            v.x = o[0] | ((uint)o[1]<<16); v.y = o[2] | ((uint)o[3]<<16);
            v.z = o[4] | ((uint)o[5]<<16); v.w = o[6] | ((uint)o[7]<<16);
            *reinterpret_cast<uint4*>(dst + (((size_t)bb*NHEADS + hn)*P + p0 + pl)*32 + cs) = v;
        }
    }
}

// ---------------------------------------------------------------------------
// pack_cvt: flat fp32 -> bf16 (n4 = count/4)
// ---------------------------------------------------------------------------
__global__ __launch_bounds__(256) void pack_cvt(
    const float* __restrict__ src, ushort* __restrict__ dst, int n4)
{
    for (size_t i = (size_t)blockIdx.x * 256 + threadIdx.x; i < (size_t)n4;
         i += (size_t)gridDim.x * 256) {
        const float4 v = *reinterpret_cast<const float4*>(src + i*4);
        uint2 o;
        o.x = f2bf(v.x) | ((uint)f2bf(v.y) << 16);
        o.y = f2bf(v.z) | ((uint)f2bf(v.w) << 16);
        *reinterpret_cast<uint2*>(dst + i*4) = o;
    }
}

// ---------------------------------------------------------------------------
// bf16 MFMA projection GEMM with fused pack epilogues.
//   O[b][f][p] = sum_c W[f][c] X[b][c][pOff + p],  f,c = 256, p = ncols.
//   A = W rows (m=f, direct global, L2-hot); B = XP rows (n=p) from the
//   packed-T layout [b][8 c-chunk][P][32].
// Per block: 64f x 64p tile, wave w owns f-rows w*16..+15. 8 K-steps of 32.
// Epilogue stages C in LDS f32 and writes per `variant`:
//   0 = packed-T bf16 [b][8][OP][32]  (attention Q/K input layout)
//   1 = natural bf16  [b][256][OP]    (attention V input layout)
//   2 = natural fp32  [b][256][OP]
// ---------------------------------------------------------------------------
__global__ __launch_bounds__(256) void proj_mfma(
    const ushort* __restrict__ XPK, int P, int pOff, int ncols, int OP,
    const ushort* __restrict__ W0, const ushort* __restrict__ W1, const ushort* __restrict__ W2,
    void* __restrict__ O0, void* __restrict__ O1, void* __restrict__ O2,
    int v0, int v1, int v2)
{
    const int ptiles = (ncols + 63) >> 6;
    const int b  = blockIdx.x / ptiles;
    const int pt = blockIdx.x % ptiles;
    const int fbase = blockIdx.y * 64;
    const int z = blockIdx.z;
    const ushort* W = (z == 0) ? W0 : (z == 1) ? W1 : W2;
    void*        O = (z == 0) ? O0 : (z == 1) ? O1 : O2;
    const int variant = (z == 0) ? v0 : (z == 1) ? v1 : v2;

    const int tid = threadIdx.x, lane = tid & 63, w = tid >> 6;
    const int l15 = lane & 15, grp = lane >> 4;

    __shared__ float Cf[64][68];

    f32x4 acc[4];
    #pragma unroll
    for (int nt = 0; nt < 4; ++nt) acc[nt] = (f32x4){0.f, 0.f, 0.f, 0.f};

    const ushort* Wrow = W + (size_t)(fbase + w*16 + l15) * CC;
    int prow[4];
    #pragma unroll
    for (int nt = 0; nt < 4; ++nt) {
        const int p = pt*64 + nt*16 + l15;
        prow[nt] = (p < ncols) ? p : (ncols - 1);   // clamp: dup rows discarded
    }
    const size_t xb = (size_t)b * 8;

    #pragma unroll
    for (int kc = 0; kc < 8; ++kc) {
        const s8v aW = *reinterpret_cast<const s8v*>(Wrow + kc*32 + grp*8);
        #pragma unroll
        for (int nt = 0; nt < 4; ++nt) {
            const s8v bX = *reinterpret_cast<const s8v*>(
                XPK + ((xb + kc)*P + pOff + prow[nt])*32 + grp*8);
            acc[nt] = __builtin_amdgcn_mfma_f32_16x16x32_bf16(aW, bX, acc[nt], 0, 0, 0);
        }
    }
    #pragma unroll
    for (int nt = 0; nt < 4; ++nt)
        #pragma unroll
        for (int r = 0; r < 4; ++r)
            Cf[w*16 + grp*4 + r][nt*16 + l15] = acc[nt][r];
    __syncthreads();

    if (variant == 0) {
        ushort* dst = (ushort*)O;
        const int p_l = tid >> 2, c8 = (tid & 3) * 8;
        const int opos = pt*64 + p_l;
        if (opos < ncols) {
            #pragma unroll
            for (int hq = 0; hq < 2; ++hq) {
                ushort e[8];
                #pragma unroll
                for (int j = 0; j < 8; ++j) e[j] = f2bf(Cf[hq*32 + c8 + j][p_l]);
                uint4 v;
                v.x = e[0] | ((uint)e[1]<<16); v.y = e[2] | ((uint)e[3]<<16);
                v.z = e[4] | ((uint)e[5]<<16); v.w = e[6] | ((uint)e[7]<<16);
                *reinterpret_cast<uint4*>(
                    dst + (((size_t)b*NHEADS + (fbase >> 5) + hq)*OP + opos)*32 + c8) = v;
            }
        }
    } else if (variant == 1) {
        ushort* dst = (ushort*)O;
        #pragma unroll
        for (int pass = 0; pass < 2; ++pass) {
            const int idx = pass*256 + tid;
            const int f_l = idx >> 3, u = idx & 7;
            const int p0 = pt*64 + u*8;
            if (p0 < ncols) {   // ncols % 8 == 0 -> full vector valid
                ushort e[8];
                #pragma unroll
                for (int j = 0; j < 8; ++j) e[j] = f2bf(Cf[f_l][u*8 + j]);
                uint4 v;
                v.x = e[0] | ((uint)e[1]<<16); v.y = e[2] | ((uint)e[3]<<16);
                v.z = e[4] | ((uint)e[5]<<16); v.w = e[6] | ((uint)e[7]<<16);
                *reinterpret_cast<uint4*>(
                    dst + ((size_t)b*CC + fbase + f_l)*OP + p0) = v;
            }
        }
    } else {
        float* dst = (float*)O;
        #pragma unroll
        for (int pass = 0; pass < 2; ++pass) {
            const int idx = pass*256 + tid;
            const int f_l = idx >> 3, u = idx & 7;
            const int p0 = pt*64 + u*8;
            if (p0 < ncols) {
                float* dp = dst + ((size_t)b*CC + fbase + f_l)*OP + p0;
                *reinterpret_cast<float4*>(dp)     = *reinterpret_cast<const float4*>(&Cf[f_l][u*8]);
                *reinterpret_cast<float4*>(dp + 4) = *reinterpret_cast<const float4*>(&Cf[f_l][u*8 + 4]);
            }
        }
    }
}

// ---------------------------------------------------------------------------
// Demo attention — bf16 MFMA, 512 threads, 2 wave-groups split over j.
// ---------------------------------------------------------------------------
__global__ __launch_bounds__(512) void demo_attn_mfma(
    const ushort* __restrict__ QdP, const ushort* __restrict__ KdP,
    const ushort* __restrict__ VdP, ushort* __restrict__ dvattP)
{
    const int ib = blockIdx.x, hn = blockIdx.y, bb = blockIdx.z;
    const int tid = threadIdx.x;
    const int g   = tid >> 8;          // wave-group 0/1
    const int gt  = tid & 255;         // group-local tid
    const int lane = tid & 63;
    const int w    = (tid >> 6) & 3;   // group-local wave
    const int l15 = lane & 15, grp = lane >> 4;

    __shared__ __align__(16) ushort smem_d[14848];   // 29696 B
    ushort* Qc = smem_d;               // + g*2560
    ushort* Vc = smem_d + 5120;        // + g*2304

    const size_t hBase = ((size_t)bb*NHEADS + hn) * DPOS;
    const size_t vRow0 = ((size_t)bb*CC + hn*CH) * DPOS;

    const int i_glob = ib*64 + w*16 + l15;
    const s8v bK = *reinterpret_cast<const s8v*>(KdP + (hBase + i_glob)*32 + grp*8);

    auto fetchQ = [&](int j0) -> uint4 {
        const int r = gt >> 2, sg = gt & 3;
        return *reinterpret_cast<const uint4*>(QdP + (hBase + j0 + r)*32 + sg*8);
    };
    auto writeQ = [&](uint4 v) {
        const int r = gt >> 2, sg = gt & 3;
        *reinterpret_cast<uint4*>(&Qc[g*2560 + r*40 + sg*8]) = v;
    };
    auto fetchV = [&](int j0) -> uint4 {
        const int c = gt >> 3, sg = gt & 7;
        return *reinterpret_cast<const uint4*>(VdP + vRow0 + (size_t)c*DPOS + j0 + sg*8);
    };
    auto writeV = [&](uint4 v) {
        const int c = gt >> 3, sg = gt & 7;
        *reinterpret_cast<uint4*>(&Vc[g*2304 + c*72 + sg*8]) = v;
    };

    const int myFirst = g ? 7 : 0;
    const int myCount = g ? 6 : 7;

    writeQ(fetchQ(myFirst*64));
    writeV(fetchV(myFirst*64));
    f32x4 accO[2] = {{0.f,0.f,0.f,0.f}, {0.f,0.f,0.f,0.f}};
    float m_run = -1e30f, l_run = 0.f;
    __syncthreads();

    for (int it = 0; it < 7; ++it) {
        const bool active = (it < myCount);
        const int ch = myFirst + it;
        const bool pf = (it + 1 < myCount);
        uint4 nQ, nV;
        if (pf) { nQ = fetchQ((ch+1)*64); nV = fetchV((ch+1)*64); }

        if (active) {
            const int nt = (ch == 12) ? 1 : 4;
            f32x4 st[4];
            for (int jt = 0; jt < nt; ++jt) {
                const s8v aQ = *reinterpret_cast<const s8v*>(
                    &Qc[g*2560 + (jt*16 + l15)*40 + grp*8]);
                const f32x4 z = {0.f,0.f,0.f,0.f};
                st[jt] = __builtin_amdgcn_mfma_f32_16x16x32_bf16(aQ, bK, z, 0, 0, 0);
            }
            float mloc = -1e30f;
            for (int jt = 0; jt < nt; ++jt)
                #pragma unroll
                for (int r = 0; r < 4; ++r) {
                    const float v = st[jt][r] * INV_TEMP;
                    st[jt][r] = v;
                    mloc = fmaxf(mloc, v);
                }
            mloc = fmaxf(mloc, __shfl_xor(mloc, 16));
            mloc = fmaxf(mloc, __shfl_xor(mloc, 32));
            const float mnew  = fmaxf(m_run, mloc);
            const float scale = __expf(m_run - mnew);
            m_run = mnew;
            float lsum = 0.f;
            for (int jt = 0; jt < nt; ++jt)
                #pragma unroll
                for (int r = 0; r < 4; ++r) {
                    const float e = __expf(st[jt][r] - mnew);
                    st[jt][r] = e;
                    lsum += e;
                }
            lsum += __shfl_xor(lsum, 16);
            lsum += __shfl_xor(lsum, 32);
            l_run = l_run * scale + lsum;
            #pragma unroll
            for (int ct = 0; ct < 2; ++ct)
                #pragma unroll
                for (int r = 0; r < 4; ++r) accO[ct][r] *= scale;

            for (int jt = 0; jt < nt; ++jt) {
                s4v pf4;
                #pragma unroll
                for (int r = 0; r < 4; ++r) pf4[r] = (short)f2bf(st[jt][r]);
                #pragma unroll
                for (int ct = 0; ct < 2; ++ct) {
                    const s4v aV = *reinterpret_cast<const s4v*>(
                        &Vc[g*2304 + (ct*16 + l15)*72 + jt*16 + grp*4]);
                    accO[ct] = mfma_pv(aV, pf4, accO[ct]);
                }
            }
        }
        __syncthreads();
        if (pf) { writeQ(nQ); writeV(nV); }
        __syncthreads();
    }

    // ---- merge group 1 into group 0 (flash combine) ----
    float* mbase = reinterpret_cast<float*>(smem_d + 9728);
    float* Mb = mbase;          // [4][64]
    float* Lb = mbase + 256;    // [4][64]
    float* Ob = mbase + 512;    // [4][64][8]
    if (g == 1) {
        Mb[w*64 + lane] = m_run;
        Lb[w*64 + lane] = l_run;
        #pragma unroll
        for (int ct = 0; ct < 2; ++ct)
            #pragma unroll
            for (int r = 0; r < 4; ++r)
                Ob[(w*64 + lane)*8 + ct*4 + r] = accO[ct][r];
    }
    __syncthreads();
    if (g == 0) {
        const float m1 = Mb[w*64 + lane], l1 = Lb[w*64 + lane];
        const float mm = fmaxf(m_run, m1);
        const float s0 = __expf(m_run - mm), s1 = __expf(m1 - mm);
        const float linv = 1.f / (l_run * s0 + l1 * s1);
        #pragma unroll
        for (int ct = 0; ct < 2; ++ct)
            #pragma unroll
            for (int r = 0; r < 4; ++r) {
                const float o = (accO[ct][r]*s0 + Ob[(w*64 + lane)*8 + ct*4 + r]*s1) * linv;
                Vc[(ct*16 + grp*4 + r)*72 + w*16 + l15] = f2bf(o);
            }
    }
    __syncthreads();
    if (g == 0) {
        const int c = gt >> 3, sg = gt & 7;
        const int col = ib*64 + sg*8;
        if (col < DPOS) {
            const uint4 v = *reinterpret_cast<const uint4*>(&Vc[c*72 + sg*8]);
            *reinterpret_cast<uint4*>(dvattP + vRow0 + (size_t)c*DPOS + col) = v;
        }
    }
}

// ---------------------------------------------------------------------------
// Obs attention per (b, t, n) — bf16 MFMA, 512 threads, 2 wave-groups over p.
// Output now written as packed-T bf16 mergedP [b][8][OPOS][32] (the
// out-projection's B-operand layout) — no fp32 merged buffer.
// ---------------------------------------------------------------------------
__global__ __launch_bounds__(512) void obs_attn_mfma(
    const ushort* __restrict__ KdP, const ushort* __restrict__ KoP,
    const ushort* __restrict__ QP,  const ushort* __restrict__ VdP,
    const ushort* __restrict__ VoP, ushort* __restrict__ mergedP)
{
    const int tt = blockIdx.x, hn = blockIdx.y, bb = blockIdx.z;
    __shared__ __align__(16) ushort smem_u[27136];   // 54272 B
    ushort* QT = smem_u;            // [208][40]
    ushort* KT = smem_u + 8320;     // [2][64][40]
    ushort* VT = smem_u + 13440;    // [2][32][72]

    const int tid  = threadIdx.x;
    const int g    = tid >> 8;
    const int gt   = tid & 255;
    const int lane = tid & 63;
    const int w    = (tid >> 6) & 3;
    const int l15  = lane & 15, grp = lane >> 4;

    const size_t kdBase = ((size_t)bb*NHEADS + hn) * DPOS * 32;
    const size_t koBase = ((size_t)bb*NHEADS + hn) * OPOS * 32 + (size_t)tt*HW*32;
    const size_t vdRow0 = ((size_t)bb*CC + hn*CH) * DPOS;
    const size_t voRow0 = ((size_t)bb*CC + hn*CH) * OPOS + (size_t)tt*HW;

    auto fetchK = [&](int cp) -> uint4 {
        const int r = gt >> 2, sg = gt & 3;
        const int p = cp + r;
        uint4 v = {0,0,0,0};
        if (p < DPOS)      v = *reinterpret_cast<const uint4*>(KdP + kdBase + (size_t)p*32 + sg*8);
        else if (p < NPOS) v = *reinterpret_cast<const uint4*>(KoP + koBase + (size_t)(p-DPOS)*32 + sg*8);
        return v;
    };
    auto writeK = [&](uint4 v) {
        const int r = gt >> 2, sg = gt & 3;
        *reinterpret_cast<uint4*>(&KT[(g*64 + r)*40 + sg*8]) = v;
    };
    auto fetchV = [&](int cp) -> uint4 {
        const int c = gt >> 3, sg = gt & 7;
        const int p0 = cp + sg*8;
        uint4 v = {0,0,0,0};
        const size_t vd = vdRow0 + (size_t)c*DPOS;
        const size_t vo = voRow0 + (size_t)c*OPOS;
        if (p0 + 7 < DPOS) {
            uint2 a  = *reinterpret_cast<const uint2*>(VdP + vd + p0);
            uint2 b2 = *reinterpret_cast<const uint2*>(VdP + vd + p0 + 4);
            v.x=a.x; v.y=a.y; v.z=b2.x; v.w=b2.y;
        } else if (p0 >= DPOS && p0 + 7 < NPOS) {
            uint2 a  = *reinterpret_cast<const uint2*>(VoP + vo + (p0-DPOS));
            uint2 b2 = *reinterpret_cast<const uint2*>(VoP + vo + (p0-DPOS) + 4);
            v.x=a.x; v.y=a.y; v.z=b2.x; v.w=b2.y;
        } else if (p0 < NPOS) {
            ushort e[8];
            #pragma unroll
            for (int j = 0; j < 8; j++) {
                const int p = p0 + j;
                e[j] = (p < DPOS) ? VdP[vd + p]
                     : (p < NPOS ? VoP[vo + (p-DPOS)] : (ushort)0);
            }
            v.x = e[0] | ((uint)e[1] << 16); v.y = e[2] | ((uint)e[3] << 16);
            v.z = e[4] | ((uint)e[5] << 16); v.w = e[6] | ((uint)e[7] << 16);
        }
        return v;
    };
    auto writeV = [&](uint4 v) {
        const int c = gt >> 3, sg = gt & 7;
        *reinterpret_cast<uint4*>(&VT[(g*32 + c)*72 + sg*8]) = v;
    };

    for (int idx = tid; idx < 832; idx += 512) {
        const int r = idx >> 2, sg = idx & 3;
        uint4 v = {0,0,0,0};
        if (r < HW) v = *reinterpret_cast<const uint4*>(QP + koBase + (size_t)r*32 + sg*8);
        *reinterpret_cast<uint4*>(&QT[r*40 + sg*8]) = v;
    }
    writeK(fetchK(g*512));
    writeV(fetchV(g*512));

    f32x4 accO[2][13];
    #pragma unroll
    for (int ct = 0; ct < 2; ++ct)
        #pragma unroll
        for (int qt = 0; qt < 13; ++qt)
            accO[ct][qt] = (f32x4){0.f, 0.f, 0.f, 0.f};
    __syncthreads();

    for (int it = 0; it < 8; ++it) {
        uint4 nk = {0,0,0,0}, nv = {0,0,0,0};
        if (it < 7) { nk = fetchK((g*8 + it + 1)*64); nv = fetchV((g*8 + it + 1)*64); }

        const s8v aK = *reinterpret_cast<const s8v*>(&KT[(g*64 + w*16 + l15)*40 + grp*8]);
        f32x4 ss[13];
        #pragma unroll
        for (int qt = 0; qt < 13; ++qt) {
            const s8v bQ = *reinterpret_cast<const s8v*>(&QT[(qt*16 + l15)*40 + grp*8]);
            const f32x4 z = {0.f, 0.f, 0.f, 0.f};
            ss[qt] = __builtin_amdgcn_mfma_f32_16x16x32_bf16(aK, bQ, z, 0, 0, 0);
        }
        #pragma unroll
        for (int r = 0; r < 4; ++r) {
            float m = -1e30f;
            #pragma unroll
            for (int qt = 0; qt < 13; ++qt) {
                float v = ss[qt][r] * INV_TEMP;
                if (qt == 12 && l15 >= 4) v = -1e30f;   // q >= 196 pad
                ss[qt][r] = v;
                m = fmaxf(m, v);
            }
            m = fmaxf(m, __shfl_xor(m, 1));
            m = fmaxf(m, __shfl_xor(m, 2));
            m = fmaxf(m, __shfl_xor(m, 4));
            m = fmaxf(m, __shfl_xor(m, 8));
            float sum = 0.f;
            #pragma unroll
            for (int qt = 0; qt < 13; ++qt) {
                const float e = __expf(ss[qt][r] - m);
                ss[qt][r] = e;
                sum += e;
            }
            sum += __shfl_xor(sum, 1);
            sum += __shfl_xor(sum, 2);
            sum += __shfl_xor(sum, 4);
            sum += __shfl_xor(sum, 8);
            const float is = 1.f / sum;
            #pragma unroll
            for (int qt = 0; qt < 13; ++qt) ss[qt][r] *= is;
        }
        s4v pf[13];
        #pragma unroll
        for (int qt = 0; qt < 13; ++qt) {
            s4v p4;
            #pragma unroll
            for (int r = 0; r < 4; ++r) p4[r] = (short)f2bf(ss[qt][r]);
            pf[qt] = p4;
        }
        #pragma unroll
        for (int ct = 0; ct < 2; ++ct) {
            const s4v aV = *reinterpret_cast<const s4v*>(
                &VT[(g*32 + ct*16 + l15)*72 + w*16 + grp*4]);
            #pragma unroll
            for (int qt = 0; qt < 13; ++qt)
                accO[ct][qt] = mfma_pv(aV, pf[qt], accO[ct][qt]);
        }
        __syncthreads();
        if (it < 7) { writeK(nk); writeV(nv); __syncthreads(); }
    }

    // ---- per-group 4-wave reduction into Ored[g] ----
    float* OredF = reinterpret_cast<float*>(smem_u);   // [2][32][212]
    float* Og = OredF + g * 6784;
    for (int wv = 0; wv < 4; ++wv) {
        if (w == wv) {
            #pragma unroll
            for (int ct = 0; ct < 2; ++ct)
                #pragma unroll
                for (int qt = 0; qt < 13; ++qt)
                    #pragma unroll
                    for (int r = 0; r < 4; ++r) {
                        const int c = ct*16 + grp*4 + r;
                        const int q = qt*16 + l15;
                        if (wv == 0) Og[c*212 + q]  = accO[ct][qt][r];
                        else         Og[c*212 + q] += accO[ct][qt][r];
                    }
        }
        __syncthreads();
    }
    // add group partials, convert, store packed-T bf16 [q][32c]
    for (int idx = tid; idx < HW*4; idx += 512) {
        const int q = idx >> 2, c8 = (idx & 3) * 8;
        ushort e[8];
        #pragma unroll
        for (int j = 0; j < 8; ++j) {
            const int c = c8 + j;
            e[j] = f2bf(OredF[c*212 + q] + OredF[6784 + c*212 + q]);
        }
        uint4 v;
        v.x = e[0] | ((uint)e[1]<<16); v.y = e[2] | ((uint)e[3]<<16);
        v.z = e[4] | ((uint)e[5]<<16); v.w = e[6] | ((uint)e[7]<<16);
        *reinterpret_cast<uint4*>(
            mergedP + (((size_t)bb*NHEADS + hn)*OPOS + (size_t)tt*HW + q)*32 + c8) = v;
    }
}

// ---------------------------------------------------------------------------
// Fused residual-ReLU + concat + BatchNorm. One block per channel. float4.
// ---------------------------------------------------------------------------
__global__ __launch_bounds__(256) void bn_fuse(
    const float* __restrict__ xin, const float* __restrict__ obsout,
    const float* __restrict__ gamma, const float* __restrict__ beta,
    float* __restrict__ xout)
{
    const int c = blockIdx.x;
    const int tid = threadIdx.x;
    float sum = 0.f, sumsq = 0.f;
    for (int idx = tid; idx < BB*(DPOS/4); idx += 256) {
        const int b = idx / (DPOS/4), pos = idx % (DPOS/4);
        const float4 v = *reinterpret_cast<const float4*>(
            &xin[((size_t)b*CC + c) * XROW + pos*4]);
        sum   += v.x + v.y + v.z + v.w;
        sumsq += v.x*v.x + v.y*v.y + v.z*v.z + v.w*v.w;
    }
    for (int idx = tid; idx < BB*(OPOS/4); idx += 256) {
        const int b = idx / (OPOS/4), pos = idx % (OPOS/4);
        const float4 xv = *reinterpret_cast<const float4*>(
            &xin[((size_t)b*CC + c) * XROW + DPOS + pos*4]);
        const float4 ov = *reinterpret_cast<const float4*>(
            &obsout[((size_t)b*CC + c) * OPOS + pos*4]);
        const float4 v = make_float4(xv.x + fmaxf(ov.x, 0.f), xv.y + fmaxf(ov.y, 0.f),
                                     xv.z + fmaxf(ov.z, 0.f), xv.w + fmaxf(ov.w, 0.f));
        sum   += v.x + v.y + v.z + v.w;
        sumsq += v.x*v.x + v.y*v.y + v.z*v.z + v.w*v.w;
    }
    #pragma unroll
    for (int off = 32; off > 0; off >>= 1) {
        sum   += __shfl_xor(sum, off);
        sumsq += __shfl_xor(sumsq, off);
    }
    __shared__ float ssum[4], ssq[4];
    __shared__ float s_mean, s_inv;
    const int lane = tid & 63, w = tid >> 6;
    if (lane == 0) { ssum[w] = sum; ssq[w] = sumsq; }
    __syncthreads();
    if (tid == 0) {
        float s  = ssum[0] + ssum[1] + ssum[2] + ssum[3];
        float sq = ssq[0] + ssq[1] + ssq[2] + ssq[3];
        const float mean = s / 12544.f;
        const float var  = sq / 12544.f - mean * mean;
        s_mean = mean;
        s_inv  = rsqrtf(var + 1e-5f);
    }
    __syncthreads();
    const float mean = s_mean;
    const float gi = gamma[c] * s_inv;
    const float bt = beta[c];
    for (int idx = tid; idx < BB*(DPOS/4); idx += 256) {
        const int b = idx / (DPOS/4), pos = idx % (DPOS/4);
        const size_t o = ((size_t)b*CC + c) * XROW + pos*4;
        const float4 v = *reinterpret_cast<const float4*>(&xin[o]);
        const float4 r = make_float4((v.x-mean)*gi+bt, (v.y-mean)*gi+bt,
                                     (v.z-mean)*gi+bt, (v.w-mean)*gi+bt);
        *reinterpret_cast<float4*>(&xout[o]) = r;
    }
    for (int idx = tid; idx < BB*(OPOS/4); idx += 256) {
        const int b = idx / (OPOS/4), pos = idx % (OPOS/4);
        const float4 xv = *reinterpret_cast<const float4*>(
            &xin[((size_t)b*CC + c) * XROW + DPOS + pos*4]);
        const float4 ov = *reinterpret_cast<const float4*>(
            &obsout[((size_t)b*CC + c) * OPOS + pos*4]);
        const float4 v = make_float4(xv.x + fmaxf(ov.x, 0.f), xv.y + fmaxf(ov.y, 0.f),
                                     xv.z + fmaxf(ov.z, 0.f), xv.w + fmaxf(ov.w, 0.f));
        const float4 r = make_float4((v.x-mean)*gi+bt, (v.y-mean)*gi+bt,
                                     (v.z-mean)*gi+bt, (v.w-mean)*gi+bt);
        *reinterpret_cast<float4*>(&xout[((size_t)b*CC + c) * XROW + DPOS + pos*4]) = r;
    }
}

// ---------------------------------------------------------------------------
extern "C" void kernel_launch(void* const* d_in, const int* in_sizes, int n_in,
                              void* d_out, int out_size, void* d_ws, size_t ws_size,
                              hipStream_t stream)
{
    const float* x   = (const float*)d_in[0];
    const float* dqw = (const float*)d_in[1];
    const float* dkw = (const float*)d_in[2];
    const float* dvw = (const float*)d_in[3];
    const float* oqw = (const float*)d_in[4];
    const float* okw = (const float*)d_in[5];
    const float* ovw = (const float*)d_in[6];
    const float* oow = (const float*)d_in[7];
    const float* gam = (const float*)d_in[8];
    const float* bet = (const float*)d_in[9];

    const size_t XN = (size_t)BB * CC * TT * HW;   // 3,211,264
    const size_t DN = (size_t)BB * CC * DPOS;      //   802,816
    const size_t ON = (size_t)BB * CC * OPOS;      // 2,408,448
    const size_t WN = (size_t)3 * CC * CC;         //   196,608 (per weight tensor, all layers)

    // ws layout (no aliasing needed; total ~70 MB)
    float*  xb0     = (float*)d_ws;
    float*  xb1     = xb0 + XN;
    float*  obsout  = xb1 + XN;
    ushort* XP      = (ushort*)(obsout + ON);     // [b][8][3136][32]
    ushort* QdP     = XP + XN;
    ushort* KdP     = QdP + DN;
    ushort* VdemoP  = KdP + DN;
    ushort* dvattP  = VdemoP + DN;
    ushort* QP      = dvattP + DN;
    ushort* KoP     = QP + ON;
    ushort* VoP     = KoP + ON;
    ushort* mergedP = VoP + ON;
    ushort* wpk     = mergedP + ON;
    ushort* dqwb = wpk;          ushort* dkwb = wpk + WN;   ushort* dvwb = wpk + 2*WN;
    ushort* oqwb = wpk + 3*WN;   ushort* okwb = wpk + 4*WN; ushort* ovwb = wpk + 5*WN;
    ushort* oowb = wpk + 6*WN;

    const dim3 blk(256);
    const dim3 blk2(512);

    // weight bf16 packs (all layers at once)
    pack_cvt<<<dim3(192), blk, 0, stream>>>(dqw, dqwb, (int)(WN/4));
    pack_cvt<<<dim3(192), blk, 0, stream>>>(dkw, dkwb, (int)(WN/4));
    pack_cvt<<<dim3(192), blk, 0, stream>>>(dvw, dvwb, (int)(WN/4));
    pack_cvt<<<dim3(192), blk, 0, stream>>>(oqw, oqwb, (int)(WN/4));
    pack_cvt<<<dim3(192), blk, 0, stream>>>(okw, okwb, (int)(WN/4));
    pack_cvt<<<dim3(192), blk, 0, stream>>>(ovw, ovwb, (int)(WN/4));
    pack_cvt<<<dim3(192), blk, 0, stream>>>(oow, oowb, (int)(WN/4));

    for (int i = 0; i < 3; i++) {
        const float* xin  = (i == 0) ? x : (i == 1 ? xb0 : xb1);
        float*       xout = (i == 2) ? (float*)d_out : (i == 0 ? xb0 : xb1);
        const size_t wB = (size_t)i * CC * CC;

        // 1: pack x -> XP (per-32-channel-chunk transposed bf16)
        pack_T<<<dim3(49, 8, BB), blk, 0, stream>>>(xin, XP, XROW);

        // 2: demo projections (MFMA) -> packed Q/K, natural-bf16 V
        proj_mfma<<<dim3(BB*13, 4, 3), blk, 0, stream>>>(
            XP, XROW, 0, DPOS, DPOS,
            dqwb + wB, dkwb + wB, dvwb + wB,
            QdP, KdP, VdemoP, 0, 0, 1);

        // 3: demo attention
        demo_attn_mfma<<<dim3(13, NHEADS, BB), blk2, 0, stream>>>(
            QdP, KdP, VdemoP, dvattP);

        // 4: obs projections (MFMA)
        proj_mfma<<<dim3(BB*37, 4, 3), blk, 0, stream>>>(
            XP, XROW, DPOS, OPOS, OPOS,
            oqwb + wB, okwb + wB, ovwb + wB,
            QP, KoP, VoP, 0, 0, 1);

        // 5: obs attention -> mergedP (packed-T bf16)
        obs_attn_mfma<<<dim3(OBS_T, NHEADS, BB), blk2, 0, stream>>>(
            KdP, KoP, QP, dvattP, VoP, mergedP);

        // 6: output projection (MFMA, fp32 out)
        proj_mfma<<<dim3(BB*37, 4, 1), blk, 0, stream>>>(
            mergedP, OPOS, 0, OPOS, OPOS,
            oowb + wB, oowb + wB, oowb + wB,
            obsout, obsout, obsout, 2, 2, 2);

        // 7: residual + BN
        bn_fuse<<<dim3(CC), blk, 0, stream>>>(xin, obsout, gam + i*CC, bet + i*CC, xout);
    }
}

// Round 7
// 497.036 us; speedup vs baseline: 7.6787x; 1.0440x over previous
//
#include <hip/hip_runtime.h>
#include <hip/hip_bf16.h>

// Problem constants
#define BB 4
#define CC 256
#define TT 16
#define HW 196
#define DEMO_T 4
#define OBS_T 12
#define DPOS 784      // DEMO_T*HW
#define OPOS 2352     // OBS_T*HW
#define XROW 3136     // TT*HW
#define NHEADS 8
#define CH 32
#define NPOS 980      // DPOS + HW (cat keys per (b,t,n))

typedef float  f32x4 __attribute__((ext_vector_type(4)));
typedef short  s8v   __attribute__((ext_vector_type(8)));
typedef short  s4v   __attribute__((ext_vector_type(4)));

static __device__ __forceinline__ ushort f2bf(float f) {
    union { float f; uint u; } x; x.f = f;
    const uint r = x.u + 0x7FFF + ((x.u >> 16) & 1);   // RNE
    return (ushort)(r >> 16);
}

static __device__ __forceinline__ f32x4 mfma_pv(s4v a, s4v b, f32x4 c) {
#if __has_builtin(__builtin_amdgcn_mfma_f32_16x16x16bf16_1k)
    return __builtin_amdgcn_mfma_f32_16x16x16bf16_1k(a, b, c, 0, 0, 0);
#else
    s8v a8 = {a[0], a[1], a[2], a[3], 0, 0, 0, 0};
    s8v b8 = {b[0], b[1], b[2], b[3], 0, 0, 0, 0};
    return __builtin_amdgcn_mfma_f32_16x16x32_bf16(a8, b8, c, 0, 0, 0);
#endif
}

// ---------------------------------------------------------------------------
// pack_T: fp32 [b][256][P] -> bf16 [b][8][P][32]  (per-c-chunk transpose)
// ---------------------------------------------------------------------------
__global__ __launch_bounds__(256) void pack_T(
    const float* __restrict__ src, ushort* __restrict__ dst, int P)
{
    const int hn = blockIdx.y, bb = blockIdx.z;
    const int p0 = blockIdx.x * 64;
    __shared__ float L[32][73];
    const int tid = threadIdx.x;
    {
        const int c = tid >> 3, sg = tid & 7;
        const int p = p0 + sg*8;
        const float* s = src + ((size_t)bb*CC + hn*CH + c) * P + p;
        float4 a = {0,0,0,0}, b2 = {0,0,0,0};
        if (p < P) { a = *reinterpret_cast<const float4*>(s);
                     b2 = *reinterpret_cast<const float4*>(s + 4); }
        L[c][sg*8+0]=a.x;  L[c][sg*8+1]=a.y;  L[c][sg*8+2]=a.z;  L[c][sg*8+3]=a.w;
        L[c][sg*8+4]=b2.x; L[c][sg*8+5]=b2.y; L[c][sg*8+6]=b2.z; L[c][sg*8+7]=b2.w;
    }
    __syncthreads();
    {
        const int pl = tid >> 2, cs = (tid & 3) * 8;
        if (p0 + pl < P) {
            ushort o[8];
            #pragma unroll
            for (int j = 0; j < 8; j++) o[j] = f2bf(L[cs+j][pl]);
            uint4 v;
            v.x = o[0] | ((uint)o[1]<<16); v.y = o[2] | ((uint)o[3]<<16);
            v.z = o[4] | ((uint)o[5]<<16); v.w = o[6] | ((uint)o[7]<<16);
            *reinterpret_cast<uint4*>(dst + (((size_t)bb*NHEADS + hn)*P + p0 + pl)*32 + cs) = v;
        }
    }
}

// ---------------------------------------------------------------------------
// pack_cvt: flat fp32 -> bf16 (n4 = count/4)
// ---------------------------------------------------------------------------
__global__ __launch_bounds__(256) void pack_cvt(
    const float* __restrict__ src, ushort* __restrict__ dst, int n4)
{
    for (size_t i = (size_t)blockIdx.x * 256 + threadIdx.x; i < (size_t)n4;
         i += (size_t)gridDim.x * 256) {
        const float4 v = *reinterpret_cast<const float4*>(src + i*4);
        uint2 o;
        o.x = f2bf(v.x) | ((uint)f2bf(v.y) << 16);
        o.y = f2bf(v.z) | ((uint)f2bf(v.w) << 16);
        *reinterpret_cast<uint2*>(dst + i*4) = o;
    }
}

// ---------------------------------------------------------------------------
// bf16 MFMA projection GEMM with fused pack epilogues (+ per-z output scale,
// used to fold the attention 1/TEMP into Q at pack time — 1/16 is a power of
// two, bit-exact in bf16).
//   variant 0 = packed-T bf16 [b][8][OP][32]; 1 = natural bf16 [b][256][OP];
//   2 = natural fp32 [b][256][OP]
// ---------------------------------------------------------------------------
__global__ __launch_bounds__(256) void proj_mfma(
    const ushort* __restrict__ XPK, int P, int pOff, int ncols, int OP,
    const ushort* __restrict__ W0, const ushort* __restrict__ W1, const ushort* __restrict__ W2,
    void* __restrict__ O0, void* __restrict__ O1, void* __restrict__ O2,
    int v0, int v1, int v2, float sc0, float sc1, float sc2)
{
    const int ptiles = (ncols + 63) >> 6;
    const int b  = blockIdx.x / ptiles;
    const int pt = blockIdx.x % ptiles;
    const int fbase = blockIdx.y * 64;
    const int z = blockIdx.z;
    const ushort* W = (z == 0) ? W0 : (z == 1) ? W1 : W2;
    void*        O = (z == 0) ? O0 : (z == 1) ? O1 : O2;
    const int variant = (z == 0) ? v0 : (z == 1) ? v1 : v2;
    const float sc    = (z == 0) ? sc0 : (z == 1) ? sc1 : sc2;

    const int tid = threadIdx.x, lane = tid & 63, w = tid >> 6;
    const int l15 = lane & 15, grp = lane >> 4;

    __shared__ float Cf[64][68];

    f32x4 acc[4];
    #pragma unroll
    for (int nt = 0; nt < 4; ++nt) acc[nt] = (f32x4){0.f, 0.f, 0.f, 0.f};

    const ushort* Wrow = W + (size_t)(fbase + w*16 + l15) * CC;
    int prow[4];
    #pragma unroll
    for (int nt = 0; nt < 4; ++nt) {
        const int p = pt*64 + nt*16 + l15;
        prow[nt] = (p < ncols) ? p : (ncols - 1);   // clamp: dup rows discarded
    }
    const size_t xb = (size_t)b * 8;

    #pragma unroll
    for (int kc = 0; kc < 8; ++kc) {
        const s8v aW = *reinterpret_cast<const s8v*>(Wrow + kc*32 + grp*8);
        #pragma unroll
        for (int nt = 0; nt < 4; ++nt) {
            const s8v bX = *reinterpret_cast<const s8v*>(
                XPK + ((xb + kc)*P + pOff + prow[nt])*32 + grp*8);
            acc[nt] = __builtin_amdgcn_mfma_f32_16x16x32_bf16(aW, bX, acc[nt], 0, 0, 0);
        }
    }
    #pragma unroll
    for (int nt = 0; nt < 4; ++nt)
        #pragma unroll
        for (int r = 0; r < 4; ++r)
            Cf[w*16 + grp*4 + r][nt*16 + l15] = acc[nt][r] * sc;
    __syncthreads();

    if (variant == 0) {
        ushort* dst = (ushort*)O;
        const int p_l = tid >> 2, c8 = (tid & 3) * 8;
        const int opos = pt*64 + p_l;
        if (opos < ncols) {
            #pragma unroll
            for (int hq = 0; hq < 2; ++hq) {
                ushort e[8];
                #pragma unroll
                for (int j = 0; j < 8; ++j) e[j] = f2bf(Cf[hq*32 + c8 + j][p_l]);
                uint4 v;
                v.x = e[0] | ((uint)e[1]<<16); v.y = e[2] | ((uint)e[3]<<16);
                v.z = e[4] | ((uint)e[5]<<16); v.w = e[6] | ((uint)e[7]<<16);
                *reinterpret_cast<uint4*>(
                    dst + (((size_t)b*NHEADS + (fbase >> 5) + hq)*OP + opos)*32 + c8) = v;
            }
        }
    } else if (variant == 1) {
        ushort* dst = (ushort*)O;
        #pragma unroll
        for (int pass = 0; pass < 2; ++pass) {
            const int idx = pass*256 + tid;
            const int f_l = idx >> 3, u = idx & 7;
            const int p0 = pt*64 + u*8;
            if (p0 < ncols) {
                ushort e[8];
                #pragma unroll
                for (int j = 0; j < 8; ++j) e[j] = f2bf(Cf[f_l][u*8 + j]);
                uint4 v;
                v.x = e[0] | ((uint)e[1]<<16); v.y = e[2] | ((uint)e[3]<<16);
                v.z = e[4] | ((uint)e[5]<<16); v.w = e[6] | ((uint)e[7]<<16);
                *reinterpret_cast<uint4*>(
                    dst + ((size_t)b*CC + fbase + f_l)*OP + p0) = v;
            }
        }
    } else {
        float* dst = (float*)O;
        #pragma unroll
        for (int pass = 0; pass < 2; ++pass) {
            const int idx = pass*256 + tid;
            const int f_l = idx >> 3, u = idx & 7;
            const int p0 = pt*64 + u*8;
            if (p0 < ncols) {
                float* dp = dst + ((size_t)b*CC + fbase + f_l)*OP + p0;
                *reinterpret_cast<float4*>(dp)     = *reinterpret_cast<const float4*>(&Cf[f_l][u*8]);
                *reinterpret_cast<float4*>(dp + 4) = *reinterpret_cast<const float4*>(&Cf[f_l][u*8 + 4]);
            }
        }
    }
}

// ---------------------------------------------------------------------------
// Demo attention — bf16 MFMA, 512 threads, BARRIER-FREE main loop.
// All operands read directly from global (packed layouts == fragment
// layouts); waves fully independent until the final flash merge.
// Group g (waves 0-3 / 4-7) takes j-chunks 0..6 / 7..12; Q is pre-scaled
// by 1/16 at pack time.
// ---------------------------------------------------------------------------
__global__ __launch_bounds__(512) void demo_attn_mfma(
    const ushort* __restrict__ QdP, const ushort* __restrict__ KdP,
    const ushort* __restrict__ VdP, ushort* __restrict__ dvattP)
{
    const int ib = blockIdx.x, hn = blockIdx.y, bb = blockIdx.z;
    const int tid = threadIdx.x;
    const int g   = tid >> 8;          // j-half
    const int gt  = tid & 255;
    const int lane = tid & 63;
    const int w    = (tid >> 6) & 3;   // i-quarter
    const int l15 = lane & 15, grp = lane >> 4;

    __shared__ float mrg[2560];                       // Mb[256] Lb[256] Ob[2048]
    __shared__ __align__(16) ushort OutS[32*72];

    const size_t hBase = ((size_t)bb*NHEADS + hn) * DPOS;
    const size_t vRow0 = ((size_t)bb*CC + hn*CH) * DPOS;

    const int i_glob = ib*64 + w*16 + l15;
    const s8v bK = *reinterpret_cast<const s8v*>(KdP + (hBase + i_glob)*32 + grp*8);

    f32x4 accO[2] = {{0.f,0.f,0.f,0.f}, {0.f,0.f,0.f,0.f}};
    float m_run = -1e30f, l_run = 0.f;

    const int chFirst = g ? 7 : 0;
    const int chEnd   = g ? 13 : 7;
    for (int ch = chFirst; ch < chEnd; ++ch) {
        const int nt = (ch == 12) ? 1 : 4;
        f32x4 st[4];
        for (int jt = 0; jt < nt; ++jt) {
            const s8v aQ = *reinterpret_cast<const s8v*>(
                QdP + (hBase + ch*64 + jt*16 + l15)*32 + grp*8);
            const f32x4 z = {0.f,0.f,0.f,0.f};
            st[jt] = __builtin_amdgcn_mfma_f32_16x16x32_bf16(aQ, bK, z, 0, 0, 0);
        }
        float mloc = -1e30f;
        for (int jt = 0; jt < nt; ++jt)
            #pragma unroll
            for (int r = 0; r < 4; ++r) mloc = fmaxf(mloc, st[jt][r]);
        mloc = fmaxf(mloc, __shfl_xor(mloc, 16));
        mloc = fmaxf(mloc, __shfl_xor(mloc, 32));
        const float mnew  = fmaxf(m_run, mloc);
        const float scale = __expf(m_run - mnew);
        m_run = mnew;
        float lsum = 0.f;
        for (int jt = 0; jt < nt; ++jt)
            #pragma unroll
            for (int r = 0; r < 4; ++r) {
                const float e = __expf(st[jt][r] - mnew);
                st[jt][r] = e;
                lsum += e;
            }
        lsum += __shfl_xor(lsum, 16);
        lsum += __shfl_xor(lsum, 32);
        l_run = l_run * scale + lsum;
        #pragma unroll
        for (int ct = 0; ct < 2; ++ct)
            #pragma unroll
            for (int r = 0; r < 4; ++r) accO[ct][r] *= scale;

        for (int jt = 0; jt < nt; ++jt) {
            s4v pf4;
            #pragma unroll
            for (int r = 0; r < 4; ++r) pf4[r] = (short)f2bf(st[jt][r]);
            #pragma unroll
            for (int ct = 0; ct < 2; ++ct) {
                const s4v aV = *reinterpret_cast<const s4v*>(
                    VdP + vRow0 + (size_t)(ct*16 + l15)*DPOS + ch*64 + jt*16 + grp*4);
                accO[ct] = mfma_pv(aV, pf4, accO[ct]);
            }
        }
    }

    // ---- flash merge: group 1 -> group 0 ----
    float* Mb = mrg;
    float* Lb = mrg + 256;
    float* Ob = mrg + 512;
    if (g == 1) {
        Mb[w*64 + lane] = m_run;
        Lb[w*64 + lane] = l_run;
        #pragma unroll
        for (int ct = 0; ct < 2; ++ct)
            #pragma unroll
            for (int r = 0; r < 4; ++r)
                Ob[(w*64 + lane)*8 + ct*4 + r] = accO[ct][r];
    }
    __syncthreads();
    if (g == 0) {
        const float m1 = Mb[w*64 + lane], l1 = Lb[w*64 + lane];
        const float mm = fmaxf(m_run, m1);
        const float s0 = __expf(m_run - mm), s1 = __expf(m1 - mm);
        const float linv = 1.f / (l_run * s0 + l1 * s1);
        #pragma unroll
        for (int ct = 0; ct < 2; ++ct)
            #pragma unroll
            for (int r = 0; r < 4; ++r) {
                const float o = (accO[ct][r]*s0 + Ob[(w*64 + lane)*8 + ct*4 + r]*s1) * linv;
                OutS[(ct*16 + grp*4 + r)*72 + w*16 + l15] = f2bf(o);
            }
    }
    __syncthreads();
    if (g == 0) {
        const int c = gt >> 3, sg = gt & 7;
        const int col = ib*64 + sg*8;
        if (col < DPOS) {
            const uint4 v = *reinterpret_cast<const uint4*>(&OutS[c*72 + sg*8]);
            *reinterpret_cast<uint4*>(dvattP + vRow0 + (size_t)c*DPOS + col) = v;
        }
    }
}

// ---------------------------------------------------------------------------
// Obs attention per (b, t, n) — bf16 MFMA, 512 threads, BARRIER-FREE main
// loop. Q staged in LDS once (read-only); K/V fragments read directly from
// global per wave (aK: contiguous 1KB/wave; aV: 8B/lane, L1-cached). Wave
// (g*4+w) owns p in [(g*4+w)*128, +128). Pad rows: aK=0 / aV=0 (V=0 kills
// pad contributions). Epilogue: 2-group LDS reduce (unchanged), output
// written as packed-T bf16 mergedP [b][8][OPOS][32]. Q pre-scaled by 1/16.
// ---------------------------------------------------------------------------
__global__ __launch_bounds__(512) void obs_attn_mfma(
    const ushort* __restrict__ KdP, const ushort* __restrict__ KoP,
    const ushort* __restrict__ QP,  const ushort* __restrict__ VdP,
    const ushort* __restrict__ VoP, ushort* __restrict__ mergedP)
{
    const int tt = blockIdx.x, hn = blockIdx.y, bb = blockIdx.z;
    __shared__ __align__(16) ushort smem_u[27136];   // QT[208][40] ∪ Ored[2][32][212]f32
    ushort* QT = smem_u;

    const int tid  = threadIdx.x;
    const int g    = tid >> 8;
    const int lane = tid & 63;
    const int w    = (tid >> 6) & 3;
    const int l15  = lane & 15, grp = lane >> 4;

    const size_t kdBase = ((size_t)bb*NHEADS + hn) * DPOS * 32;
    const size_t koBase = ((size_t)bb*NHEADS + hn) * OPOS * 32 + (size_t)tt*HW*32;
    const size_t vdRow0 = ((size_t)bb*CC + hn*CH) * DPOS;
    const size_t voRow0 = ((size_t)bb*CC + hn*CH) * OPOS + (size_t)tt*HW;

    // stage Q once (rows >= 196 zero)
    for (int idx = tid; idx < 832; idx += 512) {
        const int r = idx >> 2, sg = idx & 3;
        uint4 v = {0,0,0,0};
        if (r < HW) v = *reinterpret_cast<const uint4*>(QP + koBase + (size_t)r*32 + sg*8);
        *reinterpret_cast<uint4*>(&QT[r*40 + sg*8]) = v;
    }

    f32x4 accO[2][13];
    #pragma unroll
    for (int ct = 0; ct < 2; ++ct)
        #pragma unroll
        for (int qt = 0; qt < 13; ++qt)
            accO[ct][qt] = (f32x4){0.f, 0.f, 0.f, 0.f};
    __syncthreads();

    const int pw = (g*4 + w) * 128;
    for (int s = 0; s < 8; ++s) {
        const int p0 = pw + s*16;
        // ---- K fragment: direct global ----
        const int pk = p0 + l15;
        s8v aK = {0,0,0,0,0,0,0,0};
        if (pk < NPOS) {
            const ushort* kp = (pk < DPOS)
                ? KdP + kdBase + (size_t)pk*32
                : KoP + koBase + (size_t)(pk - DPOS)*32;
            aK = *reinterpret_cast<const s8v*>(kp + grp*8);
        }
        // ---- S: 13 q-tiles ----
        f32x4 ss[13];
        #pragma unroll
        for (int qt = 0; qt < 13; ++qt) {
            const s8v bQ = *reinterpret_cast<const s8v*>(&QT[(qt*16 + l15)*40 + grp*8]);
            const f32x4 z = {0.f, 0.f, 0.f, 0.f};
            ss[qt] = __builtin_amdgcn_mfma_f32_16x16x32_bf16(aK, bQ, z, 0, 0, 0);
        }
        // ---- softmax over q per p-row ----
        #pragma unroll
        for (int r = 0; r < 4; ++r) {
            float m = -1e30f;
            #pragma unroll
            for (int qt = 0; qt < 13; ++qt) {
                float v = ss[qt][r];
                if (qt == 12 && l15 >= 4) v = -1e30f;   // q >= 196 pad
                ss[qt][r] = v;
                m = fmaxf(m, v);
            }
            m = fmaxf(m, __shfl_xor(m, 1));
            m = fmaxf(m, __shfl_xor(m, 2));
            m = fmaxf(m, __shfl_xor(m, 4));
            m = fmaxf(m, __shfl_xor(m, 8));
            float sum = 0.f;
            #pragma unroll
            for (int qt = 0; qt < 13; ++qt) {
                const float e = __expf(ss[qt][r] - m);
                ss[qt][r] = e;
                sum += e;
            }
            sum += __shfl_xor(sum, 1);
            sum += __shfl_xor(sum, 2);
            sum += __shfl_xor(sum, 4);
            sum += __shfl_xor(sum, 8);
            const float is = 1.f / sum;
            #pragma unroll
            for (int qt = 0; qt < 13; ++qt) ss[qt][r] *= is;
        }
        s4v pf[13];
        #pragma unroll
        for (int qt = 0; qt < 13; ++qt) {
            s4v p4;
            #pragma unroll
            for (int r = 0; r < 4; ++r) p4[r] = (short)f2bf(ss[qt][r]);
            pf[qt] = p4;
        }
        // ---- PV: V fragments direct global ----
        #pragma unroll
        for (int ct = 0; ct < 2; ++ct) {
            const int c  = ct*16 + l15;
            const int pv = p0 + grp*4;
            s4v aV = {0,0,0,0};
            if (pv < NPOS) {
                const ushort* vp = (pv < DPOS)
                    ? VdP + vdRow0 + (size_t)c*DPOS + pv
                    : VoP + voRow0 + (size_t)c*OPOS + (pv - DPOS);
                aV = *reinterpret_cast<const s4v*>(vp);
            }
            #pragma unroll
            for (int qt = 0; qt < 13; ++qt)
                accO[ct][qt] = mfma_pv(aV, pf[qt], accO[ct][qt]);
        }
    }
    __syncthreads();

    // ---- per-group 4-wave reduction into Ored[g] ----
    float* OredF = reinterpret_cast<float*>(smem_u);   // [2][32][212]
    float* Og = OredF + g * 6784;
    for (int wv = 0; wv < 4; ++wv) {
        if (w == wv) {
            #pragma unroll
            for (int ct = 0; ct < 2; ++ct)
                #pragma unroll
                for (int qt = 0; qt < 13; ++qt)
                    #pragma unroll
                    for (int r = 0; r < 4; ++r) {
                        const int c = ct*16 + grp*4 + r;
                        const int q = qt*16 + l15;
                        if (wv == 0) Og[c*212 + q]  = accO[ct][qt][r];
                        else         Og[c*212 + q] += accO[ct][qt][r];
                    }
        }
        __syncthreads();
    }
    // add group partials, convert, store packed-T bf16 [q][32c]
    for (int idx = tid; idx < HW*4; idx += 512) {
        const int q = idx >> 2, c8 = (idx & 3) * 8;
        ushort e[8];
        #pragma unroll
        for (int j = 0; j < 8; ++j) {
            const int c = c8 + j;
            e[j] = f2bf(OredF[c*212 + q] + OredF[6784 + c*212 + q]);
        }
        uint4 v;
        v.x = e[0] | ((uint)e[1]<<16); v.y = e[2] | ((uint)e[3]<<16);
        v.z = e[4] | ((uint)e[5]<<16); v.w = e[6] | ((uint)e[7]<<16);
        *reinterpret_cast<uint4*>(
            mergedP + (((size_t)bb*NHEADS + hn)*OPOS + (size_t)tt*HW + q)*32 + c8) = v;
    }
}

// ---------------------------------------------------------------------------
// Fused residual-ReLU + concat + BatchNorm. One block per channel. float4.
// ---------------------------------------------------------------------------
__global__ __launch_bounds__(256) void bn_fuse(
    const float* __restrict__ xin, const float* __restrict__ obsout,
    const float* __restrict__ gamma, const float* __restrict__ beta,
    float* __restrict__ xout)
{
    const int c = blockIdx.x;
    const int tid = threadIdx.x;
    float sum = 0.f, sumsq = 0.f;
    for (int idx = tid; idx < BB*(DPOS/4); idx += 256) {
        const int b = idx / (DPOS/4), pos = idx % (DPOS/4);
        const float4 v = *reinterpret_cast<const float4*>(
            &xin[((size_t)b*CC + c) * XROW + pos*4]);
        sum   += v.x + v.y + v.z + v.w;
        sumsq += v.x*v.x + v.y*v.y + v.z*v.z + v.w*v.w;
    }
    for (int idx = tid; idx < BB*(OPOS/4); idx += 256) {
        const int b = idx / (OPOS/4), pos = idx % (OPOS/4);
        const float4 xv = *reinterpret_cast<const float4*>(
            &xin[((size_t)b*CC + c) * XROW + DPOS + pos*4]);
        const float4 ov = *reinterpret_cast<const float4*>(
            &obsout[((size_t)b*CC + c) * OPOS + pos*4]);
        const float4 v = make_float4(xv.x + fmaxf(ov.x, 0.f), xv.y + fmaxf(ov.y, 0.f),
                                     xv.z + fmaxf(ov.z, 0.f), xv.w + fmaxf(ov.w, 0.f));
        sum   += v.x + v.y + v.z + v.w;
        sumsq += v.x*v.x + v.y*v.y + v.z*v.z + v.w*v.w;
    }
    #pragma unroll
    for (int off = 32; off > 0; off >>= 1) {
        sum   += __shfl_xor(sum, off);
        sumsq += __shfl_xor(sumsq, off);
    }
    __shared__ float ssum[4], ssq[4];
    __shared__ float s_mean, s_inv;
    const int lane = tid & 63, w = tid >> 6;
    if (lane == 0) { ssum[w] = sum; ssq[w] = sumsq; }
    __syncthreads();
    if (tid == 0) {
        float s  = ssum[0] + ssum[1] + ssum[2] + ssum[3];
        float sq = ssq[0] + ssq[1] + ssq[2] + ssq[3];
        const float mean = s / 12544.f;
        const float var  = sq / 12544.f - mean * mean;
        s_mean = mean;
        s_inv  = rsqrtf(var + 1e-5f);
    }
    __syncthreads();
    const float mean = s_mean;
    const float gi = gamma[c] * s_inv;
    const float bt = beta[c];
    for (int idx = tid; idx < BB*(DPOS/4); idx += 256) {
        const int b = idx / (DPOS/4), pos = idx % (DPOS/4);
        const size_t o = ((size_t)b*CC + c) * XROW + pos*4;
        const float4 v = *reinterpret_cast<const float4*>(&xin[o]);
        const float4 r = make_float4((v.x-mean)*gi+bt, (v.y-mean)*gi+bt,
                                     (v.z-mean)*gi+bt, (v.w-mean)*gi+bt);
        *reinterpret_cast<float4*>(&xout[o]) = r;
    }
    for (int idx = tid; idx < BB*(OPOS/4); idx += 256) {
        const int b = idx / (OPOS/4), pos = idx % (OPOS/4);
        const float4 xv = *reinterpret_cast<const float4*>(
            &xin[((size_t)b*CC + c) * XROW + DPOS + pos*4]);
        const float4 ov = *reinterpret_cast<const float4*>(
            &obsout[((size_t)b*CC + c) * OPOS + pos*4]);
        const float4 v = make_float4(xv.x + fmaxf(ov.x, 0.f), xv.y + fmaxf(ov.y, 0.f),
                                     xv.z + fmaxf(ov.z, 0.f), xv.w + fmaxf(ov.w, 0.f));
        const float4 r = make_float4((v.x-mean)*gi+bt, (v.y-mean)*gi+bt,
                                     (v.z-mean)*gi+bt, (v.w-mean)*gi+bt);
        *reinterpret_cast<float4*>(&xout[((size_t)b*CC + c) * XROW + DPOS + pos*4]) = r;
    }
}

// ---------------------------------------------------------------------------
extern "C" void kernel_launch(void* const* d_in, const int* in_sizes, int n_in,
                              void* d_out, int out_size, void* d_ws, size_t ws_size,
                              hipStream_t stream)
{
    const float* x   = (const float*)d_in[0];
    const float* dqw = (const float*)d_in[1];
    const float* dkw = (const float*)d_in[2];
    const float* dvw = (const float*)d_in[3];
    const float* oqw = (const float*)d_in[4];
    const float* okw = (const float*)d_in[5];
    const float* ovw = (const float*)d_in[6];
    const float* oow = (const float*)d_in[7];
    const float* gam = (const float*)d_in[8];
    const float* bet = (const float*)d_in[9];

    const size_t XN = (size_t)BB * CC * TT * HW;   // 3,211,264
    const size_t DN = (size_t)BB * CC * DPOS;      //   802,816
    const size_t ON = (size_t)BB * CC * OPOS;      // 2,408,448
    const size_t WN = (size_t)3 * CC * CC;         //   196,608

    float*  xb0     = (float*)d_ws;
    float*  xb1     = xb0 + XN;
    float*  obsout  = xb1 + XN;
    ushort* XP      = (ushort*)(obsout + ON);     // [b][8][3136][32]
    ushort* QdP     = XP + XN;
    ushort* KdP     = QdP + DN;
    ushort* VdemoP  = KdP + DN;
    ushort* dvattP  = VdemoP + DN;
    ushort* QP      = dvattP + DN;
    ushort* KoP     = QP + ON;
    ushort* VoP     = KoP + ON;
    ushort* mergedP = VoP + ON;
    ushort* wpk     = mergedP + ON;
    ushort* dqwb = wpk;          ushort* dkwb = wpk + WN;   ushort* dvwb = wpk + 2*WN;
    ushort* oqwb = wpk + 3*WN;   ushort* okwb = wpk + 4*WN; ushort* ovwb = wpk + 5*WN;
    ushort* oowb = wpk + 6*WN;

    const dim3 blk(256);
    const dim3 blk2(512);
    const float QS = 0.0625f;   // 1/sqrt(C), exact power of two

    pack_cvt<<<dim3(192), blk, 0, stream>>>(dqw, dqwb, (int)(WN/4));
    pack_cvt<<<dim3(192), blk, 0, stream>>>(dkw, dkwb, (int)(WN/4));
    pack_cvt<<<dim3(192), blk, 0, stream>>>(dvw, dvwb, (int)(WN/4));
    pack_cvt<<<dim3(192), blk, 0, stream>>>(oqw, oqwb, (int)(WN/4));
    pack_cvt<<<dim3(192), blk, 0, stream>>>(okw, okwb, (int)(WN/4));
    pack_cvt<<<dim3(192), blk, 0, stream>>>(ovw, ovwb, (int)(WN/4));
    pack_cvt<<<dim3(192), blk, 0, stream>>>(oow, oowb, (int)(WN/4));

    for (int i = 0; i < 3; i++) {
        const float* xin  = (i == 0) ? x : (i == 1 ? xb0 : xb1);
        float*       xout = (i == 2) ? (float*)d_out : (i == 0 ? xb0 : xb1);
        const size_t wB = (size_t)i * CC * CC;

        // 1: pack x -> XP
        pack_T<<<dim3(49, 8, BB), blk, 0, stream>>>(xin, XP, XROW);

        // 2: demo projections (Q scaled by 1/16 at pack)
        proj_mfma<<<dim3(BB*13, 4, 3), blk, 0, stream>>>(
            XP, XROW, 0, DPOS, DPOS,
            dqwb + wB, dkwb + wB, dvwb + wB,
            QdP, KdP, VdemoP, 0, 0, 1, QS, 1.f, 1.f);

        // 3: demo attention
        demo_attn_mfma<<<dim3(13, NHEADS, BB), blk2, 0, stream>>>(
            QdP, KdP, VdemoP, dvattP);

        // 4: obs projections (Q scaled by 1/16 at pack)
        proj_mfma<<<dim3(BB*37, 4, 3), blk, 0, stream>>>(
            XP, XROW, DPOS, OPOS, OPOS,
            oqwb + wB, okwb + wB, ovwb + wB,
            QP, KoP, VoP, 0, 0, 1, QS, 1.f, 1.f);

        // 5: obs attention -> mergedP
        obs_attn_mfma<<<dim3(OBS_T, NHEADS, BB), blk2, 0, stream>>>(
            KdP, KoP, QP, dvattP, VoP, mergedP);

        // 6: output projection (fp32 out)
        proj_mfma<<<dim3(BB*37, 4, 1), blk, 0, stream>>>(
            mergedP, OPOS, 0, OPOS, OPOS,
            oowb + wB, oowb + wB, oowb + wB,
            obsout, obsout, obsout, 2, 2, 2, 1.f, 1.f, 1.f);

        // 7: residual + BN
        bn_fuse<<<dim3(CC), blk, 0, stream>>>(xin, obsout, gam + i*CC, bet + i*CC, xout);
    }
}

// Round 8
// 445.186 us; speedup vs baseline: 8.5730x; 1.1165x over previous
//
#include <hip/hip_runtime.h>
#include <hip/hip_bf16.h>

// Problem constants
#define BB 4
#define CC 256
#define TT 16
#define HW 196
#define DEMO_T 4
#define OBS_T 12
#define DPOS 784      // DEMO_T*HW
#define OPOS 2352     // OBS_T*HW
#define XROW 3136     // TT*HW
#define NHEADS 8
#define CH 32
#define NPOS 980      // DPOS + HW (cat keys per (b,t,n))

typedef float  f32x4 __attribute__((ext_vector_type(4)));
typedef short  s8v   __attribute__((ext_vector_type(8)));
typedef short  s4v   __attribute__((ext_vector_type(4)));

// bf16 convert via official cast — compiler fuses pairs into v_cvt_pk_bf16_f32
static __device__ __forceinline__ ushort f2bf(float f) {
    union { __hip_bfloat16 h; ushort u; } cv;
    cv.h = __float2bfloat16(f);
    return cv.u;
}
static __device__ __forceinline__ short bfr(float f) { return (short)f2bf(f); }

static __device__ __forceinline__ float fast_rcp(float x) {
#if __has_builtin(__builtin_amdgcn_rcpf)
    return __builtin_amdgcn_rcpf(x);
#else
    return 1.f / x;
#endif
}

static __device__ __forceinline__ f32x4 mfma_pv(s4v a, s4v b, f32x4 c) {
#if __has_builtin(__builtin_amdgcn_mfma_f32_16x16x16bf16_1k)
    return __builtin_amdgcn_mfma_f32_16x16x16bf16_1k(a, b, c, 0, 0, 0);
#else
    s8v a8 = {a[0], a[1], a[2], a[3], 0, 0, 0, 0};
    s8v b8 = {b[0], b[1], b[2], b[3], 0, 0, 0, 0};
    return __builtin_amdgcn_mfma_f32_16x16x32_bf16(a8, b8, c, 0, 0, 0);
#endif
}

// ---------------------------------------------------------------------------
// pack_T: fp32 [b][256][P] -> bf16 [b][8][P][32]  (per-c-chunk transpose)
// ---------------------------------------------------------------------------
__global__ __launch_bounds__(256) void pack_T(
    const float* __restrict__ src, ushort* __restrict__ dst, int P)
{
    const int hn = blockIdx.y, bb = blockIdx.z;
    const int p0 = blockIdx.x * 64;
    __shared__ float L[32][73];
    const int tid = threadIdx.x;
    {
        const int c = tid >> 3, sg = tid & 7;
        const int p = p0 + sg*8;
        const float* s = src + ((size_t)bb*CC + hn*CH + c) * P + p;
        float4 a = {0,0,0,0}, b2 = {0,0,0,0};
        if (p < P) { a = *reinterpret_cast<const float4*>(s);
                     b2 = *reinterpret_cast<const float4*>(s + 4); }
        L[c][sg*8+0]=a.x;  L[c][sg*8+1]=a.y;  L[c][sg*8+2]=a.z;  L[c][sg*8+3]=a.w;
        L[c][sg*8+4]=b2.x; L[c][sg*8+5]=b2.y; L[c][sg*8+6]=b2.z; L[c][sg*8+7]=b2.w;
    }
    __syncthreads();
    {
        const int pl = tid >> 2, cs = (tid & 3) * 8;
        if (p0 + pl < P) {
            ushort o[8];
            #pragma unroll
            for (int j = 0; j < 8; j++) o[j] = f2bf(L[cs+j][pl]);
            uint4 v;
            v.x = o[0] | ((uint)o[1]<<16); v.y = o[2] | ((uint)o[3]<<16);
            v.z = o[4] | ((uint)o[5]<<16); v.w = o[6] | ((uint)o[7]<<16);
            *reinterpret_cast<uint4*>(dst + (((size_t)bb*NHEADS + hn)*P + p0 + pl)*32 + cs) = v;
        }
    }
}

// ---------------------------------------------------------------------------
// pack_cvt: flat fp32 -> bf16 (n4 = count/4)
// ---------------------------------------------------------------------------
__global__ __launch_bounds__(256) void pack_cvt(
    const float* __restrict__ src, ushort* __restrict__ dst, int n4)
{
    for (size_t i = (size_t)blockIdx.x * 256 + threadIdx.x; i < (size_t)n4;
         i += (size_t)gridDim.x * 256) {
        const float4 v = *reinterpret_cast<const float4*>(src + i*4);
        uint2 o;
        o.x = f2bf(v.x) | ((uint)f2bf(v.y) << 16);
        o.y = f2bf(v.z) | ((uint)f2bf(v.w) << 16);
        *reinterpret_cast<uint2*>(dst + i*4) = o;
    }
}

// ---------------------------------------------------------------------------
// bf16 MFMA projection GEMM with fused pack epilogues (+ per-z output scale).
//   variant 0 = packed-T bf16 [b][8][OP][32]; 1 = natural bf16 [b][256][OP];
//   2 = natural fp32 [b][256][OP]
// ---------------------------------------------------------------------------
__global__ __launch_bounds__(256) void proj_mfma(
    const ushort* __restrict__ XPK, int P, int pOff, int ncols, int OP,
    const ushort* __restrict__ W0, const ushort* __restrict__ W1, const ushort* __restrict__ W2,
    void* __restrict__ O0, void* __restrict__ O1, void* __restrict__ O2,
    int v0, int v1, int v2, float sc0, float sc1, float sc2)
{
    const int ptiles = (ncols + 63) >> 6;
    const int b  = blockIdx.x / ptiles;
    const int pt = blockIdx.x % ptiles;
    const int fbase = blockIdx.y * 64;
    const int z = blockIdx.z;
    const ushort* W = (z == 0) ? W0 : (z == 1) ? W1 : W2;
    void*        O = (z == 0) ? O0 : (z == 1) ? O1 : O2;
    const int variant = (z == 0) ? v0 : (z == 1) ? v1 : v2;
    const float sc    = (z == 0) ? sc0 : (z == 1) ? sc1 : sc2;

    const int tid = threadIdx.x, lane = tid & 63, w = tid >> 6;
    const int l15 = lane & 15, grp = lane >> 4;

    __shared__ float Cf[64][68];

    f32x4 acc[4];
    #pragma unroll
    for (int nt = 0; nt < 4; ++nt) acc[nt] = (f32x4){0.f, 0.f, 0.f, 0.f};

    const ushort* Wrow = W + (size_t)(fbase + w*16 + l15) * CC;
    int prow[4];
    #pragma unroll
    for (int nt = 0; nt < 4; ++nt) {
        const int p = pt*64 + nt*16 + l15;
        prow[nt] = (p < ncols) ? p : (ncols - 1);   // clamp: dup rows discarded
    }
    const size_t xb = (size_t)b * 8;

    #pragma unroll
    for (int kc = 0; kc < 8; ++kc) {
        const s8v aW = *reinterpret_cast<const s8v*>(Wrow + kc*32 + grp*8);
        #pragma unroll
        for (int nt = 0; nt < 4; ++nt) {
            const s8v bX = *reinterpret_cast<const s8v*>(
                XPK + ((xb + kc)*P + pOff + prow[nt])*32 + grp*8);
            acc[nt] = __builtin_amdgcn_mfma_f32_16x16x32_bf16(aW, bX, acc[nt], 0, 0, 0);
        }
    }
    #pragma unroll
    for (int nt = 0; nt < 4; ++nt)
        #pragma unroll
        for (int r = 0; r < 4; ++r)
            Cf[w*16 + grp*4 + r][nt*16 + l15] = acc[nt][r] * sc;
    __syncthreads();

    if (variant == 0) {
        ushort* dst = (ushort*)O;
        const int p_l = tid >> 2, c8 = (tid & 3) * 8;
        const int opos = pt*64 + p_l;
        if (opos < ncols) {
            #pragma unroll
            for (int hq = 0; hq < 2; ++hq) {
                ushort e[8];
                #pragma unroll
                for (int j = 0; j < 8; ++j) e[j] = f2bf(Cf[hq*32 + c8 + j][p_l]);
                uint4 v;
                v.x = e[0] | ((uint)e[1]<<16); v.y = e[2] | ((uint)e[3]<<16);
                v.z = e[4] | ((uint)e[5]<<16); v.w = e[6] | ((uint)e[7]<<16);
                *reinterpret_cast<uint4*>(
                    dst + (((size_t)b*NHEADS + (fbase >> 5) + hq)*OP + opos)*32 + c8) = v;
            }
        }
    } else if (variant == 1) {
        ushort* dst = (ushort*)O;
        #pragma unroll
        for (int pass = 0; pass < 2; ++pass) {
            const int idx = pass*256 + tid;
            const int f_l = idx >> 3, u = idx & 7;
            const int p0 = pt*64 + u*8;
            if (p0 < ncols) {
                ushort e[8];
                #pragma unroll
                for (int j = 0; j < 8; ++j) e[j] = f2bf(Cf[f_l][u*8 + j]);
                uint4 v;
                v.x = e[0] | ((uint)e[1]<<16); v.y = e[2] | ((uint)e[3]<<16);
                v.z = e[4] | ((uint)e[5]<<16); v.w = e[6] | ((uint)e[7]<<16);
                *reinterpret_cast<uint4*>(
                    dst + ((size_t)b*CC + fbase + f_l)*OP + p0) = v;
            }
        }
    } else {
        float* dst = (float*)O;
        #pragma unroll
        for (int pass = 0; pass < 2; ++pass) {
            const int idx = pass*256 + tid;
            const int f_l = idx >> 3, u = idx & 7;
            const int p0 = pt*64 + u*8;
            if (p0 < ncols) {
                float* dp = dst + ((size_t)b*CC + fbase + f_l)*OP + p0;
                *reinterpret_cast<float4*>(dp)     = *reinterpret_cast<const float4*>(&Cf[f_l][u*8]);
                *reinterpret_cast<float4*>(dp + 4) = *reinterpret_cast<const float4*>(&Cf[f_l][u*8 + 4]);
            }
        }
    }
}

// ---------------------------------------------------------------------------
// Demo attention — bf16 MFMA, 512 threads, NO-MAX softmax (scores bounded),
// barrier-free main loop with ZERO in-loop cross-lane ops: accumulate
// unnormalized O and per-lane partial l; single reduce + merge at the end.
// Group g takes j-chunks 0..6 / 7..12. Q pre-scaled by 1/16 at pack time.
// ---------------------------------------------------------------------------
__global__ __launch_bounds__(512) void demo_attn_mfma(
    const ushort* __restrict__ QdP, const ushort* __restrict__ KdP,
    const ushort* __restrict__ VdP, ushort* __restrict__ dvattP)
{
    const int ib = blockIdx.x, hn = blockIdx.y, bb = blockIdx.z;
    const int tid = threadIdx.x;
    const int g   = tid >> 8;          // j-half
    const int gt  = tid & 255;
    const int lane = tid & 63;
    const int w    = (tid >> 6) & 3;   // i-quarter
    const int l15 = lane & 15, grp = lane >> 4;

    __shared__ float mrg[2304];                       // Lb[256] Ob[2048]
    __shared__ __align__(16) ushort OutS[32*72];

    const size_t hBase = ((size_t)bb*NHEADS + hn) * DPOS;
    const size_t vRow0 = ((size_t)bb*CC + hn*CH) * DPOS;

    const int i_glob = ib*64 + w*16 + l15;
    const s8v bK = *reinterpret_cast<const s8v*>(KdP + (hBase + i_glob)*32 + grp*8);

    f32x4 accO[2] = {{0.f,0.f,0.f,0.f}, {0.f,0.f,0.f,0.f}};
    float l_run = 0.f;

    const int chFirst = g ? 7 : 0;
    const int chEnd   = g ? 13 : 7;
    for (int ch = chFirst; ch < chEnd; ++ch) {
        const int nt = (ch == 12) ? 1 : 4;
        for (int jt = 0; jt < nt; ++jt) {
            const s8v aQ = *reinterpret_cast<const s8v*>(
                QdP + (hBase + ch*64 + jt*16 + l15)*32 + grp*8);
            const f32x4 z = {0.f,0.f,0.f,0.f};
            const f32x4 st = __builtin_amdgcn_mfma_f32_16x16x32_bf16(aQ, bK, z, 0, 0, 0);
            const float e0 = __expf(st[0]), e1 = __expf(st[1]);
            const float e2 = __expf(st[2]), e3 = __expf(st[3]);
            l_run += (e0 + e1) + (e2 + e3);
            s4v pf4;
            pf4[0] = bfr(e0); pf4[1] = bfr(e1); pf4[2] = bfr(e2); pf4[3] = bfr(e3);
            #pragma unroll
            for (int ct = 0; ct < 2; ++ct) {
                const s4v aV = *reinterpret_cast<const s4v*>(
                    VdP + vRow0 + (size_t)(ct*16 + l15)*DPOS + ch*64 + jt*16 + grp*4);
                accO[ct] = mfma_pv(aV, pf4, accO[ct]);
            }
        }
    }
    // cross-grp partial-l reduce (j spans grp via the C-row mapping)
    l_run += __shfl_xor(l_run, 16);
    l_run += __shfl_xor(l_run, 32);

    // ---- merge: simple (l, O) add across groups, then normalize ----
    float* Lb = mrg;          // [256]
    float* Ob = mrg + 256;    // [256][8]
    if (g == 1) {
        Lb[w*64 + lane] = l_run;
        #pragma unroll
        for (int ct = 0; ct < 2; ++ct)
            #pragma unroll
            for (int r = 0; r < 4; ++r)
                Ob[(w*64 + lane)*8 + ct*4 + r] = accO[ct][r];
    }
    __syncthreads();
    if (g == 0) {
        const float linv = 1.f / (l_run + Lb[w*64 + lane]);
        #pragma unroll
        for (int ct = 0; ct < 2; ++ct)
            #pragma unroll
            for (int r = 0; r < 4; ++r) {
                const float o = (accO[ct][r] + Ob[(w*64 + lane)*8 + ct*4 + r]) * linv;
                OutS[(ct*16 + grp*4 + r)*72 + w*16 + l15] = f2bf(o);
            }
    }
    __syncthreads();
    if (g == 0) {
        const int c = gt >> 3, sg = gt & 7;
        const int col = ib*64 + sg*8;
        if (col < DPOS) {
            const uint4 v = *reinterpret_cast<const uint4*>(&OutS[c*72 + sg*8]);
            *reinterpret_cast<uint4*>(dvattP + vRow0 + (size_t)c*DPOS + col) = v;
        }
    }
}

// ---------------------------------------------------------------------------
// Obs attention per (b, t, n) — bf16 MFMA, 512 threads, barrier-free main
// loop, NO-MAX softmax (scores bounded: sigma~0.35). Q staged in LDS once;
// K/V fragments direct from global. Wave (g*4+w) owns p in [wave*128, +128).
// Pad q-cols zeroed post-exp; pad p-rows harmless (V=0). Q pre-scaled 1/16.
// ---------------------------------------------------------------------------
__global__ __launch_bounds__(512) void obs_attn_mfma(
    const ushort* __restrict__ KdP, const ushort* __restrict__ KoP,
    const ushort* __restrict__ QP,  const ushort* __restrict__ VdP,
    const ushort* __restrict__ VoP, ushort* __restrict__ mergedP)
{
    const int tt = blockIdx.x, hn = blockIdx.y, bb = blockIdx.z;
    __shared__ __align__(16) ushort smem_u[27136];   // QT[208][40] ∪ Ored[2][32][212]f32
    ushort* QT = smem_u;

    const int tid  = threadIdx.x;
    const int g    = tid >> 8;
    const int lane = tid & 63;
    const int w    = (tid >> 6) & 3;
    const int l15  = lane & 15, grp = lane >> 4;

    const size_t kdBase = ((size_t)bb*NHEADS + hn) * DPOS * 32;
    const size_t koBase = ((size_t)bb*NHEADS + hn) * OPOS * 32 + (size_t)tt*HW*32;
    const size_t vdRow0 = ((size_t)bb*CC + hn*CH) * DPOS;
    const size_t voRow0 = ((size_t)bb*CC + hn*CH) * OPOS + (size_t)tt*HW;

    // stage Q once (rows >= 196 zero)
    for (int idx = tid; idx < 832; idx += 512) {
        const int r = idx >> 2, sg = idx & 3;
        uint4 v = {0,0,0,0};
        if (r < HW) v = *reinterpret_cast<const uint4*>(QP + koBase + (size_t)r*32 + sg*8);
        *reinterpret_cast<uint4*>(&QT[r*40 + sg*8]) = v;
    }

    f32x4 accO[2][13];
    #pragma unroll
    for (int ct = 0; ct < 2; ++ct)
        #pragma unroll
        for (int qt = 0; qt < 13; ++qt)
            accO[ct][qt] = (f32x4){0.f, 0.f, 0.f, 0.f};
    __syncthreads();

    const int pw = (g*4 + w) * 128;
    for (int s = 0; s < 8; ++s) {
        const int p0 = pw + s*16;
        // ---- K fragment: direct global ----
        const int pk = p0 + l15;
        s8v aK = {0,0,0,0,0,0,0,0};
        if (pk < NPOS) {
            const ushort* kp = (pk < DPOS)
                ? KdP + kdBase + (size_t)pk*32
                : KoP + koBase + (size_t)(pk - DPOS)*32;
            aK = *reinterpret_cast<const s8v*>(kp + grp*8);
        }
        // ---- S: 13 q-tiles ----
        f32x4 ss[13];
        #pragma unroll
        for (int qt = 0; qt < 13; ++qt) {
            const s8v bQ = *reinterpret_cast<const s8v*>(&QT[(qt*16 + l15)*40 + grp*8]);
            const f32x4 z = {0.f, 0.f, 0.f, 0.f};
            ss[qt] = __builtin_amdgcn_mfma_f32_16x16x32_bf16(aK, bQ, z, 0, 0, 0);
        }
        // ---- no-max softmax over q per p-row ----
        #pragma unroll
        for (int r = 0; r < 4; ++r) {
            #pragma unroll
            for (int qt = 0; qt < 13; ++qt) ss[qt][r] = __expf(ss[qt][r]);
            if (l15 >= 4) ss[12][r] = 0.f;   // q >= 196 pad
            float sum = ((((ss[0][r]+ss[1][r]) + (ss[2][r]+ss[3][r]))
                        + ((ss[4][r]+ss[5][r]) + (ss[6][r]+ss[7][r])))
                        + (((ss[8][r]+ss[9][r]) + (ss[10][r]+ss[11][r])) + ss[12][r]));
            sum += __shfl_xor(sum, 1);
            sum += __shfl_xor(sum, 2);
            sum += __shfl_xor(sum, 4);
            sum += __shfl_xor(sum, 8);
            const float is = fast_rcp(sum);
            #pragma unroll
            for (int qt = 0; qt < 13; ++qt) ss[qt][r] *= is;
        }
        s4v pf[13];
        #pragma unroll
        for (int qt = 0; qt < 13; ++qt) {
            s4v p4;
            #pragma unroll
            for (int r = 0; r < 4; ++r) p4[r] = bfr(ss[qt][r]);
            pf[qt] = p4;
        }
        // ---- PV: V fragments direct global ----
        #pragma unroll
        for (int ct = 0; ct < 2; ++ct) {
            const int c  = ct*16 + l15;
            const int pv = p0 + grp*4;
            s4v aV = {0,0,0,0};
            if (pv < NPOS) {
                const ushort* vp = (pv < DPOS)
                    ? VdP + vdRow0 + (size_t)c*DPOS + pv
                    : VoP + voRow0 + (size_t)c*OPOS + (pv - DPOS);
                aV = *reinterpret_cast<const s4v*>(vp);
            }
            #pragma unroll
            for (int qt = 0; qt < 13; ++qt)
                accO[ct][qt] = mfma_pv(aV, pf[qt], accO[ct][qt]);
        }
    }
    __syncthreads();

    // ---- per-group 4-wave reduction into Ored[g] ----
    float* OredF = reinterpret_cast<float*>(smem_u);   // [2][32][212]
    float* Og = OredF + g * 6784;
    for (int wv = 0; wv < 4; ++wv) {
        if (w == wv) {
            #pragma unroll
            for (int ct = 0; ct < 2; ++ct)
                #pragma unroll
                for (int qt = 0; qt < 13; ++qt)
                    #pragma unroll
                    for (int r = 0; r < 4; ++r) {
                        const int c = ct*16 + grp*4 + r;
                        const int q = qt*16 + l15;
                        if (wv == 0) Og[c*212 + q]  = accO[ct][qt][r];
                        else         Og[c*212 + q] += accO[ct][qt][r];
                    }
        }
        __syncthreads();
    }
    // add group partials, convert, store packed-T bf16 [q][32c]
    for (int idx = tid; idx < HW*4; idx += 512) {
        const int q = idx >> 2, c8 = (idx & 3) * 8;
        ushort e[8];
        #pragma unroll
        for (int j = 0; j < 8; ++j) {
            const int c = c8 + j;
            e[j] = f2bf(OredF[c*212 + q] + OredF[6784 + c*212 + q]);
        }
        uint4 v;
        v.x = e[0] | ((uint)e[1]<<16); v.y = e[2] | ((uint)e[3]<<16);
        v.z = e[4] | ((uint)e[5]<<16); v.w = e[6] | ((uint)e[7]<<16);
        *reinterpret_cast<uint4*>(
            mergedP + (((size_t)bb*NHEADS + hn)*OPOS + (size_t)tt*HW + q)*32 + c8) = v;
    }
}

// ---------------------------------------------------------------------------
// Fused residual-ReLU + concat + BatchNorm. One block per channel. float4.
// ---------------------------------------------------------------------------
__global__ __launch_bounds__(256) void bn_fuse(
    const float* __restrict__ xin, const float* __restrict__ obsout,
    const float* __restrict__ gamma, const float* __restrict__ beta,
    float* __restrict__ xout)
{
    const int c = blockIdx.x;
    const int tid = threadIdx.x;
    float sum = 0.f, sumsq = 0.f;
    for (int idx = tid; idx < BB*(DPOS/4); idx += 256) {
        const int b = idx / (DPOS/4), pos = idx % (DPOS/4);
        const float4 v = *reinterpret_cast<const float4*>(
            &xin[((size_t)b*CC + c) * XROW + pos*4]);
        sum   += v.x + v.y + v.z + v.w;
        sumsq += v.x*v.x + v.y*v.y + v.z*v.z + v.w*v.w;
    }
    for (int idx = tid; idx < BB*(OPOS/4); idx += 256) {
        const int b = idx / (OPOS/4), pos = idx % (OPOS/4);
        const float4 xv = *reinterpret_cast<const float4*>(
            &xin[((size_t)b*CC + c) * XROW + DPOS + pos*4]);
        const float4 ov = *reinterpret_cast<const float4*>(
            &obsout[((size_t)b*CC + c) * OPOS + pos*4]);
        const float4 v = make_float4(xv.x + fmaxf(ov.x, 0.f), xv.y + fmaxf(ov.y, 0.f),
                                     xv.z + fmaxf(ov.z, 0.f), xv.w + fmaxf(ov.w, 0.f));
        sum   += v.x + v.y + v.z + v.w;
        sumsq += v.x*v.x + v.y*v.y + v.z*v.z + v.w*v.w;
    }
    #pragma unroll
    for (int off = 32; off > 0; off >>= 1) {
        sum   += __shfl_xor(sum, off);
        sumsq += __shfl_xor(sumsq, off);
    }
    __shared__ float ssum[4], ssq[4];
    __shared__ float s_mean, s_inv;
    const int lane = tid & 63, w = tid >> 6;
    if (lane == 0) { ssum[w] = sum; ssq[w] = sumsq; }
    __syncthreads();
    if (tid == 0) {
        float s  = ssum[0] + ssum[1] + ssum[2] + ssum[3];
        float sq = ssq[0] + ssq[1] + ssq[2] + ssq[3];
        const float mean = s / 12544.f;
        const float var  = sq / 12544.f - mean * mean;
        s_mean = mean;
        s_inv  = rsqrtf(var + 1e-5f);
    }
    __syncthreads();
    const float mean = s_mean;
    const float gi = gamma[c] * s_inv;
    const float bt = beta[c];
    for (int idx = tid; idx < BB*(DPOS/4); idx += 256) {
        const int b = idx / (DPOS/4), pos = idx % (DPOS/4);
        const size_t o = ((size_t)b*CC + c) * XROW + pos*4;
        const float4 v = *reinterpret_cast<const float4*>(&xin[o]);
        const float4 r = make_float4((v.x-mean)*gi+bt, (v.y-mean)*gi+bt,
                                     (v.z-mean)*gi+bt, (v.w-mean)*gi+bt);
        *reinterpret_cast<float4*>(&xout[o]) = r;
    }
    for (int idx = tid; idx < BB*(OPOS/4); idx += 256) {
        const int b = idx / (OPOS/4), pos = idx % (OPOS/4);
        const float4 xv = *reinterpret_cast<const float4*>(
            &xin[((size_t)b*CC + c) * XROW + DPOS + pos*4]);
        const float4 ov = *reinterpret_cast<const float4*>(
            &obsout[((size_t)b*CC + c) * OPOS + pos*4]);
        const float4 v = make_float4(xv.x + fmaxf(ov.x, 0.f), xv.y + fmaxf(ov.y, 0.f),
                                     xv.z + fmaxf(ov.z, 0.f), xv.w + fmaxf(ov.w, 0.f));
        const float4 r = make_float4((v.x-mean)*gi+bt, (v.y-mean)*gi+bt,
                                     (v.z-mean)*gi+bt, (v.w-mean)*gi+bt);
        *reinterpret_cast<float4*>(&xout[((size_t)b*CC + c) * XROW + DPOS + pos*4]) = r;
    }
}

// ---------------------------------------------------------------------------
extern "C" void kernel_launch(void* const* d_in, const int* in_sizes, int n_in,
                              void* d_out, int out_size, void* d_ws, size_t ws_size,
                              hipStream_t stream)
{
    const float* x   = (const float*)d_in[0];
    const float* dqw = (const float*)d_in[1];
    const float* dkw = (const float*)d_in[2];
    const float* dvw = (const float*)d_in[3];
    const float* oqw = (const float*)d_in[4];
    const float* okw = (const float*)d_in[5];
    const float* ovw = (const float*)d_in[6];
    const float* oow = (const float*)d_in[7];
    const float* gam = (const float*)d_in[8];
    const float* bet = (const float*)d_in[9];

    const size_t XN = (size_t)BB * CC * TT * HW;   // 3,211,264
    const size_t DN = (size_t)BB * CC * DPOS;      //   802,816
    const size_t ON = (size_t)BB * CC * OPOS;      // 2,408,448
    const size_t WN = (size_t)3 * CC * CC;         //   196,608

    float*  xb0     = (float*)d_ws;
    float*  xb1     = xb0 + XN;
    float*  obsout  = xb1 + XN;
    ushort* XP      = (ushort*)(obsout + ON);     // [b][8][3136][32]
    ushort* QdP     = XP + XN;
    ushort* KdP     = QdP + DN;
    ushort* VdemoP  = KdP + DN;
    ushort* dvattP  = VdemoP + DN;
    ushort* QP      = dvattP + DN;
    ushort* KoP     = QP + ON;
    ushort* VoP     = KoP + ON;
    ushort* mergedP = VoP + ON;
    ushort* wpk     = mergedP + ON;
    ushort* dqwb = wpk;          ushort* dkwb = wpk + WN;   ushort* dvwb = wpk + 2*WN;
    ushort* oqwb = wpk + 3*WN;   ushort* okwb = wpk + 4*WN; ushort* ovwb = wpk + 5*WN;
    ushort* oowb = wpk + 6*WN;

    const dim3 blk(256);
    const dim3 blk2(512);
    const float QS = 0.0625f;   // 1/sqrt(C), exact power of two

    pack_cvt<<<dim3(192), blk, 0, stream>>>(dqw, dqwb, (int)(WN/4));
    pack_cvt<<<dim3(192), blk, 0, stream>>>(dkw, dkwb, (int)(WN/4));
    pack_cvt<<<dim3(192), blk, 0, stream>>>(dvw, dvwb, (int)(WN/4));
    pack_cvt<<<dim3(192), blk, 0, stream>>>(oqw, oqwb, (int)(WN/4));
    pack_cvt<<<dim3(192), blk, 0, stream>>>(okw, okwb, (int)(WN/4));
    pack_cvt<<<dim3(192), blk, 0, stream>>>(ovw, ovwb, (int)(WN/4));
    pack_cvt<<<dim3(192), blk, 0, stream>>>(oow, oowb, (int)(WN/4));

    for (int i = 0; i < 3; i++) {
        const float* xin  = (i == 0) ? x : (i == 1 ? xb0 : xb1);
        float*       xout = (i == 2) ? (float*)d_out : (i == 0 ? xb0 : xb1);
        const size_t wB = (size_t)i * CC * CC;

        // 1: pack x -> XP
        pack_T<<<dim3(49, 8, BB), blk, 0, stream>>>(xin, XP, XROW);

        // 2: demo projections (Q scaled by 1/16 at pack)
        proj_mfma<<<dim3(BB*13, 4, 3), blk, 0, stream>>>(
            XP, XROW, 0, DPOS, DPOS,
            dqwb + wB, dkwb + wB, dvwb + wB,
            QdP, KdP, VdemoP, 0, 0, 1, QS, 1.f, 1.f);

        // 3: demo attention
        demo_attn_mfma<<<dim3(13, NHEADS, BB), blk2, 0, stream>>>(
            QdP, KdP, VdemoP, dvattP);

        // 4: obs projections (Q scaled by 1/16 at pack)
        proj_mfma<<<dim3(BB*37, 4, 3), blk, 0, stream>>>(
            XP, XROW, DPOS, OPOS, OPOS,
            oqwb + wB, okwb + wB, ovwb + wB,
            QP, KoP, VoP, 0, 0, 1, QS, 1.f, 1.f);

        // 5: obs attention -> mergedP
        obs_attn_mfma<<<dim3(OBS_T, NHEADS, BB), blk2, 0, stream>>>(
            KdP, KoP, QP, dvattP, VoP, mergedP);

        // 6: output projection (fp32 out)
        proj_mfma<<<dim3(BB*37, 4, 1), blk, 0, stream>>>(
            mergedP, OPOS, 0, OPOS, OPOS,
            oowb + wB, oowb + wB, oowb + wB,
            obsout, obsout, obsout, 2, 2, 2, 1.f, 1.f, 1.f);

        // 7: residual + BN
        bn_fuse<<<dim3(CC), blk, 0, stream>>>(xin, obsout, gam + i*CC, bet + i*CC, xout);
    }
}

// Round 9
// 431.493 us; speedup vs baseline: 8.8451x; 1.0317x over previous
//
#include <hip/hip_runtime.h>
#include <hip/hip_bf16.h>

// Problem constants
#define BB 4
#define CC 256
#define TT 16
#define HW 196
#define DEMO_T 4
#define OBS_T 12
#define DPOS 784      // DEMO_T*HW
#define OPOS 2352     // OBS_T*HW
#define XROW 3136     // TT*HW
#define NHEADS 8
#define CH 32
#define NPOS 980      // DPOS + HW (cat keys per (b,t,n))

typedef float  f32x4 __attribute__((ext_vector_type(4)));
typedef short  s8v   __attribute__((ext_vector_type(8)));
typedef short  s4v   __attribute__((ext_vector_type(4)));

// bf16 convert via official cast — compiler fuses pairs into v_cvt_pk_bf16_f32
static __device__ __forceinline__ ushort f2bf(float f) {
    union { __hip_bfloat16 h; ushort u; } cv;
    cv.h = __float2bfloat16(f);
    return cv.u;
}
static __device__ __forceinline__ short bfr(float f) { return (short)f2bf(f); }

static __device__ __forceinline__ float fast_rcp(float x) {
#if __has_builtin(__builtin_amdgcn_rcpf)
    return __builtin_amdgcn_rcpf(x);
#else
    return 1.f / x;
#endif
}

static __device__ __forceinline__ float fexp2(float x) {
#if __has_builtin(__builtin_amdgcn_exp2f)
    return __builtin_amdgcn_exp2f(x);
#else
    return exp2f(x);
#endif
}

// DPP row-rotate add: allreduce-sum across an aligned 16-lane row in 4 VALU
// ops (vs 4 x ~30cy ds-shuffles). CTRL: 0x120|n = row_ror:n.
template<int CTRL>
static __device__ __forceinline__ float dpp_add(float x) {
    union { float f; int i; } a, o;
    a.f = x;
    o.i = __builtin_amdgcn_update_dpp(0, a.i, CTRL, 0xF, 0xF, true);
    return x + o.f;
}
static __device__ __forceinline__ float row16_sum(float x) {
    x = dpp_add<0x128>(x);   // ror 8
    x = dpp_add<0x124>(x);   // ror 4
    x = dpp_add<0x122>(x);   // ror 2
    x = dpp_add<0x121>(x);   // ror 1
    return x;
}

static __device__ __forceinline__ f32x4 mfma_pv(s4v a, s4v b, f32x4 c) {
#if __has_builtin(__builtin_amdgcn_mfma_f32_16x16x16bf16_1k)
    return __builtin_amdgcn_mfma_f32_16x16x16bf16_1k(a, b, c, 0, 0, 0);
#else
    s8v a8 = {a[0], a[1], a[2], a[3], 0, 0, 0, 0};
    s8v b8 = {b[0], b[1], b[2], b[3], 0, 0, 0, 0};
    return __builtin_amdgcn_mfma_f32_16x16x32_bf16(a8, b8, c, 0, 0, 0);
#endif
}

// ---------------------------------------------------------------------------
// pack_T: fp32 [b][256][P] -> bf16 [b][8][P][32]  (per-c-chunk transpose)
// ---------------------------------------------------------------------------
__global__ __launch_bounds__(256) void pack_T(
    const float* __restrict__ src, ushort* __restrict__ dst, int P)
{
    const int hn = blockIdx.y, bb = blockIdx.z;
    const int p0 = blockIdx.x * 64;
    __shared__ float L[32][73];
    const int tid = threadIdx.x;
    {
        const int c = tid >> 3, sg = tid & 7;
        const int p = p0 + sg*8;
        const float* s = src + ((size_t)bb*CC + hn*CH + c) * P + p;
        float4 a = {0,0,0,0}, b2 = {0,0,0,0};
        if (p < P) { a = *reinterpret_cast<const float4*>(s);
                     b2 = *reinterpret_cast<const float4*>(s + 4); }
        L[c][sg*8+0]=a.x;  L[c][sg*8+1]=a.y;  L[c][sg*8+2]=a.z;  L[c][sg*8+3]=a.w;
        L[c][sg*8+4]=b2.x; L[c][sg*8+5]=b2.y; L[c][sg*8+6]=b2.z; L[c][sg*8+7]=b2.w;
    }
    __syncthreads();
    {
        const int pl = tid >> 2, cs = (tid & 3) * 8;
        if (p0 + pl < P) {
            ushort o[8];
            #pragma unroll
            for (int j = 0; j < 8; j++) o[j] = f2bf(L[cs+j][pl]);
            uint4 v;
            v.x = o[0] | ((uint)o[1]<<16); v.y = o[2] | ((uint)o[3]<<16);
            v.z = o[4] | ((uint)o[5]<<16); v.w = o[6] | ((uint)o[7]<<16);
            *reinterpret_cast<uint4*>(dst + (((size_t)bb*NHEADS + hn)*P + p0 + pl)*32 + cs) = v;
        }
    }
}

// ---------------------------------------------------------------------------
// pack_cvt: flat fp32 -> bf16 (n4 = count/4)
// ---------------------------------------------------------------------------
__global__ __launch_bounds__(256) void pack_cvt(
    const float* __restrict__ src, ushort* __restrict__ dst, int n4)
{
    for (size_t i = (size_t)blockIdx.x * 256 + threadIdx.x; i < (size_t)n4;
         i += (size_t)gridDim.x * 256) {
        const float4 v = *reinterpret_cast<const float4*>(src + i*4);
        uint2 o;
        o.x = f2bf(v.x) | ((uint)f2bf(v.y) << 16);
        o.y = f2bf(v.z) | ((uint)f2bf(v.w) << 16);
        *reinterpret_cast<uint2*>(dst + i*4) = o;
    }
}

// ---------------------------------------------------------------------------
// bf16 MFMA projection GEMM with fused pack epilogues (+ per-z output scale).
//   variant 0 = packed-T bf16 [b][8][OP][32]; 1 = natural bf16 [b][256][OP];
//   2 = natural fp32 [b][256][OP]
// ---------------------------------------------------------------------------
__global__ __launch_bounds__(256) void proj_mfma(
    const ushort* __restrict__ XPK, int P, int pOff, int ncols, int OP,
    const ushort* __restrict__ W0, const ushort* __restrict__ W1, const ushort* __restrict__ W2,
    void* __restrict__ O0, void* __restrict__ O1, void* __restrict__ O2,
    int v0, int v1, int v2, float sc0, float sc1, float sc2)
{
    const int ptiles = (ncols + 63) >> 6;
    const int b  = blockIdx.x / ptiles;
    const int pt = blockIdx.x % ptiles;
    const int fbase = blockIdx.y * 64;
    const int z = blockIdx.z;
    const ushort* W = (z == 0) ? W0 : (z == 1) ? W1 : W2;
    void*        O = (z == 0) ? O0 : (z == 1) ? O1 : O2;
    const int variant = (z == 0) ? v0 : (z == 1) ? v1 : v2;
    const float sc    = (z == 0) ? sc0 : (z == 1) ? sc1 : sc2;

    const int tid = threadIdx.x, lane = tid & 63, w = tid >> 6;
    const int l15 = lane & 15, grp = lane >> 4;

    __shared__ float Cf[64][68];

    f32x4 acc[4];
    #pragma unroll
    for (int nt = 0; nt < 4; ++nt) acc[nt] = (f32x4){0.f, 0.f, 0.f, 0.f};

    const ushort* Wrow = W + (size_t)(fbase + w*16 + l15) * CC;
    int prow[4];
    #pragma unroll
    for (int nt = 0; nt < 4; ++nt) {
        const int p = pt*64 + nt*16 + l15;
        prow[nt] = (p < ncols) ? p : (ncols - 1);   // clamp: dup rows discarded
    }
    const size_t xb = (size_t)b * 8;

    #pragma unroll
    for (int kc = 0; kc < 8; ++kc) {
        const s8v aW = *reinterpret_cast<const s8v*>(Wrow + kc*32 + grp*8);
        #pragma unroll
        for (int nt = 0; nt < 4; ++nt) {
            const s8v bX = *reinterpret_cast<const s8v*>(
                XPK + ((xb + kc)*P + pOff + prow[nt])*32 + grp*8);
            acc[nt] = __builtin_amdgcn_mfma_f32_16x16x32_bf16(aW, bX, acc[nt], 0, 0, 0);
        }
    }
    #pragma unroll
    for (int nt = 0; nt < 4; ++nt)
        #pragma unroll
        for (int r = 0; r < 4; ++r)
            Cf[w*16 + grp*4 + r][nt*16 + l15] = acc[nt][r] * sc;
    __syncthreads();

    if (variant == 0) {
        ushort* dst = (ushort*)O;
        const int p_l = tid >> 2, c8 = (tid & 3) * 8;
        const int opos = pt*64 + p_l;
        if (opos < ncols) {
            #pragma unroll
            for (int hq = 0; hq < 2; ++hq) {
                ushort e[8];
                #pragma unroll
                for (int j = 0; j < 8; ++j) e[j] = f2bf(Cf[hq*32 + c8 + j][p_l]);
                uint4 v;
                v.x = e[0] | ((uint)e[1]<<16); v.y = e[2] | ((uint)e[3]<<16);
                v.z = e[4] | ((uint)e[5]<<16); v.w = e[6] | ((uint)e[7]<<16);
                *reinterpret_cast<uint4*>(
                    dst + (((size_t)b*NHEADS + (fbase >> 5) + hq)*OP + opos)*32 + c8) = v;
            }
        }
    } else if (variant == 1) {
        ushort* dst = (ushort*)O;
        #pragma unroll
        for (int pass = 0; pass < 2; ++pass) {
            const int idx = pass*256 + tid;
            const int f_l = idx >> 3, u = idx & 7;
            const int p0 = pt*64 + u*8;
            if (p0 < ncols) {
                ushort e[8];
                #pragma unroll
                for (int j = 0; j < 8; ++j) e[j] = f2bf(Cf[f_l][u*8 + j]);
                uint4 v;
                v.x = e[0] | ((uint)e[1]<<16); v.y = e[2] | ((uint)e[3]<<16);
                v.z = e[4] | ((uint)e[5]<<16); v.w = e[6] | ((uint)e[7]<<16);
                *reinterpret_cast<uint4*>(
                    dst + ((size_t)b*CC + fbase + f_l)*OP + p0) = v;
            }
        }
    } else {
        float* dst = (float*)O;
        #pragma unroll
        for (int pass = 0; pass < 2; ++pass) {
            const int idx = pass*256 + tid;
            const int f_l = idx >> 3, u = idx & 7;
            const int p0 = pt*64 + u*8;
            if (p0 < ncols) {
                float* dp = dst + ((size_t)b*CC + fbase + f_l)*OP + p0;
                *reinterpret_cast<float4*>(dp)     = *reinterpret_cast<const float4*>(&Cf[f_l][u*8]);
                *reinterpret_cast<float4*>(dp + 4) = *reinterpret_cast<const float4*>(&Cf[f_l][u*8 + 4]);
            }
        }
    }
}

// ---------------------------------------------------------------------------
// Demo attention — bf16 MFMA, 512 threads, NO-MAX softmax, barrier-free main
// loop. Q pre-scaled by log2(e)/16 at pack time -> raw exp2 here.
// ---------------------------------------------------------------------------
__global__ __launch_bounds__(512) void demo_attn_mfma(
    const ushort* __restrict__ QdP, const ushort* __restrict__ KdP,
    const ushort* __restrict__ VdP, ushort* __restrict__ dvattP)
{
    const int ib = blockIdx.x, hn = blockIdx.y, bb = blockIdx.z;
    const int tid = threadIdx.x;
    const int g   = tid >> 8;          // j-half
    const int gt  = tid & 255;
    const int lane = tid & 63;
    const int w    = (tid >> 6) & 3;   // i-quarter
    const int l15 = lane & 15, grp = lane >> 4;

    __shared__ float mrg[2304];                       // Lb[256] Ob[2048]
    __shared__ __align__(16) ushort OutS[32*72];

    const size_t hBase = ((size_t)bb*NHEADS + hn) * DPOS;
    const size_t vRow0 = ((size_t)bb*CC + hn*CH) * DPOS;

    const int i_glob = ib*64 + w*16 + l15;
    const s8v bK = *reinterpret_cast<const s8v*>(KdP + (hBase + i_glob)*32 + grp*8);

    f32x4 accO[2] = {{0.f,0.f,0.f,0.f}, {0.f,0.f,0.f,0.f}};
    float l_run = 0.f;

    const int chFirst = g ? 7 : 0;
    const int chEnd   = g ? 13 : 7;
    for (int ch = chFirst; ch < chEnd; ++ch) {
        const int nt = (ch == 12) ? 1 : 4;
        for (int jt = 0; jt < nt; ++jt) {
            const s8v aQ = *reinterpret_cast<const s8v*>(
                QdP + (hBase + ch*64 + jt*16 + l15)*32 + grp*8);
            const f32x4 z = {0.f,0.f,0.f,0.f};
            const f32x4 st = __builtin_amdgcn_mfma_f32_16x16x32_bf16(aQ, bK, z, 0, 0, 0);
            const float e0 = fexp2(st[0]), e1 = fexp2(st[1]);
            const float e2 = fexp2(st[2]), e3 = fexp2(st[3]);
            l_run += (e0 + e1) + (e2 + e3);
            s4v pf4;
            pf4[0] = bfr(e0); pf4[1] = bfr(e1); pf4[2] = bfr(e2); pf4[3] = bfr(e3);
            #pragma unroll
            for (int ct = 0; ct < 2; ++ct) {
                const s4v aV = *reinterpret_cast<const s4v*>(
                    VdP + vRow0 + (size_t)(ct*16 + l15)*DPOS + ch*64 + jt*16 + grp*4);
                accO[ct] = mfma_pv(aV, pf4, accO[ct]);
            }
        }
    }
    // cross-grp partial-l reduce (j spans grp via the C-row mapping)
    l_run += __shfl_xor(l_run, 16);
    l_run += __shfl_xor(l_run, 32);

    // ---- merge: simple (l, O) add across groups, then normalize ----
    float* Lb = mrg;          // [256]
    float* Ob = mrg + 256;    // [256][8]
    if (g == 1) {
        Lb[w*64 + lane] = l_run;
        #pragma unroll
        for (int ct = 0; ct < 2; ++ct)
            #pragma unroll
            for (int r = 0; r < 4; ++r)
                Ob[(w*64 + lane)*8 + ct*4 + r] = accO[ct][r];
    }
    __syncthreads();
    if (g == 0) {
        const float linv = 1.f / (l_run + Lb[w*64 + lane]);
        #pragma unroll
        for (int ct = 0; ct < 2; ++ct)
            #pragma unroll
            for (int r = 0; r < 4; ++r) {
                const float o = (accO[ct][r] + Ob[(w*64 + lane)*8 + ct*4 + r]) * linv;
                OutS[(ct*16 + grp*4 + r)*72 + w*16 + l15] = f2bf(o);
            }
    }
    __syncthreads();
    if (g == 0) {
        const int c = gt >> 3, sg = gt & 7;
        const int col = ib*64 + sg*8;
        if (col < DPOS) {
            const uint4 v = *reinterpret_cast<const uint4*>(&OutS[c*72 + sg*8]);
            *reinterpret_cast<uint4*>(dvattP + vRow0 + (size_t)c*DPOS + col) = v;
        }
    }
}

// ---------------------------------------------------------------------------
// Obs attention per (b, t, n) — bf16 MFMA, 512 threads, barrier-free main
// loop, NO-MAX softmax, DPP row-rotate allreduce for the q-sum (the 16-lane
// group sharing grp is an aligned DPP row). Q pre-scaled log2(e)/16 -> exp2.
// ---------------------------------------------------------------------------
__global__ __launch_bounds__(512) void obs_attn_mfma(
    const ushort* __restrict__ KdP, const ushort* __restrict__ KoP,
    const ushort* __restrict__ QP,  const ushort* __restrict__ VdP,
    const ushort* __restrict__ VoP, ushort* __restrict__ mergedP)
{
    const int tt = blockIdx.x, hn = blockIdx.y, bb = blockIdx.z;
    __shared__ __align__(16) ushort smem_u[27136];   // QT[208][40] ∪ Ored[2][32][212]f32
    ushort* QT = smem_u;

    const int tid  = threadIdx.x;
    const int g    = tid >> 8;
    const int lane = tid & 63;
    const int w    = (tid >> 6) & 3;
    const int l15  = lane & 15, grp = lane >> 4;

    const size_t kdBase = ((size_t)bb*NHEADS + hn) * DPOS * 32;
    const size_t koBase = ((size_t)bb*NHEADS + hn) * OPOS * 32 + (size_t)tt*HW*32;
    const size_t vdRow0 = ((size_t)bb*CC + hn*CH) * DPOS;
    const size_t voRow0 = ((size_t)bb*CC + hn*CH) * OPOS + (size_t)tt*HW;

    // stage Q once (rows >= 196 zero)
    for (int idx = tid; idx < 832; idx += 512) {
        const int r = idx >> 2, sg = idx & 3;
        uint4 v = {0,0,0,0};
        if (r < HW) v = *reinterpret_cast<const uint4*>(QP + koBase + (size_t)r*32 + sg*8);
        *reinterpret_cast<uint4*>(&QT[r*40 + sg*8]) = v;
    }

    f32x4 accO[2][13];
    #pragma unroll
    for (int ct = 0; ct < 2; ++ct)
        #pragma unroll
        for (int qt = 0; qt < 13; ++qt)
            accO[ct][qt] = (f32x4){0.f, 0.f, 0.f, 0.f};
    __syncthreads();

    const int pw = (g*4 + w) * 128;
    for (int s = 0; s < 8; ++s) {
        const int p0 = pw + s*16;
        // ---- K fragment: direct global ----
        const int pk = p0 + l15;
        s8v aK = {0,0,0,0,0,0,0,0};
        if (pk < NPOS) {
            const ushort* kp = (pk < DPOS)
                ? KdP + kdBase + (size_t)pk*32
                : KoP + koBase + (size_t)(pk - DPOS)*32;
            aK = *reinterpret_cast<const s8v*>(kp + grp*8);
        }
        // ---- S: 13 q-tiles ----
        f32x4 ss[13];
        #pragma unroll
        for (int qt = 0; qt < 13; ++qt) {
            const s8v bQ = *reinterpret_cast<const s8v*>(&QT[(qt*16 + l15)*40 + grp*8]);
            const f32x4 z = {0.f, 0.f, 0.f, 0.f};
            ss[qt] = __builtin_amdgcn_mfma_f32_16x16x32_bf16(aK, bQ, z, 0, 0, 0);
        }
        // ---- no-max softmax over q per p-row (DPP row16 allreduce) ----
        #pragma unroll
        for (int r = 0; r < 4; ++r) {
            #pragma unroll
            for (int qt = 0; qt < 13; ++qt) ss[qt][r] = fexp2(ss[qt][r]);
            if (l15 >= 4) ss[12][r] = 0.f;   // q >= 196 pad
            float sum = ((((ss[0][r]+ss[1][r]) + (ss[2][r]+ss[3][r]))
                        + ((ss[4][r]+ss[5][r]) + (ss[6][r]+ss[7][r])))
                        + (((ss[8][r]+ss[9][r]) + (ss[10][r]+ss[11][r])) + ss[12][r]));
            sum = row16_sum(sum);
            const float is = fast_rcp(sum);
            #pragma unroll
            for (int qt = 0; qt < 13; ++qt) ss[qt][r] *= is;
        }
        s4v pf[13];
        #pragma unroll
        for (int qt = 0; qt < 13; ++qt) {
            s4v p4;
            #pragma unroll
            for (int r = 0; r < 4; ++r) p4[r] = bfr(ss[qt][r]);
            pf[qt] = p4;
        }
        // ---- PV: V fragments direct global ----
        #pragma unroll
        for (int ct = 0; ct < 2; ++ct) {
            const int c  = ct*16 + l15;
            const int pv = p0 + grp*4;
            s4v aV = {0,0,0,0};
            if (pv < NPOS) {
                const ushort* vp = (pv < DPOS)
                    ? VdP + vdRow0 + (size_t)c*DPOS + pv
                    : VoP + voRow0 + (size_t)c*OPOS + (pv - DPOS);
                aV = *reinterpret_cast<const s4v*>(vp);
            }
            #pragma unroll
            for (int qt = 0; qt < 13; ++qt)
                accO[ct][qt] = mfma_pv(aV, pf[qt], accO[ct][qt]);
        }
    }
    __syncthreads();

    // ---- per-group 4-wave reduction into Ored[g] ----
    float* OredF = reinterpret_cast<float*>(smem_u);   // [2][32][212]
    float* Og = OredF + g * 6784;
    for (int wv = 0; wv < 4; ++wv) {
        if (w == wv) {
            #pragma unroll
            for (int ct = 0; ct < 2; ++ct)
                #pragma unroll
                for (int qt = 0; qt < 13; ++qt)
                    #pragma unroll
                    for (int r = 0; r < 4; ++r) {
                        const int c = ct*16 + grp*4 + r;
                        const int q = qt*16 + l15;
                        if (wv == 0) Og[c*212 + q]  = accO[ct][qt][r];
                        else         Og[c*212 + q] += accO[ct][qt][r];
                    }
        }
        __syncthreads();
    }
    // add group partials, convert, store packed-T bf16 [q][32c]
    for (int idx = tid; idx < HW*4; idx += 512) {
        const int q = idx >> 2, c8 = (idx & 3) * 8;
        ushort e[8];
        #pragma unroll
        for (int j = 0; j < 8; ++j) {
            const int c = c8 + j;
            e[j] = f2bf(OredF[c*212 + q] + OredF[6784 + c*212 + q]);
        }
        uint4 v;
        v.x = e[0] | ((uint)e[1]<<16); v.y = e[2] | ((uint)e[3]<<16);
        v.z = e[4] | ((uint)e[5]<<16); v.w = e[6] | ((uint)e[7]<<16);
        *reinterpret_cast<uint4*>(
            mergedP + (((size_t)bb*NHEADS + hn)*OPOS + (size_t)tt*HW + q)*32 + c8) = v;
    }
}

// ---------------------------------------------------------------------------
// Fused residual-ReLU + concat + BatchNorm. One block per channel. float4.
// ---------------------------------------------------------------------------
__global__ __launch_bounds__(256) void bn_fuse(
    const float* __restrict__ xin, const float* __restrict__ obsout,
    const float* __restrict__ gamma, const float* __restrict__ beta,
    float* __restrict__ xout)
{
    const int c = blockIdx.x;
    const int tid = threadIdx.x;
    float sum = 0.f, sumsq = 0.f;
    for (int idx = tid; idx < BB*(DPOS/4); idx += 256) {
        const int b = idx / (DPOS/4), pos = idx % (DPOS/4);
        const float4 v = *reinterpret_cast<const float4*>(
            &xin[((size_t)b*CC + c) * XROW + pos*4]);
        sum   += v.x + v.y + v.z + v.w;
        sumsq += v.x*v.x + v.y*v.y + v.z*v.z + v.w*v.w;
    }
    for (int idx = tid; idx < BB*(OPOS/4); idx += 256) {
        const int b = idx / (OPOS/4), pos = idx % (OPOS/4);
        const float4 xv = *reinterpret_cast<const float4*>(
            &xin[((size_t)b*CC + c) * XROW + DPOS + pos*4]);
        const float4 ov = *reinterpret_cast<const float4*>(
            &obsout[((size_t)b*CC + c) * OPOS + pos*4]);
        const float4 v = make_float4(xv.x + fmaxf(ov.x, 0.f), xv.y + fmaxf(ov.y, 0.f),
                                     xv.z + fmaxf(ov.z, 0.f), xv.w + fmaxf(ov.w, 0.f));
        sum   += v.x + v.y + v.z + v.w;
        sumsq += v.x*v.x + v.y*v.y + v.z*v.z + v.w*v.w;
    }
    #pragma unroll
    for (int off = 32; off > 0; off >>= 1) {
        sum   += __shfl_xor(sum, off);
        sumsq += __shfl_xor(sumsq, off);
    }
    __shared__ float ssum[4], ssq[4];
    __shared__ float s_mean, s_inv;
    const int lane = tid & 63, w = tid >> 6;
    if (lane == 0) { ssum[w] = sum; ssq[w] = sumsq; }
    __syncthreads();
    if (tid == 0) {
        float s  = ssum[0] + ssum[1] + ssum[2] + ssum[3];
        float sq = ssq[0] + ssq[1] + ssq[2] + ssq[3];
        const float mean = s / 12544.f;
        const float var  = sq / 12544.f - mean * mean;
        s_mean = mean;
        s_inv  = rsqrtf(var + 1e-5f);
    }
    __syncthreads();
    const float mean = s_mean;
    const float gi = gamma[c] * s_inv;
    const float bt = beta[c];
    for (int idx = tid; idx < BB*(DPOS/4); idx += 256) {
        const int b = idx / (DPOS/4), pos = idx % (DPOS/4);
        const size_t o = ((size_t)b*CC + c) * XROW + pos*4;
        const float4 v = *reinterpret_cast<const float4*>(&xin[o]);
        const float4 r = make_float4((v.x-mean)*gi+bt, (v.y-mean)*gi+bt,
                                     (v.z-mean)*gi+bt, (v.w-mean)*gi+bt);
        *reinterpret_cast<float4*>(&xout[o]) = r;
    }
    for (int idx = tid; idx < BB*(OPOS/4); idx += 256) {
        const int b = idx / (OPOS/4), pos = idx % (OPOS/4);
        const float4 xv = *reinterpret_cast<const float4*>(
            &xin[((size_t)b*CC + c) * XROW + DPOS + pos*4]);
        const float4 ov = *reinterpret_cast<const float4*>(
            &obsout[((size_t)b*CC + c) * OPOS + pos*4]);
        const float4 v = make_float4(xv.x + fmaxf(ov.x, 0.f), xv.y + fmaxf(ov.y, 0.f),
                                     xv.z + fmaxf(ov.z, 0.f), xv.w + fmaxf(ov.w, 0.f));
        const float4 r = make_float4((v.x-mean)*gi+bt, (v.y-mean)*gi+bt,
                                     (v.z-mean)*gi+bt, (v.w-mean)*gi+bt);
        *reinterpret_cast<float4*>(&xout[((size_t)b*CC + c) * XROW + DPOS + pos*4]) = r;
    }
}

// ---------------------------------------------------------------------------
extern "C" void kernel_launch(void* const* d_in, const int* in_sizes, int n_in,
                              void* d_out, int out_size, void* d_ws, size_t ws_size,
                              hipStream_t stream)
{
    const float* x   = (const float*)d_in[0];
    const float* dqw = (const float*)d_in[1];
    const float* dkw = (const float*)d_in[2];
    const float* dvw = (const float*)d_in[3];
    const float* oqw = (const float*)d_in[4];
    const float* okw = (const float*)d_in[5];
    const float* ovw = (const float*)d_in[6];
    const float* oow = (const float*)d_in[7];
    const float* gam = (const float*)d_in[8];
    const float* bet = (const float*)d_in[9];

    const size_t XN = (size_t)BB * CC * TT * HW;   // 3,211,264
    const size_t DN = (size_t)BB * CC * DPOS;      //   802,816
    const size_t ON = (size_t)BB * CC * OPOS;      // 2,408,448
    const size_t WN = (size_t)3 * CC * CC;         //   196,608

    float*  xb0     = (float*)d_ws;
    float*  xb1     = xb0 + XN;
    float*  obsout  = xb1 + XN;
    ushort* XP      = (ushort*)(obsout + ON);     // [b][8][3136][32]
    ushort* QdP     = XP + XN;
    ushort* KdP     = QdP + DN;
    ushort* VdemoP  = KdP + DN;
    ushort* dvattP  = VdemoP + DN;
    ushort* QP      = dvattP + DN;
    ushort* KoP     = QP + ON;
    ushort* VoP     = KoP + ON;
    ushort* mergedP = VoP + ON;
    ushort* wpk     = mergedP + ON;
    ushort* dqwb = wpk;          ushort* dkwb = wpk + WN;   ushort* dvwb = wpk + 2*WN;
    ushort* oqwb = wpk + 3*WN;   ushort* okwb = wpk + 4*WN; ushort* ovwb = wpk + 5*WN;
    ushort* oowb = wpk + 6*WN;

    const dim3 blk(256);
    const dim3 blk2(512);
    const float QS = 0.0625f * 1.44269504f;   // (1/sqrt(C)) * log2(e) -> raw exp2 in attn

    pack_cvt<<<dim3(192), blk, 0, stream>>>(dqw, dqwb, (int)(WN/4));
    pack_cvt<<<dim3(192), blk, 0, stream>>>(dkw, dkwb, (int)(WN/4));
    pack_cvt<<<dim3(192), blk, 0, stream>>>(dvw, dvwb, (int)(WN/4));
    pack_cvt<<<dim3(192), blk, 0, stream>>>(oqw, oqwb, (int)(WN/4));
    pack_cvt<<<dim3(192), blk, 0, stream>>>(okw, okwb, (int)(WN/4));
    pack_cvt<<<dim3(192), blk, 0, stream>>>(ovw, ovwb, (int)(WN/4));
    pack_cvt<<<dim3(192), blk, 0, stream>>>(oow, oowb, (int)(WN/4));

    for (int i = 0; i < 3; i++) {
        const float* xin  = (i == 0) ? x : (i == 1 ? xb0 : xb1);
        float*       xout = (i == 2) ? (float*)d_out : (i == 0 ? xb0 : xb1);
        const size_t wB = (size_t)i * CC * CC;

        // 1: pack x -> XP
        pack_T<<<dim3(49, 8, BB), blk, 0, stream>>>(xin, XP, XROW);

        // 2: demo projections (Q scaled by log2(e)/16 at pack)
        proj_mfma<<<dim3(BB*13, 4, 3), blk, 0, stream>>>(
            XP, XROW, 0, DPOS, DPOS,
            dqwb + wB, dkwb + wB, dvwb + wB,
            QdP, KdP, VdemoP, 0, 0, 1, QS, 1.f, 1.f);

        // 3: demo attention
        demo_attn_mfma<<<dim3(13, NHEADS, BB), blk2, 0, stream>>>(
            QdP, KdP, VdemoP, dvattP);

        // 4: obs projections (Q scaled by log2(e)/16 at pack)
        proj_mfma<<<dim3(BB*37, 4, 3), blk, 0, stream>>>(
            XP, XROW, DPOS, OPOS, OPOS,
            oqwb + wB, okwb + wB, ovwb + wB,
            QP, KoP, VoP, 0, 0, 1, QS, 1.f, 1.f);

        // 5: obs attention -> mergedP
        obs_attn_mfma<<<dim3(OBS_T, NHEADS, BB), blk2, 0, stream>>>(
            KdP, KoP, QP, dvattP, VoP, mergedP);

        // 6: output projection (fp32 out)
        proj_mfma<<<dim3(BB*37, 4, 1), blk, 0, stream>>>(
            mergedP, OPOS, 0, OPOS, OPOS,
            oowb + wB, oowb + wB, oowb + wB,
            obsout, obsout, obsout, 2, 2, 2, 1.f, 1.f, 1.f);

        // 7: residual + BN
        bn_fuse<<<dim3(CC), blk, 0, stream>>>(xin, obsout, gam + i*CC, bet + i*CC, xout);
    }
}